// Round 1
// baseline (4000.249 us; speedup 1.0000x reference)
//
#include <hip/hip_runtime.h>
#include <hip/hip_bf16.h>
#include <cstddef>
#include <cstdint>

// Problem constants (B=1)
#define S      2048
#define DIM    1024
#define HEADS  16
#define KVH    2
#define GQ     8
#define DH     64
#define CBS    64
#define SBS    64
#define NUMSEL 8
#define WIN    512
#define NCB    (S / CBS)      // 32
#define CDIM   (CBS * DH)     // 4096
#define QKVC   (HEADS * DH + 2 * KVH * DH)   // 1280
#define KOFF   (HEADS * DH)                  // 1024 (k cols start)
#define VOFF   (HEADS * DH + KVH * DH)       // 1152 (v cols start)
#define SCALE  0.125f
#define RMS_EPS 1.1920928955078125e-07f

// ---------------- wave (64-lane) reductions ----------------
__device__ inline float wave_max(float v) {
    for (int o = 32; o > 0; o >>= 1) v = fmaxf(v, __shfl_xor(v, o));
    return v;
}
__device__ inline float wave_sum(float v) {
    for (int o = 32; o > 0; o >>= 1) v += __shfl_xor(v, o);
    return v;
}

// ---------------- RMSNorm ----------------
__global__ __launch_bounds__(256) void rmsnorm_kernel(
        const float* __restrict__ x, const float* __restrict__ g,
        float* __restrict__ xn) {
    int s = blockIdx.x, tid = threadIdx.x;
    const float4* row = (const float4*)(x + (size_t)s * DIM);
    float4 v = row[tid];
    float ss = v.x * v.x + v.y * v.y + v.z * v.z + v.w * v.w;
    ss = wave_sum(ss);
    __shared__ float red[4];
    if ((tid & 63) == 0) red[tid >> 6] = ss;
    __syncthreads();
    float tot = red[0] + red[1] + red[2] + red[3];
    float sc = rsqrtf(tot / (float)DIM + RMS_EPS);
    float4 gg = ((const float4*)g)[tid];
    float4 o;
    o.x = v.x * sc * gg.x; o.y = v.y * sc * gg.y;
    o.z = v.z * sc * gg.z; o.w = v.w * sc * gg.w;
    ((float4*)(xn + (size_t)s * DIM))[tid] = o;
}

// ---------------- generic tiled fp32 GEMM: C = act(A@B + bias) ----------------
// A: (M,K) row-major, B: (K,N) row-major. ACT: 0=none 1=relu 2=sigmoid
template <int ACT>
__global__ __launch_bounds__(256) void gemm_kernel(
        const float* __restrict__ A, const float* __restrict__ B,
        const float* __restrict__ bias, float* __restrict__ C,
        int M, int N, int K) {
    const int BM = 64, BN = 64, BK = 16;
    __shared__ float As[BK][BM + 4];
    __shared__ float Bs[BK][BN];
    int bm = blockIdx.y * BM, bn = blockIdx.x * BN;
    int tid = threadIdx.x;
    int tx = tid & 15, ty = tid >> 4;
    float acc[4][4] = {{0.f}};
    for (int k0 = 0; k0 < K; k0 += BK) {
        #pragma unroll
        for (int e = 0; e < 4; e++) {
            int idx = tid + e * 256;            // 0..1023
            int m = idx >> 4, kk = idx & 15;
            int gm = bm + m;
            As[kk][m] = (gm < M) ? A[(size_t)gm * K + k0 + kk] : 0.f;
        }
        #pragma unroll
        for (int e = 0; e < 4; e++) {
            int idx = tid + e * 256;
            int kk = idx >> 6, n = idx & 63;
            int gn = bn + n;
            Bs[kk][n] = (gn < N) ? B[(size_t)(k0 + kk) * N + gn] : 0.f;
        }
        __syncthreads();
        #pragma unroll
        for (int kk = 0; kk < BK; kk++) {
            float a[4], b[4];
            #pragma unroll
            for (int i = 0; i < 4; i++) a[i] = As[kk][ty * 4 + i];
            #pragma unroll
            for (int j = 0; j < 4; j++) b[j] = Bs[kk][tx * 4 + j];
            #pragma unroll
            for (int i = 0; i < 4; i++)
                #pragma unroll
                for (int j = 0; j < 4; j++) acc[i][j] += a[i] * b[j];
        }
        __syncthreads();
    }
    #pragma unroll
    for (int i = 0; i < 4; i++) {
        int gm = bm + ty * 4 + i;
        if (gm >= M) continue;
        #pragma unroll
        for (int j = 0; j < 4; j++) {
            int gn = bn + tx * 4 + j;
            if (gn >= N) continue;
            float v = acc[i][j];
            if (bias) v += bias[gn];
            if (ACT == 1) v = fmaxf(v, 0.f);
            if (ACT == 2) v = 1.f / (1.f + expf(-v));
            C[(size_t)gm * N + gn] = v;
        }
    }
}

// ---------------- rotary embedding (interleaved pairs, theta=10000) ----------------
// rq: (S, HEADS, DH), rk: (S, KVH, DH)
__global__ __launch_bounds__(256) void rotary_kernel(
        const float* __restrict__ qkv, float* __restrict__ rq, float* __restrict__ rk) {
    int s = blockIdx.x, tid = threadIdx.x;
    for (int p = tid; p < (HEADS + KVH) * (DH / 2); p += 256) {
        int t; const float* src; float* dst;
        if (p < HEADS * (DH / 2)) {
            int h = p >> 5; t = p & 31;
            src = qkv + (size_t)s * QKVC + h * DH + 2 * t;
            dst = rq + (size_t)s * (HEADS * DH) + h * DH + 2 * t;
        } else {
            int pp = p - HEADS * (DH / 2);
            int h = pp >> 5; t = pp & 31;
            src = qkv + (size_t)s * QKVC + KOFF + h * DH + 2 * t;
            dst = rk + (size_t)s * (KVH * DH) + h * DH + 2 * t;
        }
        float u0 = src[0], u1 = src[1];
        float freq = powf(10000.f, -((float)(2 * t) / (float)DH));
        float ang = (float)s * freq;
        float sn, cs;
        sincosf(ang, &sn, &cs);
        dst[0] = u0 * cs - u1 * sn;
        dst[1] = u1 * cs + u0 * sn;
    }
}

// ---------------- build compress-MLP input matrices (64 rows x 4096) ----------------
__global__ __launch_bounds__(256) void build_cmat_kernel(
        const float* __restrict__ qkv, const float* __restrict__ k_pos,
        const float* __restrict__ v_pos, float* __restrict__ kcm, float* __restrict__ vcm) {
    int r = blockIdx.x;          // r = h*32 + w
    int h = r >> 5, w = r & 31;
    for (int e = threadIdx.x; e < CDIM; e += 256) {
        int i = e >> 6, d = e & 63;
        size_t qb = (size_t)(w * CBS + i) * QKVC;
        kcm[(size_t)r * CDIM + e] = qkv[qb + KOFF + h * DH + d] + k_pos[(h * CBS + i) * DH + d];
        vcm[(size_t)r * CDIM + e] = qkv[qb + VOFF + h * DH + d] + v_pos[(h * CBS + i) * DH + d];
    }
}

// ---------------- assemble ck/cv: prepend mem_kv -> (KVH, 33, DH) ----------------
__global__ __launch_bounds__(256) void assemble_kernel(
        const float* __restrict__ ckb, const float* __restrict__ cvb,
        const float* __restrict__ mem_kv, float* __restrict__ ck, float* __restrict__ cv) {
    int e = blockIdx.x * 256 + threadIdx.x;
    if (e >= KVH * (NCB + 1) * DH) return;
    int d = e & 63;
    int j = (e >> 6) % (NCB + 1);
    int h = e / ((NCB + 1) * DH);
    if (j == 0) {
        ck[e] = mem_kv[0 * KVH * DH + h * DH + d];
        cv[e] = mem_kv[1 * KVH * DH + h * DH + d];
    } else {
        ck[e] = ckb[((size_t)h * NCB + j - 1) * DH + d];
        cv[e] = cvb[((size_t)h * NCB + j - 1) * DH + d];
    }
}

// ---------------- block importance: imp[kvh][s][w] ----------------
__global__ __launch_bounds__(64) void imp_kernel(
        const float* __restrict__ qkv, const float* __restrict__ ck,
        float* __restrict__ imp) {
    int kvh = blockIdx.x, s = blockIdx.y, t = threadIdx.x;
    __shared__ float qg[GQ * DH];          // 8 query rows (non-rotary)
    __shared__ float ckl[NCB * 65];        // padded: bank-conflict-free
    for (int e = t; e < GQ * DH; e += 64) {
        int g = e >> 6, d = e & 63;
        qg[e] = qkv[(size_t)s * QKVC + (kvh * GQ + g) * DH + d];
    }
    for (int e = t; e < NCB * DH; e += 64) {
        int w = e >> 6, d = e & 63;
        ckl[w * 65 + d] = ck[((size_t)kvh * (NCB + 1) + 1 + w) * DH + d];
    }
    __syncthreads();
    if (t < NCB) {
        int w = t;
        float val;
        if (w * CBS + CBS - 1 < s) {        // block fully in the past
            float acc = 0.f;
            #pragma unroll
            for (int g = 0; g < GQ; g++) {
                const float* qp = qg + g * DH;
                const float* cp = ckl + w * 65;
                #pragma unroll 16
                for (int d = 0; d < DH; d++) acc += qp[d] * cp[d];
            }
            val = acc * SCALE * (1.f / (float)GQ);
        } else {
            val = -INFINITY;
        }
        imp[((size_t)kvh * S + s) * NCB + w] = val;
    }
}

// ---------------- top-8 selection (replicates lax.top_k stable ties) ----------------
__global__ __launch_bounds__(256) void select_kernel(
        const float* __restrict__ imp, int* __restrict__ sel) {
    int idx = blockIdx.x * 256 + threadIdx.x;    // (kvh*S + s)
    if (idx >= KVH * S) return;
    const float* row = imp + (size_t)idx * NCB;
    float p[NCB];
    float m = -1000.f;                            // prepended sentinel column
    for (int w = 0; w < NCB; w++) { p[w] = row[w]; m = fmaxf(m, p[w]); }
    float z = expf(-1000.f - m);
    for (int w = 0; w < NCB; w++) { p[w] = expf(p[w] - m); z += p[w]; }
    float inv = 1.f / z;
    bool used[NCB];
    for (int w = 0; w < NCB; w++) used[w] = false;
    for (int i = 0; i < NUMSEL; i++) {
        int best = 0; float bv = -1.f;
        for (int w = 0; w < NCB; w++) {
            if (!used[w]) {
                float pw = p[w] * inv;
                if (pw > bv) { bv = pw; best = w; }
            }
        }
        used[best] = true;
        sel[(size_t)idx * NUMSEL + i] = (bv > 1e-10f) ? best : -1;
    }
}

// ---------------- compressed attention (33 keys), writes g0 * c_out ----------------
__global__ __launch_bounds__(64) void cattn_kernel(
        const float* __restrict__ qkv, const float* __restrict__ ck,
        const float* __restrict__ cv, const float* __restrict__ gates,
        float* __restrict__ attn) {
    int h = blockIdx.x, s = blockIdx.y, t = threadIdx.x;
    int kvh = h >> 3;
    __shared__ float qL[DH];
    __shared__ float pL[NCB + 1];
    qL[t] = qkv[(size_t)s * QKVC + h * DH + t];   // non-rotary q
    __syncthreads();
    float score = -INFINITY;
    if (t < NCB + 1) {
        bool vis = (t == 0) ? true : ((t - 1) * CBS + CBS - 1 < s);
        if (vis) {
            const float4* cp = (const float4*)(ck + ((size_t)kvh * (NCB + 1) + t) * DH);
            const float4* q4 = (const float4*)qL;
            float acc = 0.f;
            #pragma unroll
            for (int d = 0; d < DH / 4; d++) {
                float4 a = q4[d], b = cp[d];
                acc += a.x * b.x + a.y * b.y + a.z * b.z + a.w * b.w;
            }
            score = acc * SCALE;
        }
    }
    float M = wave_max(score);
    float e = expf(score - M);          // -inf -> 0
    float Z = wave_sum(e);
    if (t < NCB + 1) pL[t] = e / Z;
    __syncthreads();
    float acc = 0.f;
    for (int j = 0; j < NCB + 1; j++)
        acc += pL[j] * cv[((size_t)kvh * (NCB + 1) + j) * DH + t];
    float g0 = gates[((size_t)s * HEADS + h) * 3 + 0];
    attn[(size_t)s * (HEADS * DH) + h * DH + t] = g0 * acc;
}

// ---------------- fine attention over 8 selected + diagonal block ----------------
__global__ __launch_bounds__(64) void fattn_kernel(
        const float* __restrict__ rq, const float* __restrict__ rk,
        const float* __restrict__ qkv, const int* __restrict__ sel,
        const float* __restrict__ gates, float* __restrict__ attn) {
    int h = blockIdx.x, s = blockIdx.y, t = threadIdx.x;
    int kvh = h >> 3;
    __shared__ float qL[DH];
    __shared__ float pL[(NUMSEL + 1) * SBS];
    __shared__ int bl[NUMSEL + 1];
    qL[t] = rq[(size_t)s * (HEADS * DH) + h * DH + t];
    if (t < NUMSEL) bl[t] = sel[((size_t)kvh * S + s) * NUMSEL + t];
    if (t == NUMSEL) bl[NUMSEL] = s >> 6;        // diagonal block
    __syncthreads();
    float sc[NUMSEL + 1];
    #pragma unroll
    for (int i = 0; i < NUMSEL + 1; i++) {
        int w = bl[i];
        float scv = -INFINITY;
        bool vis = (i < NUMSEL) ? (w >= 0) : (t <= (s & 63));
        if (vis) {
            const float4* kp = (const float4*)(rk + (size_t)(w * SBS + t) * (KVH * DH) + kvh * DH);
            const float4* q4 = (const float4*)qL;
            float acc = 0.f;
            #pragma unroll
            for (int d = 0; d < DH / 4; d++) {
                float4 a = q4[d], b = kp[d];
                acc += a.x * b.x + a.y * b.y + a.z * b.z + a.w * b.w;
            }
            scv = acc * SCALE;
        }
        sc[i] = scv;
    }
    float m = -INFINITY;
    #pragma unroll
    for (int i = 0; i < NUMSEL + 1; i++) m = fmaxf(m, sc[i]);
    float M = wave_max(m);
    float zs = 0.f;
    #pragma unroll
    for (int i = 0; i < NUMSEL + 1; i++) {
        float e = expf(sc[i] - M);
        zs += e;
        pL[i * SBS + t] = e;
    }
    float Z = wave_sum(zs);
    __syncthreads();
    float inv = 1.f / Z;
    float acc = 0.f;
    for (int i = 0; i < NUMSEL + 1; i++) {
        int w = bl[i];
        if (w < 0) continue;
        size_t base = (size_t)VOFF + kvh * DH + t;
        for (int j = 0; j < SBS; j++)
            acc += pL[i * SBS + j] * qkv[(size_t)(w * SBS + j) * QKVC + base];
    }
    float g1 = gates[((size_t)s * HEADS + h) * 3 + 1];
    attn[(size_t)s * (HEADS * DH) + h * DH + t] += g1 * (acc * inv);
}

// ---------------- causal sliding window attention (window [s-512, s]) ----------------
__global__ __launch_bounds__(64) void sattn_kernel(
        const float* __restrict__ rq, const float* __restrict__ rk,
        const float* __restrict__ qkv, const float* __restrict__ gates,
        float* __restrict__ attn) {
    int h = blockIdx.x, s = blockIdx.y, t = threadIdx.x;
    int kvh = h >> 3;
    int jstart = (s - WIN > 0) ? (s - WIN) : 0;
    __shared__ float qL[DH];
    __shared__ float pL[9 * 64];
    qL[t] = rq[(size_t)s * (HEADS * DH) + h * DH + t];
    __syncthreads();
    float sc[9];
    #pragma unroll
    for (int c = 0; c < 9; c++) {
        int j = jstart + c * 64 + t;
        float scv = -INFINITY;
        if (j <= s) {
            const float4* kp = (const float4*)(rk + (size_t)j * (KVH * DH) + kvh * DH);
            const float4* q4 = (const float4*)qL;
            float acc = 0.f;
            #pragma unroll
            for (int d = 0; d < DH / 4; d++) {
                float4 a = q4[d], b = kp[d];
                acc += a.x * b.x + a.y * b.y + a.z * b.z + a.w * b.w;
            }
            scv = acc * SCALE;
        }
        sc[c] = scv;
    }
    float m = -INFINITY;
    #pragma unroll
    for (int c = 0; c < 9; c++) m = fmaxf(m, sc[c]);
    float M = wave_max(m);
    float zs = 0.f;
    #pragma unroll
    for (int c = 0; c < 9; c++) {
        float e = expf(sc[c] - M);
        zs += e;
        pL[c * 64 + t] = e;
    }
    float Z = wave_sum(zs);
    __syncthreads();
    float inv = 1.f / Z;
    float acc = 0.f;
    for (int c = 0; c < 9; c++) {
        int jbase = jstart + c * 64;
        if (jbase > s) break;
        for (int jj = 0; jj < 64; jj++) {
            int j = jbase + jj;
            if (j > s) break;
            acc += pL[c * 64 + jj] * qkv[(size_t)j * QKVC + VOFF + kvh * DH + t];
        }
    }
    float g2 = gates[((size_t)s * HEADS + h) * 3 + 2];
    attn[(size_t)s * (HEADS * DH) + h * DH + t] += g2 * (acc * inv);
}

// ---------------- launch ----------------
extern "C" void kernel_launch(void* const* d_in, const int* in_sizes, int n_in,
                              void* d_out, int out_size, void* d_ws, size_t ws_size,
                              hipStream_t stream) {
    const float* x      = (const float*)d_in[0];
    const float* rms_g  = (const float*)d_in[1];
    const float* W_qkv  = (const float*)d_in[2];
    const float* k_pos  = (const float*)d_in[3];
    const float* v_pos  = (const float*)d_in[4];
    const float* mem_kv = (const float*)d_in[5];
    const float* kW1    = (const float*)d_in[6];
    const float* kb1    = (const float*)d_in[7];
    const float* kW2    = (const float*)d_in[8];
    const float* kb2    = (const float*)d_in[9];
    const float* vW1    = (const float*)d_in[10];
    const float* vb1    = (const float*)d_in[11];
    const float* vW2    = (const float*)d_in[12];
    const float* vb2    = (const float*)d_in[13];
    const float* W_comb = (const float*)d_in[14];
    const float* b_comb = (const float*)d_in[15];
    const float* W_out  = (const float*)d_in[16];
    float* out = (float*)d_out;

    // workspace layout (floats)
    float* ws    = (float*)d_ws;
    float* xn    = ws;                          // 2048*1024
    float* qkv   = xn    + (size_t)S * DIM;     // 2048*1280
    float* rq    = qkv   + (size_t)S * QKVC;    // 2048*1024
    float* rk    = rq    + (size_t)S * HEADS * DH;  // 2048*128
    float* kcm   = rk    + (size_t)S * KVH * DH;    // 64*4096
    float* vcm   = kcm   + (size_t)KVH * NCB * CDIM;
    float* khid  = vcm   + (size_t)KVH * NCB * CDIM;
    float* vhid  = khid  + (size_t)KVH * NCB * CDIM;
    float* ckb   = vhid  + (size_t)KVH * NCB * CDIM;  // 64*64
    float* cvb   = ckb   + (size_t)KVH * NCB * DH;
    float* ck    = cvb   + (size_t)KVH * NCB * DH;    // 2*33*64
    float* cv    = ck    + (size_t)KVH * (NCB + 1) * DH;
    float* imp   = cv    + (size_t)KVH * (NCB + 1) * DH;  // 2*2048*32
    float* gates = imp   + (size_t)KVH * S * NCB;         // 2048*48
    float* attn  = gates + (size_t)S * HEADS * 3;         // 2048*1024
    int*   sel   = (int*)(attn + (size_t)S * HEADS * DH); // 2*2048*8 ints

    // 1. RMSNorm
    rmsnorm_kernel<<<S, 256, 0, stream>>>(x, rms_g, xn);
    // 2. QKV projection: (2048,1024)@(1024,1280)
    gemm_kernel<0><<<dim3((QKVC + 63) / 64, (S + 63) / 64), 256, 0, stream>>>(
        xn, W_qkv, nullptr, qkv, S, QKVC, DIM);
    // 3. rotary
    rotary_kernel<<<S, 256, 0, stream>>>(qkv, rq, rk);
    // 4. compress-MLP inputs
    build_cmat_kernel<<<KVH * NCB, 256, 0, stream>>>(qkv, k_pos, v_pos, kcm, vcm);
    // 5-8. compress MLPs (k and v): relu(X@W1+b1)@W2+b2
    gemm_kernel<1><<<dim3(CDIM / 64, 1), 256, 0, stream>>>(kcm, kW1, kb1, khid, KVH * NCB, CDIM, CDIM);
    gemm_kernel<0><<<dim3(1, 1), 256, 0, stream>>>(khid, kW2, kb2, ckb, KVH * NCB, DH, CDIM);
    gemm_kernel<1><<<dim3(CDIM / 64, 1), 256, 0, stream>>>(vcm, vW1, vb1, vhid, KVH * NCB, CDIM, CDIM);
    gemm_kernel<0><<<dim3(1, 1), 256, 0, stream>>>(vhid, vW2, vb2, cvb, KVH * NCB, DH, CDIM);
    // 9. assemble ck/cv with mem tokens
    assemble_kernel<<<(KVH * (NCB + 1) * DH + 255) / 256, 256, 0, stream>>>(ckb, cvb, mem_kv, ck, cv);
    // 10. gates = sigmoid(xn @ W_comb + b_comb)
    gemm_kernel<2><<<dim3(1, (S + 63) / 64), 256, 0, stream>>>(xn, W_comb, b_comb, gates, S, HEADS * 3, DIM);
    // 11. block importance
    imp_kernel<<<dim3(KVH, S), 64, 0, stream>>>(qkv, ck, imp);
    // 12. top-8 selection
    select_kernel<<<(KVH * S + 255) / 256, 256, 0, stream>>>(imp, sel);
    // 13. compressed attention (writes attn = g0*c_out)
    cattn_kernel<<<dim3(HEADS, S), 64, 0, stream>>>(qkv, ck, cv, gates, attn);
    // 14. fine attention (attn += g1*f_out)
    fattn_kernel<<<dim3(HEADS, S), 64, 0, stream>>>(rq, rk, qkv, sel, gates, attn);
    // 15. sliding window (attn += g2*s_out)
    sattn_kernel<<<dim3(HEADS, S), 64, 0, stream>>>(rq, rk, qkv, gates, attn);
    // 16. output projection
    gemm_kernel<0><<<dim3(DIM / 64, (S + 63) / 64), 256, 0, stream>>>(
        attn, W_out, nullptr, out, S, DIM, DIM);
}

// Round 2
// 1251.072 us; speedup vs baseline: 3.1975x; 3.1975x over previous
//
#include <hip/hip_runtime.h>
#include <hip/hip_bf16.h>
#include <cstddef>
#include <cstdint>

// Problem constants (B=1)
#define S      2048
#define DIM    1024
#define HEADS  16
#define KVH    2
#define GQ     8
#define DH     64
#define CBS    64
#define SBS    64
#define NUMSEL 8
#define WIN    512
#define NCB    (S / CBS)      // 32
#define CDIM   (CBS * DH)     // 4096
#define QKVC   (HEADS * DH + 2 * KVH * DH)   // 1280
#define KOFF   (HEADS * DH)                  // 1024 (k cols start)
#define VOFF   (HEADS * DH + KVH * DH)       // 1152 (v cols start)
#define SCALE  0.125f
#define RMS_EPS 1.1920928955078125e-07f

// ---------------- wave (64-lane) reductions ----------------
__device__ inline float wave_max(float v) {
    for (int o = 32; o > 0; o >>= 1) v = fmaxf(v, __shfl_xor(v, o));
    return v;
}
__device__ inline float wave_sum(float v) {
    for (int o = 32; o > 0; o >>= 1) v += __shfl_xor(v, o);
    return v;
}

// ---------------- RMSNorm ----------------
__global__ __launch_bounds__(256) void rmsnorm_kernel(
        const float* __restrict__ x, const float* __restrict__ g,
        float* __restrict__ xn) {
    int s = blockIdx.x, tid = threadIdx.x;
    const float4* row = (const float4*)(x + (size_t)s * DIM);
    float4 v = row[tid];
    float ss = v.x * v.x + v.y * v.y + v.z * v.z + v.w * v.w;
    ss = wave_sum(ss);
    __shared__ float red[4];
    if ((tid & 63) == 0) red[tid >> 6] = ss;
    __syncthreads();
    float tot = red[0] + red[1] + red[2] + red[3];
    float sc = rsqrtf(tot / (float)DIM + RMS_EPS);
    float4 gg = ((const float4*)g)[tid];
    float4 o;
    o.x = v.x * sc * gg.x; o.y = v.y * sc * gg.y;
    o.z = v.z * sc * gg.z; o.w = v.w * sc * gg.w;
    ((float4*)(xn + (size_t)s * DIM))[tid] = o;
}

// ---------------- generic tiled fp32 GEMM: C = act(A@B + bias) ----------------
template <int ACT>
__global__ __launch_bounds__(256) void gemm_kernel(
        const float* __restrict__ A, const float* __restrict__ B,
        const float* __restrict__ bias, float* __restrict__ C,
        int M, int N, int K) {
    const int BM = 64, BN = 64, BK = 16;
    __shared__ float As[BK][BM + 4];
    __shared__ float Bs[BK][BN];
    int bm = blockIdx.y * BM, bn = blockIdx.x * BN;
    int tid = threadIdx.x;
    int tx = tid & 15, ty = tid >> 4;
    float acc[4][4] = {{0.f}};
    for (int k0 = 0; k0 < K; k0 += BK) {
        #pragma unroll
        for (int e = 0; e < 4; e++) {
            int idx = tid + e * 256;
            int m = idx >> 4, kk = idx & 15;
            int gm = bm + m;
            As[kk][m] = (gm < M) ? A[(size_t)gm * K + k0 + kk] : 0.f;
        }
        #pragma unroll
        for (int e = 0; e < 4; e++) {
            int idx = tid + e * 256;
            int kk = idx >> 6, n = idx & 63;
            int gn = bn + n;
            Bs[kk][n] = (gn < N) ? B[(size_t)(k0 + kk) * N + gn] : 0.f;
        }
        __syncthreads();
        #pragma unroll
        for (int kk = 0; kk < BK; kk++) {
            float a[4], b[4];
            #pragma unroll
            for (int i = 0; i < 4; i++) a[i] = As[kk][ty * 4 + i];
            #pragma unroll
            for (int j = 0; j < 4; j++) b[j] = Bs[kk][tx * 4 + j];
            #pragma unroll
            for (int i = 0; i < 4; i++)
                #pragma unroll
                for (int j = 0; j < 4; j++) acc[i][j] += a[i] * b[j];
        }
        __syncthreads();
    }
    #pragma unroll
    for (int i = 0; i < 4; i++) {
        int gm = bm + ty * 4 + i;
        if (gm >= M) continue;
        #pragma unroll
        for (int j = 0; j < 4; j++) {
            int gn = bn + tx * 4 + j;
            if (gn >= N) continue;
            float v = acc[i][j];
            if (bias) v += bias[gn];
            if (ACT == 1) v = fmaxf(v, 0.f);
            if (ACT == 2) v = 1.f / (1.f + expf(-v));
            C[(size_t)gm * N + gn] = v;
        }
    }
}

// ---------------- split-K GEMM (partials, no bias/act) ----------------
__global__ __launch_bounds__(256) void gemm_splitk_kernel(
        const float* __restrict__ A, const float* __restrict__ B,
        float* __restrict__ P, int M, int N, int K, int kslice) {
    const int BM = 64, BN = 64, BK = 16;
    __shared__ float As[BK][BM + 4];
    __shared__ float Bs[BK][BN];
    int bm = blockIdx.y * BM, bn = blockIdx.x * BN;
    int z = blockIdx.z;
    int kbeg = z * kslice, kend = kbeg + kslice;
    int tid = threadIdx.x;
    int tx = tid & 15, ty = tid >> 4;
    float acc[4][4] = {{0.f}};
    for (int k0 = kbeg; k0 < kend; k0 += BK) {
        #pragma unroll
        for (int e = 0; e < 4; e++) {
            int idx = tid + e * 256;
            int m = idx >> 4, kk = idx & 15;
            int gm = bm + m;
            As[kk][m] = (gm < M) ? A[(size_t)gm * K + k0 + kk] : 0.f;
        }
        #pragma unroll
        for (int e = 0; e < 4; e++) {
            int idx = tid + e * 256;
            int kk = idx >> 6, n = idx & 63;
            int gn = bn + n;
            Bs[kk][n] = (gn < N) ? B[(size_t)(k0 + kk) * N + gn] : 0.f;
        }
        __syncthreads();
        #pragma unroll
        for (int kk = 0; kk < BK; kk++) {
            float a[4], b[4];
            #pragma unroll
            for (int i = 0; i < 4; i++) a[i] = As[kk][ty * 4 + i];
            #pragma unroll
            for (int j = 0; j < 4; j++) b[j] = Bs[kk][tx * 4 + j];
            #pragma unroll
            for (int i = 0; i < 4; i++)
                #pragma unroll
                for (int j = 0; j < 4; j++) acc[i][j] += a[i] * b[j];
        }
        __syncthreads();
    }
    #pragma unroll
    for (int i = 0; i < 4; i++) {
        int gm = bm + ty * 4 + i;
        if (gm >= M) continue;
        #pragma unroll
        for (int j = 0; j < 4; j++) {
            int gn = bn + tx * 4 + j;
            if (gn >= N) continue;
            P[((size_t)z * M + gm) * N + gn] = acc[i][j];
        }
    }
}

template <int ACT>
__global__ __launch_bounds__(256) void reduce_splitk_kernel(
        const float* __restrict__ P, const float* __restrict__ bias,
        float* __restrict__ C, int MN, int N, int splits) {
    int e = blockIdx.x * 256 + threadIdx.x;
    if (e >= MN) return;
    float s = 0.f;
    for (int z = 0; z < splits; z++) s += P[(size_t)z * MN + e];
    s += bias[e % N];
    if (ACT == 1) s = fmaxf(s, 0.f);
    C[e] = s;
}

// ---------------- rotary embedding (interleaved pairs, theta=10000) ----------------
__global__ __launch_bounds__(256) void rotary_kernel(
        const float* __restrict__ qkv, float* __restrict__ rq, float* __restrict__ rk) {
    int s = blockIdx.x, tid = threadIdx.x;
    for (int p = tid; p < (HEADS + KVH) * (DH / 2); p += 256) {
        int t; const float* src; float* dst;
        if (p < HEADS * (DH / 2)) {
            int h = p >> 5; t = p & 31;
            src = qkv + (size_t)s * QKVC + h * DH + 2 * t;
            dst = rq + (size_t)s * (HEADS * DH) + h * DH + 2 * t;
        } else {
            int pp = p - HEADS * (DH / 2);
            int h = pp >> 5; t = pp & 31;
            src = qkv + (size_t)s * QKVC + KOFF + h * DH + 2 * t;
            dst = rk + (size_t)s * (KVH * DH) + h * DH + 2 * t;
        }
        float u0 = src[0], u1 = src[1];
        float freq = powf(10000.f, -((float)(2 * t) / (float)DH));
        float ang = (float)s * freq;
        float sn, cs;
        sincosf(ang, &sn, &cs);
        dst[0] = u0 * cs - u1 * sn;
        dst[1] = u1 * cs + u0 * sn;
    }
}

// ---------------- build compress-MLP input matrices (64 rows x 4096) ----------------
__global__ __launch_bounds__(256) void build_cmat_kernel(
        const float* __restrict__ qkv, const float* __restrict__ k_pos,
        const float* __restrict__ v_pos, float* __restrict__ kcm, float* __restrict__ vcm) {
    int r = blockIdx.x;          // r = h*32 + w
    int h = r >> 5, w = r & 31;
    for (int e = threadIdx.x; e < CDIM; e += 256) {
        int i = e >> 6, d = e & 63;
        size_t qb = (size_t)(w * CBS + i) * QKVC;
        kcm[(size_t)r * CDIM + e] = qkv[qb + KOFF + h * DH + d] + k_pos[(h * CBS + i) * DH + d];
        vcm[(size_t)r * CDIM + e] = qkv[qb + VOFF + h * DH + d] + v_pos[(h * CBS + i) * DH + d];
    }
}

// ---------------- assemble ck/cv: prepend mem_kv -> (KVH, 33, DH) ----------------
__global__ __launch_bounds__(256) void assemble_kernel(
        const float* __restrict__ ckb, const float* __restrict__ cvb,
        const float* __restrict__ mem_kv, float* __restrict__ ck, float* __restrict__ cv) {
    int e = blockIdx.x * 256 + threadIdx.x;
    if (e >= KVH * (NCB + 1) * DH) return;
    int d = e & 63;
    int j = (e >> 6) % (NCB + 1);
    int h = e / ((NCB + 1) * DH);
    if (j == 0) {
        ck[e] = mem_kv[0 * KVH * DH + h * DH + d];
        cv[e] = mem_kv[1 * KVH * DH + h * DH + d];
    } else {
        ck[e] = ckb[((size_t)h * NCB + j - 1) * DH + d];
        cv[e] = cvb[((size_t)h * NCB + j - 1) * DH + d];
    }
}

// ---------------- block importance: imp[kvh][s][w] ----------------
__global__ __launch_bounds__(64) void imp_kernel(
        const float* __restrict__ qkv, const float* __restrict__ ck,
        float* __restrict__ imp) {
    int kvh = blockIdx.x, s = blockIdx.y, t = threadIdx.x;
    __shared__ float qg[GQ * DH];
    __shared__ float ckl[NCB * 65];
    for (int e = t; e < GQ * DH; e += 64) {
        int g = e >> 6, d = e & 63;
        qg[e] = qkv[(size_t)s * QKVC + (kvh * GQ + g) * DH + d];
    }
    for (int e = t; e < NCB * DH; e += 64) {
        int w = e >> 6, d = e & 63;
        ckl[w * 65 + d] = ck[((size_t)kvh * (NCB + 1) + 1 + w) * DH + d];
    }
    __syncthreads();
    if (t < NCB) {
        int w = t;
        float val;
        if (w * CBS + CBS - 1 < s) {
            float acc = 0.f;
            #pragma unroll
            for (int g = 0; g < GQ; g++) {
                const float* qp = qg + g * DH;
                const float* cp = ckl + w * 65;
                #pragma unroll 16
                for (int d = 0; d < DH; d++) acc += qp[d] * cp[d];
            }
            val = acc * SCALE * (1.f / (float)GQ);
        } else {
            val = -INFINITY;
        }
        imp[((size_t)kvh * S + s) * NCB + w] = val;
    }
}

// ---------------- top-8 selection (replicates lax.top_k stable ties) ----------------
__global__ __launch_bounds__(256) void select_kernel(
        const float* __restrict__ imp, int* __restrict__ sel) {
    int idx = blockIdx.x * 256 + threadIdx.x;
    if (idx >= KVH * S) return;
    const float* row = imp + (size_t)idx * NCB;
    float p[NCB];
    float m = -1000.f;
    for (int w = 0; w < NCB; w++) { p[w] = row[w]; m = fmaxf(m, p[w]); }
    float z = expf(-1000.f - m);
    for (int w = 0; w < NCB; w++) { p[w] = expf(p[w] - m); z += p[w]; }
    float inv = 1.f / z;
    bool used[NCB];
    for (int w = 0; w < NCB; w++) used[w] = false;
    for (int i = 0; i < NUMSEL; i++) {
        int best = 0; float bv = -1.f;
        for (int w = 0; w < NCB; w++) {
            if (!used[w]) {
                float pw = p[w] * inv;
                if (pw > bv) { bv = pw; best = w; }
            }
        }
        used[best] = true;
        sel[(size_t)idx * NUMSEL + i] = (bv > 1e-10f) ? best : -1;
    }
}

// ---------------- compressed attention, tiled: 64 queries x 1 head per block ----------------
__global__ __launch_bounds__(256) void cattn_kernel(
        const float* __restrict__ qkv, const float* __restrict__ ck,
        const float* __restrict__ cv, const float* __restrict__ gates,
        float* __restrict__ attn) {
    int h = blockIdx.x, qb = blockIdx.y;
    int kvh = h >> 3;
    int tid = threadIdx.x;
    int tx = tid & 15, ty = tid >> 4;
    __shared__ float Qs[64][68];   // [d][q]
    __shared__ float Ks[64][68];   // [d][j]; aliased by Ps[j][q] after scores
    __shared__ float Vs[64][68];   // [j][d]
    auto& Ps = Ks;
    for (int e = tid; e < 4096; e += 256) {
        int q = e >> 6, d = e & 63;
        Qs[d][q] = qkv[(size_t)(qb * 64 + q) * QKVC + h * DH + d];
    }
    for (int e = tid; e < 4096; e += 256) {
        int j = e >> 6, d = e & 63;
        float kvl = 0.f, vvl = 0.f;
        if (j < NCB + 1) {
            kvl = ck[((size_t)kvh * (NCB + 1) + j) * DH + d];
            vvl = cv[((size_t)kvh * (NCB + 1) + j) * DH + d];
        }
        Ks[d][j] = kvl;
        Vs[j][d] = vvl;
    }
    __syncthreads();
    float sc[4][4] = {{0.f}};
    for (int d = 0; d < 64; d++) {
        float4 av = *(const float4*)&Qs[d][ty * 4];
        float4 bv = *(const float4*)&Ks[d][tx * 4];
        float a[4] = {av.x, av.y, av.z, av.w};
        float b[4] = {bv.x, bv.y, bv.z, bv.w};
        #pragma unroll
        for (int i = 0; i < 4; i++)
            #pragma unroll
            for (int j = 0; j < 4; j++) sc[i][j] += a[i] * b[j];
    }
    __syncthreads();   // Ks reads done; Ps may overwrite
    float l[4];
    float pv4[4][4];
    #pragma unroll
    for (int i = 0; i < 4; i++) {
        int spos = qb * 64 + ty * 4 + i;
        float tm = -INFINITY;
        #pragma unroll
        for (int j = 0; j < 4; j++) {
            int jj = tx * 4 + j;
            bool vis = (jj == 0) || ((jj <= NCB) && (jj * 64 <= spos));
            sc[i][j] = vis ? sc[i][j] * SCALE : -INFINITY;
            tm = fmaxf(tm, sc[i][j]);
        }
        #pragma unroll
        for (int o = 1; o < 16; o <<= 1) tm = fmaxf(tm, __shfl_xor(tm, o));
        float rs = 0.f;
        #pragma unroll
        for (int j = 0; j < 4; j++) {
            float p = expf(sc[i][j] - tm);   // tm finite: jj==0 always visible
            pv4[i][j] = p;
            rs += p;
        }
        #pragma unroll
        for (int o = 1; o < 16; o <<= 1) rs += __shfl_xor(rs, o);
        l[i] = rs;
    }
    #pragma unroll
    for (int j = 0; j < 4; j++) {
        float4 w = make_float4(pv4[0][j], pv4[1][j], pv4[2][j], pv4[3][j]);
        *(float4*)&Ps[tx * 4 + j][ty * 4] = w;
    }
    __syncthreads();
    float acc[4][4] = {{0.f}};
    for (int jj = 0; jj < 64; jj++) {
        float4 av = *(const float4*)&Ps[jj][ty * 4];
        float4 bv = *(const float4*)&Vs[jj][tx * 4];
        float a[4] = {av.x, av.y, av.z, av.w};
        float b[4] = {bv.x, bv.y, bv.z, bv.w};
        #pragma unroll
        for (int i = 0; i < 4; i++)
            #pragma unroll
            for (int j = 0; j < 4; j++) acc[i][j] += a[i] * b[j];
    }
    #pragma unroll
    for (int i = 0; i < 4; i++) {
        int spos = qb * 64 + ty * 4 + i;
        float g0 = gates[((size_t)spos * HEADS + h) * 3 + 0];
        float sca = g0 / l[i];
        #pragma unroll
        for (int j = 0; j < 4; j++)
            attn[(size_t)spos * (HEADS * DH) + h * DH + tx * 4 + j] = acc[i][j] * sca;
    }
}

// ---------------- fine attention: one block per (kvh, s); 8 grouped heads share K/V ----------------
__global__ __launch_bounds__(256) void fattn_kernel(
        const float* __restrict__ rq, const float* __restrict__ rk,
        const float* __restrict__ qkv, const int* __restrict__ sel,
        const float* __restrict__ gates, float* __restrict__ attn) {
    int kvh = blockIdx.x, s = blockIdx.y;
    int tid = threadIdx.x;
    int h = tid >> 5;                 // 0..7 within group
    int lk = tid & 31;
    __shared__ float Qs[8][64];
    __shared__ float KV[64][68];      // phase1: [d][j] (K), phase3: [j][d] (V)
    __shared__ float Ps[8][584];      // scores -> probs
    __shared__ int bl[9];
    for (int e = tid; e < 512; e += 256) {
        int hh = e >> 6, d = e & 63;
        Qs[hh][d] = rq[(size_t)s * (HEADS * DH) + (kvh * 8 + hh) * DH + d];
    }
    if (tid < NUMSEL) bl[tid] = sel[((size_t)kvh * S + s) * NUMSEL + tid];
    if (tid == NUMSEL) bl[NUMSEL] = s >> 6;
    __syncthreads();
    // phase 1: scores for all 9 slots
    for (int i = 0; i < 9; i++) {
        int w = bl[i];
        bool bok = (i < NUMSEL) ? (w >= 0) : true;
        if (bok) {
            for (int e = tid; e < 4096; e += 256) {
                int j = e >> 6, d = e & 63;
                KV[d][j] = rk[(size_t)(w * SBS + j) * (KVH * DH) + kvh * DH + d];
            }
        }
        __syncthreads();
        #pragma unroll
        for (int t2 = 0; t2 < 2; t2++) {
            int jj = lk + t2 * 32;
            float scv = -INFINITY;
            bool vis = bok && ((i < NUMSEL) || (jj <= (s & 63)));
            if (vis) {
                float acc = 0.f;
                #pragma unroll 16
                for (int d = 0; d < 64; d++) acc += Qs[h][d] * KV[d][jj];
                scv = acc * SCALE;
            }
            Ps[h][i * 64 + jj] = scv;
        }
        __syncthreads();
    }
    // phase 2: softmax over 576 per head (32 lanes per head)
    float m = -INFINITY;
    for (int e = lk; e < 576; e += 32) m = fmaxf(m, Ps[h][e]);
    #pragma unroll
    for (int o = 1; o < 32; o <<= 1) m = fmaxf(m, __shfl_xor(m, o));
    float l = 0.f;
    for (int e = lk; e < 576; e += 32) {
        float p = expf(Ps[h][e] - m);     // m finite (diag jj = s&63 visible)
        Ps[h][e] = p;
        l += p;
    }
    #pragma unroll
    for (int o = 1; o < 32; o <<= 1) l += __shfl_xor(l, o);
    float invl = 1.f / l;
    __syncthreads();
    // phase 3: PV
    float a0 = 0.f, a1 = 0.f;
    int d0 = lk * 2;
    for (int i = 0; i < 9; i++) {
        int w = bl[i];
        if (i < NUMSEL && w < 0) continue;
        __syncthreads();
        for (int e = tid; e < 4096; e += 256) {
            int j = e >> 6, d = e & 63;
            KV[j][d] = qkv[(size_t)(w * SBS + j) * QKVC + VOFF + kvh * DH + d];
        }
        __syncthreads();
        #pragma unroll 8
        for (int j = 0; j < 64; j++) {
            float p = Ps[h][i * 64 + j];
            a0 += p * KV[j][d0];
            a1 += p * KV[j][d0 + 1];
        }
    }
    float g1 = gates[((size_t)s * HEADS + (kvh * 8 + h)) * 3 + 1];
    size_t ob = (size_t)s * (HEADS * DH) + (kvh * 8 + h) * DH;
    attn[ob + d0]     += g1 * a0 * invl;
    attn[ob + d0 + 1] += g1 * a1 * invl;
}

// ---------------- sliding window, tiled flash-style: 64 queries x 1 head per block ----------------
__global__ __launch_bounds__(256) void sattn_kernel(
        const float* __restrict__ rq, const float* __restrict__ rk,
        const float* __restrict__ qkv, const float* __restrict__ gates,
        float* __restrict__ attn) {
    int h = blockIdx.x, qb = blockIdx.y;
    int kvh = h >> 3;
    int tid = threadIdx.x;
    int tx = tid & 15, ty = tid >> 4;
    __shared__ float Qs[64][68];   // [d][q]
    __shared__ float Ks[64][68];   // [d][j]; aliased by Ps[j][q]
    __shared__ float Vs[64][68];   // [j][d]
    auto& Ps = Ks;
    for (int e = tid; e < 4096; e += 256) {
        int q = e >> 6, d = e & 63;
        Qs[d][q] = rq[(size_t)(qb * 64 + q) * (HEADS * DH) + h * DH + d];
    }
    float m[4], l[4], acc[4][4];
    #pragma unroll
    for (int i = 0; i < 4; i++) {
        m[i] = -INFINITY; l[i] = 0.f;
        #pragma unroll
        for (int j = 0; j < 4; j++) acc[i][j] = 0.f;
    }
    __syncthreads();
    for (int c = 0; c < 9; c++) {
        int kb = qb * 64 - WIN + c * 64;
        if (kb + 63 < 0) continue;
        for (int e = tid; e < 4096; e += 256) {
            int j = e >> 6, d = e & 63;
            int jpos = kb + j;
            float kvl = 0.f, vvl = 0.f;
            if (jpos >= 0) {
                kvl = rk[(size_t)jpos * (KVH * DH) + kvh * DH + d];
                vvl = qkv[(size_t)jpos * QKVC + VOFF + kvh * DH + d];
            }
            Ks[d][j] = kvl;
            Vs[j][d] = vvl;
        }
        __syncthreads();
        float sc[4][4] = {{0.f}};
        for (int d = 0; d < 64; d++) {
            float4 av = *(const float4*)&Qs[d][ty * 4];
            float4 bv = *(const float4*)&Ks[d][tx * 4];
            float a[4] = {av.x, av.y, av.z, av.w};
            float b[4] = {bv.x, bv.y, bv.z, bv.w};
            #pragma unroll
            for (int i = 0; i < 4; i++)
                #pragma unroll
                for (int j = 0; j < 4; j++) sc[i][j] += a[i] * b[j];
        }
        __syncthreads();   // Ks reads done; Ps overwrite OK
        float pv4[4][4];
        #pragma unroll
        for (int i = 0; i < 4; i++) {
            int spos = qb * 64 + ty * 4 + i;
            float tm = -INFINITY;
            #pragma unroll
            for (int j = 0; j < 4; j++) {
                int jpos = kb + tx * 4 + j;
                bool valid = (jpos >= 0) && (jpos <= spos) && (jpos >= spos - WIN);
                sc[i][j] = valid ? sc[i][j] * SCALE : -INFINITY;
                tm = fmaxf(tm, sc[i][j]);
            }
            #pragma unroll
            for (int o = 1; o < 16; o <<= 1) tm = fmaxf(tm, __shfl_xor(tm, o));
            float mn = fmaxf(m[i], tm);
            float sca = (mn == -INFINITY) ? 1.f : expf(m[i] - mn);
            float rs = 0.f;
            #pragma unroll
            for (int j = 0; j < 4; j++) {
                float p = (mn == -INFINITY) ? 0.f : expf(sc[i][j] - mn);
                pv4[i][j] = p;
                rs += p;
            }
            #pragma unroll
            for (int o = 1; o < 16; o <<= 1) rs += __shfl_xor(rs, o);
            l[i] = l[i] * sca + rs;
            m[i] = mn;
            #pragma unroll
            for (int j = 0; j < 4; j++) acc[i][j] *= sca;
        }
        #pragma unroll
        for (int j = 0; j < 4; j++) {
            float4 w = make_float4(pv4[0][j], pv4[1][j], pv4[2][j], pv4[3][j]);
            *(float4*)&Ps[tx * 4 + j][ty * 4] = w;
        }
        __syncthreads();
        for (int jj = 0; jj < 64; jj++) {
            float4 av = *(const float4*)&Ps[jj][ty * 4];
            float4 bv = *(const float4*)&Vs[jj][tx * 4];
            float a[4] = {av.x, av.y, av.z, av.w};
            float b[4] = {bv.x, bv.y, bv.z, bv.w};
            #pragma unroll
            for (int i = 0; i < 4; i++)
                #pragma unroll
                for (int j = 0; j < 4; j++) acc[i][j] += a[i] * b[j];
        }
        __syncthreads();
    }
    #pragma unroll
    for (int i = 0; i < 4; i++) {
        int spos = qb * 64 + ty * 4 + i;
        float g2 = gates[((size_t)spos * HEADS + h) * 3 + 2];
        float sca = g2 / l[i];
        #pragma unroll
        for (int j = 0; j < 4; j++)
            attn[(size_t)spos * (HEADS * DH) + h * DH + tx * 4 + j] += acc[i][j] * sca;
    }
}

// ---------------- launch ----------------
extern "C" void kernel_launch(void* const* d_in, const int* in_sizes, int n_in,
                              void* d_out, int out_size, void* d_ws, size_t ws_size,
                              hipStream_t stream) {
    const float* x      = (const float*)d_in[0];
    const float* rms_g  = (const float*)d_in[1];
    const float* W_qkv  = (const float*)d_in[2];
    const float* k_pos  = (const float*)d_in[3];
    const float* v_pos  = (const float*)d_in[4];
    const float* mem_kv = (const float*)d_in[5];
    const float* kW1    = (const float*)d_in[6];
    const float* kb1    = (const float*)d_in[7];
    const float* kW2    = (const float*)d_in[8];
    const float* kb2    = (const float*)d_in[9];
    const float* vW1    = (const float*)d_in[10];
    const float* vb1    = (const float*)d_in[11];
    const float* vW2    = (const float*)d_in[12];
    const float* vb2    = (const float*)d_in[13];
    const float* W_comb = (const float*)d_in[14];
    const float* b_comb = (const float*)d_in[15];
    const float* W_out  = (const float*)d_in[16];
    float* out = (float*)d_out;

    // workspace layout (floats)
    float* ws    = (float*)d_ws;
    float* xn    = ws;                          // 2048*1024
    float* qkv   = xn    + (size_t)S * DIM;     // 2048*1280
    float* rq    = qkv   + (size_t)S * QKVC;    // 2048*1024
    float* rk    = rq    + (size_t)S * HEADS * DH;  // 2048*128
    float* kcm   = rk    + (size_t)S * KVH * DH;    // 64*4096
    float* vcm   = kcm   + (size_t)KVH * NCB * CDIM;
    float* khid  = vcm   + (size_t)KVH * NCB * CDIM;
    float* vhid  = khid  + (size_t)KVH * NCB * CDIM;
    float* ckb   = vhid  + (size_t)KVH * NCB * CDIM;  // 64*64
    float* cvb   = ckb   + (size_t)KVH * NCB * DH;
    float* ck    = cvb   + (size_t)KVH * NCB * DH;    // 2*33*64
    float* cv    = ck    + (size_t)KVH * (NCB + 1) * DH;
    float* imp   = cv    + (size_t)KVH * (NCB + 1) * DH;  // 2*2048*32 = 131072
    float* gates = imp   + (size_t)KVH * S * NCB;         // 2048*48
    float* attn  = gates + (size_t)S * HEADS * 3;         // 2048*1024 = 2097152
    int*   sel   = (int*)(attn + (size_t)S * HEADS * DH); // 2*2048*8 ints
    // split-K partial buffers (reused before their real consumers):
    float* partW1 = attn;   // 8 * 64 * 4096 = 2097152 floats (exact fit)
    float* partW2 = imp;    // 32 * 64 * 64 = 131072 floats (exact fit)

    // 1. RMSNorm
    rmsnorm_kernel<<<S, 256, 0, stream>>>(x, rms_g, xn);
    // 2. QKV projection: (2048,1024)@(1024,1280)
    gemm_kernel<0><<<dim3((QKVC + 63) / 64, (S + 63) / 64), 256, 0, stream>>>(
        xn, W_qkv, nullptr, qkv, S, QKVC, DIM);
    // 3. rotary
    rotary_kernel<<<S, 256, 0, stream>>>(qkv, rq, rk);
    // 4. compress-MLP inputs
    build_cmat_kernel<<<KVH * NCB, 256, 0, stream>>>(qkv, k_pos, v_pos, kcm, vcm);
    // 5. k-MLP: relu(kcm@kW1+kb1) -> khid (split-K 8)
    gemm_splitk_kernel<<<dim3(CDIM / 64, 1, 8), 256, 0, stream>>>(kcm, kW1, partW1, 64, CDIM, CDIM, CDIM / 8);
    reduce_splitk_kernel<1><<<(64 * CDIM + 255) / 256, 256, 0, stream>>>(partW1, kb1, khid, 64 * CDIM, CDIM, 8);
    // 6. khid@kW2+kb2 -> ckb (split-K 32)
    gemm_splitk_kernel<<<dim3(1, 1, 32), 256, 0, stream>>>(khid, kW2, partW2, 64, DH, CDIM, CDIM / 32);
    reduce_splitk_kernel<0><<<(64 * DH + 255) / 256, 256, 0, stream>>>(partW2, kb2, ckb, 64 * DH, DH, 32);
    // 7. v-MLP
    gemm_splitk_kernel<<<dim3(CDIM / 64, 1, 8), 256, 0, stream>>>(vcm, vW1, partW1, 64, CDIM, CDIM, CDIM / 8);
    reduce_splitk_kernel<1><<<(64 * CDIM + 255) / 256, 256, 0, stream>>>(partW1, vb1, vhid, 64 * CDIM, CDIM, 8);
    gemm_splitk_kernel<<<dim3(1, 1, 32), 256, 0, stream>>>(vhid, vW2, partW2, 64, DH, CDIM, CDIM / 32);
    reduce_splitk_kernel<0><<<(64 * DH + 255) / 256, 256, 0, stream>>>(partW2, vb2, cvb, 64 * DH, DH, 32);
    // 8. assemble ck/cv with mem tokens
    assemble_kernel<<<(KVH * (NCB + 1) * DH + 255) / 256, 256, 0, stream>>>(ckb, cvb, mem_kv, ck, cv);
    // 9. gates = sigmoid(xn @ W_comb + b_comb)
    gemm_kernel<2><<<dim3(1, (S + 63) / 64), 256, 0, stream>>>(xn, W_comb, b_comb, gates, S, HEADS * 3, DIM);
    // 10. block importance (imp buffer free again after step 7)
    imp_kernel<<<dim3(KVH, S), 64, 0, stream>>>(qkv, ck, imp);
    // 11. top-8 selection
    select_kernel<<<(KVH * S + 255) / 256, 256, 0, stream>>>(imp, sel);
    // 12. compressed attention (writes attn = g0*c_out; attn buffer free after step 7)
    cattn_kernel<<<dim3(HEADS, S / 64), 256, 0, stream>>>(qkv, ck, cv, gates, attn);
    // 13. fine attention (attn += g1*f_out)
    fattn_kernel<<<dim3(KVH, S), 256, 0, stream>>>(rq, rk, qkv, sel, gates, attn);
    // 14. sliding window (attn += g2*s_out)
    sattn_kernel<<<dim3(HEADS, S / 64), 256, 0, stream>>>(rq, rk, qkv, gates, attn);
    // 15. output projection
    gemm_kernel<0><<<dim3(DIM / 64, (S + 63) / 64), 256, 0, stream>>>(
        attn, W_out, nullptr, out, S, DIM, DIM);
}

// Round 4
// 1096.626 us; speedup vs baseline: 3.6478x; 1.1408x over previous
//
#include <hip/hip_runtime.h>
#include <hip/hip_bf16.h>
#include <cstddef>
#include <cstdint>

// Problem constants (B=1)
#define S      2048
#define DIM    1024
#define HEADS  16
#define KVH    2
#define GQ     8
#define DH     64
#define CBS    64
#define SBS    64
#define NUMSEL 8
#define WIN    512
#define NCB    (S / CBS)      // 32
#define CDIM   (CBS * DH)     // 4096
#define QKVC   (HEADS * DH + 2 * KVH * DH)   // 1280
#define KOFF   (HEADS * DH)                  // 1024 (k cols start)
#define VOFF   (HEADS * DH + KVH * DH)       // 1152 (v cols start)
#define SCALE  0.125f
#define RMS_EPS 1.1920928955078125e-07f

typedef __attribute__((ext_vector_type(8))) short bf16x8;   // 8 bf16 in 4 VGPRs
typedef __attribute__((ext_vector_type(4))) float f32x4;

// ---------------- wave (64-lane) reductions ----------------
__device__ inline float wave_sum(float v) {
    for (int o = 32; o > 0; o >>= 1) v += __shfl_xor(v, o);
    return v;
}

// ---------------- RMSNorm (writes fp32 + bf16 copies) ----------------
__global__ __launch_bounds__(256) void rmsnorm_kernel(
        const float* __restrict__ x, const float* __restrict__ g,
        float* __restrict__ xn, __hip_bfloat16* __restrict__ xnb) {
    int s = blockIdx.x, tid = threadIdx.x;
    const float4* row = (const float4*)(x + (size_t)s * DIM);
    float4 v = row[tid];
    float ss = v.x * v.x + v.y * v.y + v.z * v.z + v.w * v.w;
    ss = wave_sum(ss);
    __shared__ float red[4];
    if ((tid & 63) == 0) red[tid >> 6] = ss;
    __syncthreads();
    float tot = red[0] + red[1] + red[2] + red[3];
    float sc = rsqrtf(tot / (float)DIM + RMS_EPS);
    float4 gg = ((const float4*)g)[tid];
    float4 o;
    o.x = v.x * sc * gg.x; o.y = v.y * sc * gg.y;
    o.z = v.z * sc * gg.z; o.w = v.w * sc * gg.w;
    ((float4*)(xn + (size_t)s * DIM))[tid] = o;
    size_t b = (size_t)s * DIM + tid * 4;
    xnb[b + 0] = __float2bfloat16(o.x);
    xnb[b + 1] = __float2bfloat16(o.y);
    xnb[b + 2] = __float2bfloat16(o.z);
    xnb[b + 3] = __float2bfloat16(o.w);
}

// ---------------- fp32 -> bf16 cast ----------------
__global__ __launch_bounds__(256) void cast_bf16_kernel(
        const float* __restrict__ in, __hip_bfloat16* __restrict__ out, int n4) {
    int e = blockIdx.x * 256 + threadIdx.x;
    if (e >= n4) return;
    float4 v = ((const float4*)in)[e];
    out[4 * e + 0] = __float2bfloat16(v.x);
    out[4 * e + 1] = __float2bfloat16(v.y);
    out[4 * e + 2] = __float2bfloat16(v.z);
    out[4 * e + 3] = __float2bfloat16(v.w);
}

// ---------------- bf16 MFMA GEMM: C = A(bf16,MxK) @ B(fp32,KxN) [+bias] ----------------
// B cast to bf16 during LDS staging (stored [n][k]). Split-K via blockIdx.z
// (writes fp32 partials at C + z*M*N; pass bias=nullptr for split runs).
// Requires M % BM == 0, N % BN == 0, kslice % 32 == 0.
template <int BM, int BN, int WM, int WN>
__global__ __launch_bounds__(256) void gemm_mfma_kernel(
        const __hip_bfloat16* __restrict__ A, const float* __restrict__ B,
        const float* __restrict__ bias, float* __restrict__ C,
        int M, int N, int K, int kslice) {
    constexpr int BK = 32;
    constexpr int TM = BM / (WM * 16);
    constexpr int TN = BN / (WN * 16);
    constexpr int LDK = BK + 8;   // pad: stride 40 bf16 = 20 dwords (2-way free)
    __shared__ __hip_bfloat16 As[BM][LDK];
    __shared__ __hip_bfloat16 Bs[BN][LDK];
    int tid = threadIdx.x;
    int wave = tid >> 6, lane = tid & 63;
    int wm = wave % WM, wn = wave / WM;
    int m0 = wm * TM * 16, n0 = wn * TN * 16;
    int bm = blockIdx.y * BM, bn = blockIdx.x * BN;
    int kbeg = blockIdx.z * kslice, kend = kbeg + kslice;
    int lm = lane & 15, quad = lane >> 4;
    f32x4 acc[TM][TN] = {};
    for (int k0 = kbeg; k0 < kend; k0 += BK) {
        #pragma unroll
        for (int e = 0; e < BM * BK / (256 * 8); e++) {
            int idx = (tid + e * 256) * 8;
            int r = idx >> 5, kk = idx & 31;
            *(bf16x8*)(&As[r][kk]) =
                *(const bf16x8*)(A + (size_t)(bm + r) * K + k0 + kk);
        }
        #pragma unroll
        for (int e = 0; e < BN * BK / 256; e++) {
            int idx = tid + e * 256;
            int kk = idx / BN, n = idx % BN;
            Bs[n][kk] = __float2bfloat16(B[(size_t)(k0 + kk) * N + bn + n]);
        }
        __syncthreads();
        bf16x8 af[TM], bf_[TN];
        #pragma unroll
        for (int i = 0; i < TM; i++)
            af[i] = *(const bf16x8*)(&As[m0 + i * 16 + lm][quad * 8]);
        #pragma unroll
        for (int j = 0; j < TN; j++)
            bf_[j] = *(const bf16x8*)(&Bs[n0 + j * 16 + lm][quad * 8]);
        #pragma unroll
        for (int i = 0; i < TM; i++)
            #pragma unroll
            for (int j = 0; j < TN; j++)
                acc[i][j] = __builtin_amdgcn_mfma_f32_16x16x32_bf16(
                    af[i], bf_[j], acc[i][j], 0, 0, 0);
        __syncthreads();
    }
    size_t cbase = (size_t)blockIdx.z * M * N;
    #pragma unroll
    for (int i = 0; i < TM; i++) {
        #pragma unroll
        for (int j = 0; j < TN; j++) {
            int gn = bn + n0 + j * 16 + lm;
            #pragma unroll
            for (int r = 0; r < 4; r++) {
                int gm = bm + m0 + i * 16 + quad * 4 + r;
                float v = acc[i][j][r];
                if (bias) v += bias[gn];
                C[cbase + (size_t)gm * N + gn] = v;
            }
        }
    }
}

// ---------------- generic tiled fp32 GEMM: C = act(A@B + bias) ----------------
template <int ACT>
__global__ __launch_bounds__(256) void gemm_kernel(
        const float* __restrict__ A, const float* __restrict__ B,
        const float* __restrict__ bias, float* __restrict__ C,
        int M, int N, int K) {
    const int BM = 64, BN = 64, BK = 16;
    __shared__ float As[BK][BM + 4];
    __shared__ float Bs[BK][BN];
    int bm = blockIdx.y * BM, bn = blockIdx.x * BN;
    int tid = threadIdx.x;
    int tx = tid & 15, ty = tid >> 4;
    float acc[4][4] = {{0.f}};
    for (int k0 = 0; k0 < K; k0 += BK) {
        #pragma unroll
        for (int e = 0; e < 4; e++) {
            int idx = tid + e * 256;
            int m = idx >> 4, kk = idx & 15;
            int gm = bm + m;
            As[kk][m] = (gm < M) ? A[(size_t)gm * K + k0 + kk] : 0.f;
        }
        #pragma unroll
        for (int e = 0; e < 4; e++) {
            int idx = tid + e * 256;
            int kk = idx >> 6, n = idx & 63;
            int gn = bn + n;
            Bs[kk][n] = (gn < N) ? B[(size_t)(k0 + kk) * N + gn] : 0.f;
        }
        __syncthreads();
        #pragma unroll
        for (int kk = 0; kk < BK; kk++) {
            float a[4], b[4];
            #pragma unroll
            for (int i = 0; i < 4; i++) a[i] = As[kk][ty * 4 + i];
            #pragma unroll
            for (int j = 0; j < 4; j++) b[j] = Bs[kk][tx * 4 + j];
            #pragma unroll
            for (int i = 0; i < 4; i++)
                #pragma unroll
                for (int j = 0; j < 4; j++) acc[i][j] += a[i] * b[j];
        }
        __syncthreads();
    }
    #pragma unroll
    for (int i = 0; i < 4; i++) {
        int gm = bm + ty * 4 + i;
        if (gm >= M) continue;
        #pragma unroll
        for (int j = 0; j < 4; j++) {
            int gn = bn + tx * 4 + j;
            if (gn >= N) continue;
            float v = acc[i][j];
            if (bias) v += bias[gn];
            if (ACT == 1) v = fmaxf(v, 0.f);
            if (ACT == 2) v = 1.f / (1.f + expf(-v));
            C[(size_t)gm * N + gn] = v;
        }
    }
}

// ---------------- split-K fp32 GEMM (partials) — for the tiny W2 matmuls ----------------
__global__ __launch_bounds__(256) void gemm_splitk_kernel(
        const float* __restrict__ A, const float* __restrict__ B,
        float* __restrict__ P, int M, int N, int K, int kslice) {
    const int BM = 64, BN = 64, BK = 16;
    __shared__ float As[BK][BM + 4];
    __shared__ float Bs[BK][BN];
    int bm = blockIdx.y * BM, bn = blockIdx.x * BN;
    int z = blockIdx.z;
    int kbeg = z * kslice, kend = kbeg + kslice;
    int tid = threadIdx.x;
    int tx = tid & 15, ty = tid >> 4;
    float acc[4][4] = {{0.f}};
    for (int k0 = kbeg; k0 < kend; k0 += BK) {
        #pragma unroll
        for (int e = 0; e < 4; e++) {
            int idx = tid + e * 256;
            int m = idx >> 4, kk = idx & 15;
            int gm = bm + m;
            As[kk][m] = (gm < M) ? A[(size_t)gm * K + k0 + kk] : 0.f;
        }
        #pragma unroll
        for (int e = 0; e < 4; e++) {
            int idx = tid + e * 256;
            int kk = idx >> 6, n = idx & 63;
            int gn = bn + n;
            Bs[kk][n] = (gn < N) ? B[(size_t)(k0 + kk) * N + gn] : 0.f;
        }
        __syncthreads();
        #pragma unroll
        for (int kk = 0; kk < BK; kk++) {
            float a[4], b[4];
            #pragma unroll
            for (int i = 0; i < 4; i++) a[i] = As[kk][ty * 4 + i];
            #pragma unroll
            for (int j = 0; j < 4; j++) b[j] = Bs[kk][tx * 4 + j];
            #pragma unroll
            for (int i = 0; i < 4; i++)
                #pragma unroll
                for (int j = 0; j < 4; j++) acc[i][j] += a[i] * b[j];
        }
        __syncthreads();
    }
    #pragma unroll
    for (int i = 0; i < 4; i++) {
        int gm = bm + ty * 4 + i;
        if (gm >= M) continue;
        #pragma unroll
        for (int j = 0; j < 4; j++) {
            int gn = bn + tx * 4 + j;
            if (gn >= N) continue;
            P[((size_t)z * M + gm) * N + gn] = acc[i][j];
        }
    }
}

template <int ACT>
__global__ __launch_bounds__(256) void reduce_splitk_kernel(
        const float* __restrict__ P, const float* __restrict__ bias,
        float* __restrict__ C, int MN, int N, int splits) {
    int e = blockIdx.x * 256 + threadIdx.x;
    if (e >= MN) return;
    float s = 0.f;
    for (int z = 0; z < splits; z++) s += P[(size_t)z * MN + e];
    s += bias[e % N];
    if (ACT == 1) s = fmaxf(s, 0.f);
    C[e] = s;
}

// ---------------- rotary embedding (interleaved pairs, theta=10000) ----------------
__global__ __launch_bounds__(256) void rotary_kernel(
        const float* __restrict__ qkv, float* __restrict__ rq, float* __restrict__ rk) {
    int s = blockIdx.x, tid = threadIdx.x;
    for (int p = tid; p < (HEADS + KVH) * (DH / 2); p += 256) {
        int t; const float* src; float* dst;
        if (p < HEADS * (DH / 2)) {
            int h = p >> 5; t = p & 31;
            src = qkv + (size_t)s * QKVC + h * DH + 2 * t;
            dst = rq + (size_t)s * (HEADS * DH) + h * DH + 2 * t;
        } else {
            int pp = p - HEADS * (DH / 2);
            int h = pp >> 5; t = pp & 31;
            src = qkv + (size_t)s * QKVC + KOFF + h * DH + 2 * t;
            dst = rk + (size_t)s * (KVH * DH) + h * DH + 2 * t;
        }
        float u0 = src[0], u1 = src[1];
        float freq = powf(10000.f, -((float)(2 * t) / (float)DH));
        float ang = (float)s * freq;
        float sn, cs;
        sincosf(ang, &sn, &cs);
        dst[0] = u0 * cs - u1 * sn;
        dst[1] = u1 * cs + u0 * sn;
    }
}

// ---------------- build compress-MLP input matrices (bf16 output) ----------------
__global__ __launch_bounds__(256) void build_cmat_kernel(
        const float* __restrict__ qkv, const float* __restrict__ k_pos,
        const float* __restrict__ v_pos, __hip_bfloat16* __restrict__ kcm,
        __hip_bfloat16* __restrict__ vcm) {
    int r = blockIdx.x;          // r = h*32 + w
    int h = r >> 5, w = r & 31;
    for (int e = threadIdx.x; e < CDIM; e += 256) {
        int i = e >> 6, d = e & 63;
        size_t qb = (size_t)(w * CBS + i) * QKVC;
        kcm[(size_t)r * CDIM + e] =
            __float2bfloat16(qkv[qb + KOFF + h * DH + d] + k_pos[(h * CBS + i) * DH + d]);
        vcm[(size_t)r * CDIM + e] =
            __float2bfloat16(qkv[qb + VOFF + h * DH + d] + v_pos[(h * CBS + i) * DH + d]);
    }
}

// ---------------- assemble ck/cv: prepend mem_kv -> (KVH, 33, DH) ----------------
__global__ __launch_bounds__(256) void assemble_kernel(
        const float* __restrict__ ckb, const float* __restrict__ cvb,
        const float* __restrict__ mem_kv, float* __restrict__ ck, float* __restrict__ cv) {
    int e = blockIdx.x * 256 + threadIdx.x;
    if (e >= KVH * (NCB + 1) * DH) return;
    int d = e & 63;
    int j = (e >> 6) % (NCB + 1);
    int h = e / ((NCB + 1) * DH);
    if (j == 0) {
        ck[e] = mem_kv[0 * KVH * DH + h * DH + d];
        cv[e] = mem_kv[1 * KVH * DH + h * DH + d];
    } else {
        ck[e] = ckb[((size_t)h * NCB + j - 1) * DH + d];
        cv[e] = cvb[((size_t)h * NCB + j - 1) * DH + d];
    }
}

// ---------------- block importance: imp[kvh][s][w] ----------------
__global__ __launch_bounds__(64) void imp_kernel(
        const float* __restrict__ qkv, const float* __restrict__ ck,
        float* __restrict__ imp) {
    int kvh = blockIdx.x, s = blockIdx.y, t = threadIdx.x;
    __shared__ float qg[GQ * DH];
    __shared__ float ckl[NCB * 65];
    for (int e = t; e < GQ * DH; e += 64) {
        int g = e >> 6, d = e & 63;
        qg[e] = qkv[(size_t)s * QKVC + (kvh * GQ + g) * DH + d];
    }
    for (int e = t; e < NCB * DH; e += 64) {
        int w = e >> 6, d = e & 63;
        ckl[w * 65 + d] = ck[((size_t)kvh * (NCB + 1) + 1 + w) * DH + d];
    }
    __syncthreads();
    if (t < NCB) {
        int w = t;
        float val;
        if (w * CBS + CBS - 1 < s) {
            float acc = 0.f;
            #pragma unroll
            for (int g = 0; g < GQ; g++) {
                const float* qp = qg + g * DH;
                const float* cp = ckl + w * 65;
                #pragma unroll 16
                for (int d = 0; d < DH; d++) acc += qp[d] * cp[d];
            }
            val = acc * SCALE * (1.f / (float)GQ);
        } else {
            val = -INFINITY;
        }
        imp[((size_t)kvh * S + s) * NCB + w] = val;
    }
}

// ---------------- top-8 selection (replicates lax.top_k stable ties) ----------------
__global__ __launch_bounds__(256) void select_kernel(
        const float* __restrict__ imp, int* __restrict__ sel) {
    int idx = blockIdx.x * 256 + threadIdx.x;
    if (idx >= KVH * S) return;
    const float* row = imp + (size_t)idx * NCB;
    float p[NCB];
    float m = -1000.f;
    for (int w = 0; w < NCB; w++) { p[w] = row[w]; m = fmaxf(m, p[w]); }
    float z = expf(-1000.f - m);
    for (int w = 0; w < NCB; w++) { p[w] = expf(p[w] - m); z += p[w]; }
    float inv = 1.f / z;
    bool used[NCB];
    for (int w = 0; w < NCB; w++) used[w] = false;
    for (int i = 0; i < NUMSEL; i++) {
        int best = 0; float bv = -1.f;
        for (int w = 0; w < NCB; w++) {
            if (!used[w]) {
                float pw = p[w] * inv;
                if (pw > bv) { bv = pw; best = w; }
            }
        }
        used[best] = true;
        sel[(size_t)idx * NUMSEL + i] = (bv > 1e-10f) ? best : -1;
    }
}

// ---------------- compressed attention, tiled: 64 queries x 1 head per block ----------------
__global__ __launch_bounds__(256) void cattn_kernel(
        const float* __restrict__ qkv, const float* __restrict__ ck,
        const float* __restrict__ cv, const float* __restrict__ gates,
        float* __restrict__ attn) {
    int h = blockIdx.x, qb = blockIdx.y;
    int kvh = h >> 3;
    int tid = threadIdx.x;
    int tx = tid & 15, ty = tid >> 4;
    __shared__ float Qs[64][68];   // [d][q]
    __shared__ float Ks[64][68];   // [d][j]; aliased by Ps[j][q] after scores
    __shared__ float Vs[64][68];   // [j][d]
    auto& Ps = Ks;
    for (int e = tid; e < 4096; e += 256) {
        int q = e >> 6, d = e & 63;
        Qs[d][q] = qkv[(size_t)(qb * 64 + q) * QKVC + h * DH + d];
    }
    for (int e = tid; e < 4096; e += 256) {
        int j = e >> 6, d = e & 63;
        float kvl = 0.f, vvl = 0.f;
        if (j < NCB + 1) {
            kvl = ck[((size_t)kvh * (NCB + 1) + j) * DH + d];
            vvl = cv[((size_t)kvh * (NCB + 1) + j) * DH + d];
        }
        Ks[d][j] = kvl;
        Vs[j][d] = vvl;
    }
    __syncthreads();
    float sc[4][4] = {{0.f}};
    for (int d = 0; d < 64; d++) {
        float4 av = *(const float4*)&Qs[d][ty * 4];
        float4 bv = *(const float4*)&Ks[d][tx * 4];
        float a[4] = {av.x, av.y, av.z, av.w};
        float b[4] = {bv.x, bv.y, bv.z, bv.w};
        #pragma unroll
        for (int i = 0; i < 4; i++)
            #pragma unroll
            for (int j = 0; j < 4; j++) sc[i][j] += a[i] * b[j];
    }
    __syncthreads();
    float l[4];
    float pv4[4][4];
    #pragma unroll
    for (int i = 0; i < 4; i++) {
        int spos = qb * 64 + ty * 4 + i;
        float tm = -INFINITY;
        #pragma unroll
        for (int j = 0; j < 4; j++) {
            int jj = tx * 4 + j;
            bool vis = (jj == 0) || ((jj <= NCB) && (jj * 64 <= spos));
            sc[i][j] = vis ? sc[i][j] * SCALE : -INFINITY;
            tm = fmaxf(tm, sc[i][j]);
        }
        #pragma unroll
        for (int o = 1; o < 16; o <<= 1) tm = fmaxf(tm, __shfl_xor(tm, o));
        float rs = 0.f;
        #pragma unroll
        for (int j = 0; j < 4; j++) {
            float p = expf(sc[i][j] - tm);
            pv4[i][j] = p;
            rs += p;
        }
        #pragma unroll
        for (int o = 1; o < 16; o <<= 1) rs += __shfl_xor(rs, o);
        l[i] = rs;
    }
    #pragma unroll
    for (int j = 0; j < 4; j++) {
        float4 w = make_float4(pv4[0][j], pv4[1][j], pv4[2][j], pv4[3][j]);
        *(float4*)&Ps[tx * 4 + j][ty * 4] = w;
    }
    __syncthreads();
    float acc[4][4] = {{0.f}};
    for (int jj = 0; jj < 64; jj++) {
        float4 av = *(const float4*)&Ps[jj][ty * 4];
        float4 bv = *(const float4*)&Vs[jj][tx * 4];
        float a[4] = {av.x, av.y, av.z, av.w};
        float b[4] = {bv.x, bv.y, bv.z, bv.w};
        #pragma unroll
        for (int i = 0; i < 4; i++)
            #pragma unroll
            for (int j = 0; j < 4; j++) acc[i][j] += a[i] * b[j];
    }
    #pragma unroll
    for (int i = 0; i < 4; i++) {
        int spos = qb * 64 + ty * 4 + i;
        float g0 = gates[((size_t)spos * HEADS + h) * 3 + 0];
        float sca = g0 / l[i];
        #pragma unroll
        for (int j = 0; j < 4; j++)
            attn[(size_t)spos * (HEADS * DH) + h * DH + tx * 4 + j] = acc[i][j] * sca;
    }
}

// ---------------- fine attention: fused online-softmax, one block per (kvh, s) ----------------
__global__ __launch_bounds__(256) void fattn_kernel(
        const float* __restrict__ rq, const float* __restrict__ rk,
        const float* __restrict__ qkv, const int* __restrict__ sel,
        const float* __restrict__ gates, float* __restrict__ attn) {
    int kvh = blockIdx.x, s = blockIdx.y;
    int tid = threadIdx.x;
    int h = tid >> 5, lk = tid & 31, d0 = lk * 2;
    __shared__ float Qs[8][64];
    __shared__ float Ks[64][68];   // [d][j]: conflict-free score reads
    __shared__ float Vs[64][68];   // [j][d]: 2-way (free) PV reads
    __shared__ float Ps[8][64];
    __shared__ int bl[9];
    for (int e = tid; e < 512; e += 256) {
        int hh = e >> 6, d = e & 63;
        Qs[hh][d] = rq[(size_t)s * (HEADS * DH) + (kvh * 8 + hh) * DH + d];
    }
    if (tid < NUMSEL) bl[tid] = sel[((size_t)kvh * S + s) * NUMSEL + tid];
    if (tid == NUMSEL) bl[NUMSEL] = s >> 6;
    __syncthreads();
    float mh = -INFINITY, lh = 0.f, o0 = 0.f, o1 = 0.f;
    for (int i = 0; i < 9; i++) {
        int w = bl[i];
        if (i < NUMSEL && w < 0) continue;   // uniform across block (bl shared)
        for (int e = tid; e < 1024; e += 256) {
            int j = e >> 4, c = (e & 15) * 4;
            float4 kv = *(const float4*)(rk + (size_t)(w * SBS + j) * (KVH * DH) + kvh * DH + c);
            Ks[c + 0][j] = kv.x; Ks[c + 1][j] = kv.y;
            Ks[c + 2][j] = kv.z; Ks[c + 3][j] = kv.w;
            float4 vv = *(const float4*)(qkv + (size_t)(w * SBS + j) * QKVC + VOFF + kvh * DH + c);
            *(float4*)&Vs[j][c] = vv;
        }
        __syncthreads();
        float a0 = 0.f, a1 = 0.f;
        #pragma unroll 16
        for (int d = 0; d < 64; d++) {
            float qv = Qs[h][d];
            a0 += qv * Ks[d][lk];
            a1 += qv * Ks[d][lk + 32];
        }
        float s0 = a0 * SCALE, s1 = a1 * SCALE;
        if (i == NUMSEL) {                    // causal mask inside diagonal block
            if (lk > (s & 63)) s0 = -INFINITY;
            if (lk + 32 > (s & 63)) s1 = -INFINITY;
        }
        float bmx = fmaxf(s0, s1);
        #pragma unroll
        for (int o = 1; o < 32; o <<= 1) bmx = fmaxf(bmx, __shfl_xor(bmx, o));
        float mn = fmaxf(mh, bmx);            // finite: every staged block has a visible key
        float scl = expf(mh - mn);            // first round: exp(-inf) = 0
        float p0 = expf(s0 - mn), p1 = expf(s1 - mn);
        float rs = p0 + p1;
        #pragma unroll
        for (int o = 1; o < 32; o <<= 1) rs += __shfl_xor(rs, o);
        lh = lh * scl + rs;
        o0 *= scl; o1 *= scl;
        mh = mn;
        Ps[h][lk] = p0; Ps[h][lk + 32] = p1;
        __syncthreads();
        #pragma unroll 8
        for (int j = 0; j < 64; j++) {
            float p = Ps[h][j];
            float2 vv = *(const float2*)&Vs[j][d0];
            o0 += p * vv.x; o1 += p * vv.y;
        }
        __syncthreads();
    }
    float g1 = gates[((size_t)s * HEADS + (kvh * 8 + h)) * 3 + 1];
    size_t ob = (size_t)s * (HEADS * DH) + (kvh * 8 + h) * DH;
    float invl = g1 / lh;
    attn[ob + d0]     += o0 * invl;
    attn[ob + d0 + 1] += o1 * invl;
}

// ---------------- sliding window, tiled flash-style: 64 queries x 1 head per block ----------------
__global__ __launch_bounds__(256) void sattn_kernel(
        const float* __restrict__ rq, const float* __restrict__ rk,
        const float* __restrict__ qkv, const float* __restrict__ gates,
        float* __restrict__ attn) {
    int h = blockIdx.x, qb = blockIdx.y;
    int kvh = h >> 3;
    int tid = threadIdx.x;
    int tx = tid & 15, ty = tid >> 4;
    __shared__ float Qs[64][68];
    __shared__ float Ks[64][68];
    __shared__ float Vs[64][68];
    auto& Ps = Ks;
    for (int e = tid; e < 4096; e += 256) {
        int q = e >> 6, d = e & 63;
        Qs[d][q] = rq[(size_t)(qb * 64 + q) * (HEADS * DH) + h * DH + d];
    }
    float m[4], l[4], acc[4][4];
    #pragma unroll
    for (int i = 0; i < 4; i++) {
        m[i] = -INFINITY; l[i] = 0.f;
        #pragma unroll
        for (int j = 0; j < 4; j++) acc[i][j] = 0.f;
    }
    __syncthreads();
    for (int c = 0; c < 9; c++) {
        int kb = qb * 64 - WIN + c * 64;
        if (kb + 63 < 0) continue;
        for (int e = tid; e < 4096; e += 256) {
            int j = e >> 6, d = e & 63;
            int jpos = kb + j;
            float kvl = 0.f, vvl = 0.f;
            if (jpos >= 0) {
                kvl = rk[(size_t)jpos * (KVH * DH) + kvh * DH + d];
                vvl = qkv[(size_t)jpos * QKVC + VOFF + kvh * DH + d];
            }
            Ks[d][j] = kvl;
            Vs[j][d] = vvl;
        }
        __syncthreads();
        float sc[4][4] = {{0.f}};
        for (int d = 0; d < 64; d++) {
            float4 av = *(const float4*)&Qs[d][ty * 4];
            float4 bv = *(const float4*)&Ks[d][tx * 4];
            float a[4] = {av.x, av.y, av.z, av.w};
            float b[4] = {bv.x, bv.y, bv.z, bv.w};
            #pragma unroll
            for (int i = 0; i < 4; i++)
                #pragma unroll
                for (int j = 0; j < 4; j++) sc[i][j] += a[i] * b[j];
        }
        __syncthreads();
        float pv4[4][4];
        #pragma unroll
        for (int i = 0; i < 4; i++) {
            int spos = qb * 64 + ty * 4 + i;
            float tm = -INFINITY;
            #pragma unroll
            for (int j = 0; j < 4; j++) {
                int jpos = kb + tx * 4 + j;
                bool valid = (jpos >= 0) && (jpos <= spos) && (jpos >= spos - WIN);
                sc[i][j] = valid ? sc[i][j] * SCALE : -INFINITY;
                tm = fmaxf(tm, sc[i][j]);
            }
            #pragma unroll
            for (int o = 1; o < 16; o <<= 1) tm = fmaxf(tm, __shfl_xor(tm, o));
            float mn = fmaxf(m[i], tm);
            float sca = (mn == -INFINITY) ? 1.f : expf(m[i] - mn);
            float rs = 0.f;
            #pragma unroll
            for (int j = 0; j < 4; j++) {
                float p = (mn == -INFINITY) ? 0.f : expf(sc[i][j] - mn);
                pv4[i][j] = p;
                rs += p;
            }
            #pragma unroll
            for (int o = 1; o < 16; o <<= 1) rs += __shfl_xor(rs, o);
            l[i] = l[i] * sca + rs;
            m[i] = mn;
            #pragma unroll
            for (int j = 0; j < 4; j++) acc[i][j] *= sca;
        }
        #pragma unroll
        for (int j = 0; j < 4; j++) {
            float4 w = make_float4(pv4[0][j], pv4[1][j], pv4[2][j], pv4[3][j]);
            *(float4*)&Ps[tx * 4 + j][ty * 4] = w;
        }
        __syncthreads();
        for (int jj = 0; jj < 64; jj++) {
            float4 av = *(const float4*)&Ps[jj][ty * 4];
            float4 bv = *(const float4*)&Vs[jj][tx * 4];
            float a[4] = {av.x, av.y, av.z, av.w};
            float b[4] = {bv.x, bv.y, bv.z, bv.w};
            #pragma unroll
            for (int i = 0; i < 4; i++)
                #pragma unroll
                for (int j = 0; j < 4; j++) acc[i][j] += a[i] * b[j];
        }
        __syncthreads();
    }
    #pragma unroll
    for (int i = 0; i < 4; i++) {
        int spos = qb * 64 + ty * 4 + i;
        float g2 = gates[((size_t)spos * HEADS + h) * 3 + 2];
        float sca = g2 / l[i];
        #pragma unroll
        for (int j = 0; j < 4; j++)
            attn[(size_t)spos * (HEADS * DH) + h * DH + tx * 4 + j] += acc[i][j] * sca;
    }
}

// ---------------- launch ----------------
extern "C" void kernel_launch(void* const* d_in, const int* in_sizes, int n_in,
                              void* d_out, int out_size, void* d_ws, size_t ws_size,
                              hipStream_t stream) {
    const float* x      = (const float*)d_in[0];
    const float* rms_g  = (const float*)d_in[1];
    const float* W_qkv  = (const float*)d_in[2];
    const float* k_pos  = (const float*)d_in[3];
    const float* v_pos  = (const float*)d_in[4];
    const float* mem_kv = (const float*)d_in[5];
    const float* kW1    = (const float*)d_in[6];
    const float* kb1    = (const float*)d_in[7];
    const float* kW2    = (const float*)d_in[8];
    const float* kb2    = (const float*)d_in[9];
    const float* vW1    = (const float*)d_in[10];
    const float* vb1    = (const float*)d_in[11];
    const float* vW2    = (const float*)d_in[12];
    const float* vb2    = (const float*)d_in[13];
    const float* W_comb = (const float*)d_in[14];
    const float* b_comb = (const float*)d_in[15];
    const float* W_out  = (const float*)d_in[16];
    float* out = (float*)d_out;

    // workspace layout (floats) — region R (1048576 fl) is time-multiplexed:
    //   step 1-2: xnb (2048*1024 bf16 = 1048576 fl exactly)
    //   step 4-8: kcmb/vcmb (64*4096 bf16 = 131072 fl EACH), khid/vhid (262144 fl
    //             each), ckb/cvb (4096 fl each) -> ends at 794624 < 1048576
    //   step 15-16: attnb (2048*1024 bf16 = 1048576 fl exactly)
    float* ws    = (float*)d_ws;
    float* xn    = ws;                                     // 2097152
    float* qkv   = xn    + (size_t)S * DIM;                // 2621440
    float* rq    = qkv   + (size_t)S * QKVC;               // 2097152
    float* rk    = rq    + (size_t)S * HEADS * DH;         // 262144
    float* R     = rk    + (size_t)S * KVH * DH;           // 1048576
    float* ck    = R     + 1048576;                        // 4224
    float* cv    = ck    + (size_t)KVH * (NCB + 1) * DH;   // 4224
    float* imp   = cv    + (size_t)KVH * (NCB + 1) * DH;   // 131072
    float* gates = imp   + (size_t)KVH * S * NCB;          // 98304
    float* attn  = gates + (size_t)S * HEADS * 3;          // 2097152
    int*   sel   = (int*)(attn + (size_t)S * HEADS * DH);  // 32768 ints

    __hip_bfloat16* xnb   = (__hip_bfloat16*)R;            // dead after step 2
    __hip_bfloat16* kcmb  = (__hip_bfloat16*)R;            // 262144 bf16 = 131072 fl
    __hip_bfloat16* vcmb  = (__hip_bfloat16*)(R + 131072); // 262144 bf16 = 131072 fl
    float* khid  = R + 262144;                             // 262144 fl
    float* vhid  = R + 524288;                             // 262144 fl
    float* ckb   = R + 786432;                             // 4096 fl
    float* cvb   = R + 790528;                             // 4096 fl (ends 794624)
    __hip_bfloat16* attnb = (__hip_bfloat16*)R;            // reused after step 8
    float* partW1 = attn;   // 8*64*4096 = 2097152 (attn live only from step 12)
    float* partW2 = imp;    // 32*64*64 = 131072   (imp live only from step 10)

    // 1. RMSNorm (fp32 + bf16)
    rmsnorm_kernel<<<S, 256, 0, stream>>>(x, rms_g, xn, xnb);
    // 2. QKV projection (bf16 MFMA): (2048,1024)@(1024,1280)
    gemm_mfma_kernel<128, 128, 2, 2><<<dim3(QKVC / 128, S / 128, 1), 256, 0, stream>>>(
        xnb, W_qkv, nullptr, qkv, S, QKVC, DIM, DIM);
    // 3. rotary
    rotary_kernel<<<S, 256, 0, stream>>>(qkv, rq, rk);
    // 4. compress-MLP inputs (bf16)
    build_cmat_kernel<<<KVH * NCB, 256, 0, stream>>>(qkv, k_pos, v_pos, kcmb, vcmb);
    // 5. k-MLP W1 (bf16 MFMA, split-K 8): relu((64,4096)@(4096,4096)+b)
    gemm_mfma_kernel<64, 128, 1, 4><<<dim3(CDIM / 128, 1, 8), 256, 0, stream>>>(
        kcmb, kW1, nullptr, partW1, 64, CDIM, CDIM, CDIM / 8);
    reduce_splitk_kernel<1><<<(64 * CDIM + 255) / 256, 256, 0, stream>>>(
        partW1, kb1, khid, 64 * CDIM, CDIM, 8);
    // 6. k-MLP W2 (fp32 split-K 32): (64,4096)@(4096,64)+b
    gemm_splitk_kernel<<<dim3(1, 1, 32), 256, 0, stream>>>(khid, kW2, partW2, 64, DH, CDIM, CDIM / 32);
    reduce_splitk_kernel<0><<<(64 * DH + 255) / 256, 256, 0, stream>>>(partW2, kb2, ckb, 64 * DH, DH, 32);
    // 7. v-MLP
    gemm_mfma_kernel<64, 128, 1, 4><<<dim3(CDIM / 128, 1, 8), 256, 0, stream>>>(
        vcmb, vW1, nullptr, partW1, 64, CDIM, CDIM, CDIM / 8);
    reduce_splitk_kernel<1><<<(64 * CDIM + 255) / 256, 256, 0, stream>>>(
        partW1, vb1, vhid, 64 * CDIM, CDIM, 8);
    gemm_splitk_kernel<<<dim3(1, 1, 32), 256, 0, stream>>>(vhid, vW2, partW2, 64, DH, CDIM, CDIM / 32);
    reduce_splitk_kernel<0><<<(64 * DH + 255) / 256, 256, 0, stream>>>(partW2, vb2, cvb, 64 * DH, DH, 32);
    // 8. assemble ck/cv with mem tokens
    assemble_kernel<<<(KVH * (NCB + 1) * DH + 255) / 256, 256, 0, stream>>>(ckb, cvb, mem_kv, ck, cv);
    // 9. gates = sigmoid(xn @ W_comb + b_comb)  (fp32, N=48)
    gemm_kernel<2><<<dim3(1, S / 64), 256, 0, stream>>>(xn, W_comb, b_comb, gates, S, HEADS * 3, DIM);
    // 10. block importance
    imp_kernel<<<dim3(KVH, S), 64, 0, stream>>>(qkv, ck, imp);
    // 11. top-8 selection
    select_kernel<<<(KVH * S + 255) / 256, 256, 0, stream>>>(imp, sel);
    // 12. compressed attention (writes attn = g0*c_out)
    cattn_kernel<<<dim3(HEADS, S / 64), 256, 0, stream>>>(qkv, ck, cv, gates, attn);
    // 13. fine attention (attn += g1*f_out)
    fattn_kernel<<<dim3(KVH, S), 256, 0, stream>>>(rq, rk, qkv, sel, gates, attn);
    // 14. sliding window (attn += g2*s_out)
    sattn_kernel<<<dim3(HEADS, S / 64), 256, 0, stream>>>(rq, rk, qkv, gates, attn);
    // 15. cast attn -> bf16
    cast_bf16_kernel<<<(S * HEADS * DH / 4 + 255) / 256, 256, 0, stream>>>(
        attn, attnb, S * HEADS * DH / 4);
    // 16. output projection (bf16 MFMA): (2048,1024)@(1024,1024)
    gemm_mfma_kernel<128, 128, 2, 2><<<dim3(DIM / 128, S / 128, 1), 256, 0, stream>>>(
        attnb, W_out, nullptr, out, S, DIM, DIM, DIM);
}

// Round 5
// 996.440 us; speedup vs baseline: 4.0145x; 1.1005x over previous
//
#include <hip/hip_runtime.h>
#include <hip/hip_bf16.h>
#include <cstddef>
#include <cstdint>

// Problem constants (B=1)
#define S      2048
#define DIM    1024
#define HEADS  16
#define KVH    2
#define GQ     8
#define DH     64
#define CBS    64
#define SBS    64
#define NUMSEL 8
#define WIN    512
#define NCB    (S / CBS)      // 32
#define CDIM   (CBS * DH)     // 4096
#define QKVC   (HEADS * DH + 2 * KVH * DH)   // 1280
#define KOFF   (HEADS * DH)                  // 1024 (k cols start)
#define VOFF   (HEADS * DH + KVH * DH)       // 1152 (v cols start)
#define SCALE  0.125f
#define RMS_EPS 1.1920928955078125e-07f

typedef __attribute__((ext_vector_type(8))) short bf16x8;   // 8 bf16 in 4 VGPRs
typedef __attribute__((ext_vector_type(4))) float f32x4;

__device__ inline short f2bs(float f) {
    __hip_bfloat16 b = __float2bfloat16(f);
    return *(short*)&b;
}

// ---------------- wave (64-lane) reductions ----------------
__device__ inline float wave_sum(float v) {
    for (int o = 32; o > 0; o >>= 1) v += __shfl_xor(v, o);
    return v;
}

// ---------------- RMSNorm (writes fp32 + bf16 copies) ----------------
__global__ __launch_bounds__(256) void rmsnorm_kernel(
        const float* __restrict__ x, const float* __restrict__ g,
        float* __restrict__ xn, __hip_bfloat16* __restrict__ xnb) {
    int s = blockIdx.x, tid = threadIdx.x;
    const float4* row = (const float4*)(x + (size_t)s * DIM);
    float4 v = row[tid];
    float ss = v.x * v.x + v.y * v.y + v.z * v.z + v.w * v.w;
    ss = wave_sum(ss);
    __shared__ float red[4];
    if ((tid & 63) == 0) red[tid >> 6] = ss;
    __syncthreads();
    float tot = red[0] + red[1] + red[2] + red[3];
    float sc = rsqrtf(tot / (float)DIM + RMS_EPS);
    float4 gg = ((const float4*)g)[tid];
    float4 o;
    o.x = v.x * sc * gg.x; o.y = v.y * sc * gg.y;
    o.z = v.z * sc * gg.z; o.w = v.w * sc * gg.w;
    ((float4*)(xn + (size_t)s * DIM))[tid] = o;
    size_t b = (size_t)s * DIM + tid * 4;
    xnb[b + 0] = __float2bfloat16(o.x);
    xnb[b + 1] = __float2bfloat16(o.y);
    xnb[b + 2] = __float2bfloat16(o.z);
    xnb[b + 3] = __float2bfloat16(o.w);
}

// ---------------- fp32 -> bf16 cast ----------------
__global__ __launch_bounds__(256) void cast_bf16_kernel(
        const float* __restrict__ in, __hip_bfloat16* __restrict__ out, int n4) {
    int e = blockIdx.x * 256 + threadIdx.x;
    if (e >= n4) return;
    float4 v = ((const float4*)in)[e];
    out[4 * e + 0] = __float2bfloat16(v.x);
    out[4 * e + 1] = __float2bfloat16(v.y);
    out[4 * e + 2] = __float2bfloat16(v.z);
    out[4 * e + 3] = __float2bfloat16(v.w);
}

// ---------------- extract V columns of qkv -> vb (S, KVH, DH) bf16 ----------------
__global__ __launch_bounds__(256) void cast_v_kernel(
        const float* __restrict__ qkv, short* __restrict__ vb) {
    int e = blockIdx.x * 256 + threadIdx.x;    // e4 over S*KVH*DH/4
    if (e >= S * KVH * DH / 4) return;
    int idx = e * 4;
    int tok = idx / (KVH * DH), rem = idx % (KVH * DH);
    float4 v = *(const float4*)(qkv + (size_t)tok * QKVC + VOFF + rem);
    vb[idx + 0] = f2bs(v.x);
    vb[idx + 1] = f2bs(v.y);
    vb[idx + 2] = f2bs(v.z);
    vb[idx + 3] = f2bs(v.w);
}

// ---------------- bf16 MFMA GEMM: C = act(A(bf16,MxK) @ B(fp32,KxN) [+bias]) ----------
// B cast to bf16 during LDS staging (stored [n][k]). Split-K via blockIdx.z.
// N-guard supports N < BN (gates). Requires M % BM == 0, kslice % 32 == 0.
template <int BM, int BN, int WM, int WN, int ACT>
__global__ __launch_bounds__(256) void gemm_mfma_kernel(
        const __hip_bfloat16* __restrict__ A, const float* __restrict__ B,
        const float* __restrict__ bias, float* __restrict__ C,
        int M, int N, int K, int kslice) {
    constexpr int BK = 32;
    constexpr int TM = BM / (WM * 16);
    constexpr int TN = BN / (WN * 16);
    constexpr int LDK = BK + 8;   // pad: stride 40 bf16 = 20 dwords (2-way free)
    __shared__ __hip_bfloat16 As[BM][LDK];
    __shared__ __hip_bfloat16 Bs[BN][LDK];
    int tid = threadIdx.x;
    int wave = tid >> 6, lane = tid & 63;
    int wm = wave % WM, wn = wave / WM;
    int m0 = wm * TM * 16, n0 = wn * TN * 16;
    int bm = blockIdx.y * BM, bn = blockIdx.x * BN;
    int kbeg = blockIdx.z * kslice, kend = kbeg + kslice;
    int lm = lane & 15, quad = lane >> 4;
    f32x4 acc[TM][TN] = {};
    for (int k0 = kbeg; k0 < kend; k0 += BK) {
        #pragma unroll
        for (int e = 0; e < BM * BK / (256 * 8); e++) {
            int idx = (tid + e * 256) * 8;
            int r = idx >> 5, kk = idx & 31;
            *(bf16x8*)(&As[r][kk]) =
                *(const bf16x8*)(A + (size_t)(bm + r) * K + k0 + kk);
        }
        #pragma unroll
        for (int e = 0; e < BN * BK / 256; e++) {
            int idx = tid + e * 256;
            int kk = idx / BN, n = idx % BN;
            int gn = bn + n;
            Bs[n][kk] = (gn < N) ? __float2bfloat16(B[(size_t)(k0 + kk) * N + gn])
                                 : __float2bfloat16(0.f);
        }
        __syncthreads();
        bf16x8 af[TM], bf_[TN];
        #pragma unroll
        for (int i = 0; i < TM; i++)
            af[i] = *(const bf16x8*)(&As[m0 + i * 16 + lm][quad * 8]);
        #pragma unroll
        for (int j = 0; j < TN; j++)
            bf_[j] = *(const bf16x8*)(&Bs[n0 + j * 16 + lm][quad * 8]);
        #pragma unroll
        for (int i = 0; i < TM; i++)
            #pragma unroll
            for (int j = 0; j < TN; j++)
                acc[i][j] = __builtin_amdgcn_mfma_f32_16x16x32_bf16(
                    af[i], bf_[j], acc[i][j], 0, 0, 0);
        __syncthreads();
    }
    size_t cbase = (size_t)blockIdx.z * M * N;
    #pragma unroll
    for (int i = 0; i < TM; i++) {
        #pragma unroll
        for (int j = 0; j < TN; j++) {
            int gn = bn + n0 + j * 16 + lm;
            if (gn >= N) continue;
            #pragma unroll
            for (int r = 0; r < 4; r++) {
                int gm = bm + m0 + i * 16 + quad * 4 + r;
                float v = acc[i][j][r];
                if (bias) v += bias[gn];
                if (ACT == 2) v = 1.f / (1.f + expf(-v));
                C[cbase + (size_t)gm * N + gn] = v;
            }
        }
    }
}

// ---------------- split-K fp32 GEMM (partials) — for the tiny W2 matmuls ----------------
__global__ __launch_bounds__(256) void gemm_splitk_kernel(
        const float* __restrict__ A, const float* __restrict__ B,
        float* __restrict__ P, int M, int N, int K, int kslice) {
    const int BM = 64, BN = 64, BK = 16;
    __shared__ float As[BK][BM + 4];
    __shared__ float Bs[BK][BN];
    int bm = blockIdx.y * BM, bn = blockIdx.x * BN;
    int z = blockIdx.z;
    int kbeg = z * kslice, kend = kbeg + kslice;
    int tid = threadIdx.x;
    int tx = tid & 15, ty = tid >> 4;
    float acc[4][4] = {{0.f}};
    for (int k0 = kbeg; k0 < kend; k0 += BK) {
        #pragma unroll
        for (int e = 0; e < 4; e++) {
            int idx = tid + e * 256;
            int m = idx >> 4, kk = idx & 15;
            int gm = bm + m;
            As[kk][m] = (gm < M) ? A[(size_t)gm * K + k0 + kk] : 0.f;
        }
        #pragma unroll
        for (int e = 0; e < 4; e++) {
            int idx = tid + e * 256;
            int kk = idx >> 6, n = idx & 63;
            int gn = bn + n;
            Bs[kk][n] = (gn < N) ? B[(size_t)(k0 + kk) * N + gn] : 0.f;
        }
        __syncthreads();
        #pragma unroll
        for (int kk = 0; kk < BK; kk++) {
            float a[4], b[4];
            #pragma unroll
            for (int i = 0; i < 4; i++) a[i] = As[kk][ty * 4 + i];
            #pragma unroll
            for (int j = 0; j < 4; j++) b[j] = Bs[kk][tx * 4 + j];
            #pragma unroll
            for (int i = 0; i < 4; i++)
                #pragma unroll
                for (int j = 0; j < 4; j++) acc[i][j] += a[i] * b[j];
        }
        __syncthreads();
    }
    #pragma unroll
    for (int i = 0; i < 4; i++) {
        int gm = bm + ty * 4 + i;
        if (gm >= M) continue;
        #pragma unroll
        for (int j = 0; j < 4; j++) {
            int gn = bn + tx * 4 + j;
            if (gn >= N) continue;
            P[((size_t)z * M + gm) * N + gn] = acc[i][j];
        }
    }
}

template <int ACT>
__global__ __launch_bounds__(256) void reduce_splitk_kernel(
        const float* __restrict__ P, const float* __restrict__ bias,
        float* __restrict__ C, int MN, int N, int splits) {
    int e = blockIdx.x * 256 + threadIdx.x;
    if (e >= MN) return;
    float s = 0.f;
    for (int z = 0; z < splits; z++) s += P[(size_t)z * MN + e];
    s += bias[e % N];
    if (ACT == 1) s = fmaxf(s, 0.f);
    C[e] = s;
}

// ---------------- rotary embedding (interleaved pairs, theta=10000) ----------------
// also emits bf16 rk copy (rkb) for the MFMA fine-attention
__global__ __launch_bounds__(256) void rotary_kernel(
        const float* __restrict__ qkv, float* __restrict__ rq, float* __restrict__ rk,
        short* __restrict__ rkb) {
    int s = blockIdx.x, tid = threadIdx.x;
    for (int p = tid; p < (HEADS + KVH) * (DH / 2); p += 256) {
        int t; const float* src; float* dst; short* dst2 = nullptr;
        if (p < HEADS * (DH / 2)) {
            int h = p >> 5; t = p & 31;
            src = qkv + (size_t)s * QKVC + h * DH + 2 * t;
            dst = rq + (size_t)s * (HEADS * DH) + h * DH + 2 * t;
        } else {
            int pp = p - HEADS * (DH / 2);
            int h = pp >> 5; t = pp & 31;
            src = qkv + (size_t)s * QKVC + KOFF + h * DH + 2 * t;
            dst = rk + (size_t)s * (KVH * DH) + h * DH + 2 * t;
            dst2 = rkb + (size_t)s * (KVH * DH) + h * DH + 2 * t;
        }
        float u0 = src[0], u1 = src[1];
        float freq = powf(10000.f, -((float)(2 * t) / (float)DH));
        float ang = (float)s * freq;
        float sn, cs;
        sincosf(ang, &sn, &cs);
        float o0 = u0 * cs - u1 * sn;
        float o1 = u1 * cs + u0 * sn;
        dst[0] = o0;
        dst[1] = o1;
        if (dst2) { dst2[0] = f2bs(o0); dst2[1] = f2bs(o1); }
    }
}

// ---------------- build compress-MLP input matrices (bf16 output) ----------------
__global__ __launch_bounds__(256) void build_cmat_kernel(
        const float* __restrict__ qkv, const float* __restrict__ k_pos,
        const float* __restrict__ v_pos, __hip_bfloat16* __restrict__ kcm,
        __hip_bfloat16* __restrict__ vcm) {
    int r = blockIdx.x;          // r = h*32 + w
    int h = r >> 5, w = r & 31;
    for (int e = threadIdx.x; e < CDIM; e += 256) {
        int i = e >> 6, d = e & 63;
        size_t qb = (size_t)(w * CBS + i) * QKVC;
        kcm[(size_t)r * CDIM + e] =
            __float2bfloat16(qkv[qb + KOFF + h * DH + d] + k_pos[(h * CBS + i) * DH + d]);
        vcm[(size_t)r * CDIM + e] =
            __float2bfloat16(qkv[qb + VOFF + h * DH + d] + v_pos[(h * CBS + i) * DH + d]);
    }
}

// ---------------- assemble ck/cv: prepend mem_kv -> (KVH, 33, DH) ----------------
__global__ __launch_bounds__(256) void assemble_kernel(
        const float* __restrict__ ckb, const float* __restrict__ cvb,
        const float* __restrict__ mem_kv, float* __restrict__ ck, float* __restrict__ cv) {
    int e = blockIdx.x * 256 + threadIdx.x;
    if (e >= KVH * (NCB + 1) * DH) return;
    int d = e & 63;
    int j = (e >> 6) % (NCB + 1);
    int h = e / ((NCB + 1) * DH);
    if (j == 0) {
        ck[e] = mem_kv[0 * KVH * DH + h * DH + d];
        cv[e] = mem_kv[1 * KVH * DH + h * DH + d];
    } else {
        ck[e] = ckb[((size_t)h * NCB + j - 1) * DH + d];
        cv[e] = cvb[((size_t)h * NCB + j - 1) * DH + d];
    }
}

// ---------------- block importance: imp[kvh][s][w] ----------------
__global__ __launch_bounds__(64) void imp_kernel(
        const float* __restrict__ qkv, const float* __restrict__ ck,
        float* __restrict__ imp) {
    int kvh = blockIdx.x, s = blockIdx.y, t = threadIdx.x;
    __shared__ float qg[GQ * DH];
    __shared__ float ckl[NCB * 65];
    for (int e = t; e < GQ * DH; e += 64) {
        int g = e >> 6, d = e & 63;
        qg[e] = qkv[(size_t)s * QKVC + (kvh * GQ + g) * DH + d];
    }
    for (int e = t; e < NCB * DH; e += 64) {
        int w = e >> 6, d = e & 63;
        ckl[w * 65 + d] = ck[((size_t)kvh * (NCB + 1) + 1 + w) * DH + d];
    }
    __syncthreads();
    if (t < NCB) {
        int w = t;
        float val;
        if (w * CBS + CBS - 1 < s) {
            float acc = 0.f;
            #pragma unroll
            for (int g = 0; g < GQ; g++) {
                const float* qp = qg + g * DH;
                const float* cp = ckl + w * 65;
                #pragma unroll 16
                for (int d = 0; d < DH; d++) acc += qp[d] * cp[d];
            }
            val = acc * SCALE * (1.f / (float)GQ);
        } else {
            val = -INFINITY;
        }
        imp[((size_t)kvh * S + s) * NCB + w] = val;
    }
}

// ---------------- top-8 selection (replicates lax.top_k stable ties) ----------------
__global__ __launch_bounds__(256) void select_kernel(
        const float* __restrict__ imp, int* __restrict__ sel) {
    int idx = blockIdx.x * 256 + threadIdx.x;
    if (idx >= KVH * S) return;
    const float* row = imp + (size_t)idx * NCB;
    float p[NCB];
    float m = -1000.f;
    for (int w = 0; w < NCB; w++) { p[w] = row[w]; m = fmaxf(m, p[w]); }
    float z = expf(-1000.f - m);
    for (int w = 0; w < NCB; w++) { p[w] = expf(p[w] - m); z += p[w]; }
    float inv = 1.f / z;
    bool used[NCB];
    for (int w = 0; w < NCB; w++) used[w] = false;
    for (int i = 0; i < NUMSEL; i++) {
        int best = 0; float bv = -1.f;
        for (int w = 0; w < NCB; w++) {
            if (!used[w]) {
                float pw = p[w] * inv;
                if (pw > bv) { bv = pw; best = w; }
            }
        }
        used[best] = true;
        sel[(size_t)idx * NUMSEL + i] = (bv > 1e-10f) ? best : -1;
    }
}

// ---------------- compressed attention, tiled: 64 queries x 1 head per block ----------------
__global__ __launch_bounds__(256) void cattn_kernel(
        const float* __restrict__ qkv, const float* __restrict__ ck,
        const float* __restrict__ cv, const float* __restrict__ gates,
        float* __restrict__ attn) {
    int h = blockIdx.x, qb = blockIdx.y;
    int kvh = h >> 3;
    int tid = threadIdx.x;
    int tx = tid & 15, ty = tid >> 4;
    __shared__ float Qs[64][68];   // [d][q]
    __shared__ float Ks[64][68];   // [d][j]; aliased by Ps[j][q] after scores
    __shared__ float Vs[64][68];   // [j][d]
    auto& Ps = Ks;
    for (int e = tid; e < 4096; e += 256) {
        int q = e >> 6, d = e & 63;
        Qs[d][q] = qkv[(size_t)(qb * 64 + q) * QKVC + h * DH + d];
    }
    for (int e = tid; e < 4096; e += 256) {
        int j = e >> 6, d = e & 63;
        float kvl = 0.f, vvl = 0.f;
        if (j < NCB + 1) {
            kvl = ck[((size_t)kvh * (NCB + 1) + j) * DH + d];
            vvl = cv[((size_t)kvh * (NCB + 1) + j) * DH + d];
        }
        Ks[d][j] = kvl;
        Vs[j][d] = vvl;
    }
    __syncthreads();
    float sc[4][4] = {{0.f}};
    for (int d = 0; d < 64; d++) {
        float4 av = *(const float4*)&Qs[d][ty * 4];
        float4 bv = *(const float4*)&Ks[d][tx * 4];
        float a[4] = {av.x, av.y, av.z, av.w};
        float b[4] = {bv.x, bv.y, bv.z, bv.w};
        #pragma unroll
        for (int i = 0; i < 4; i++)
            #pragma unroll
            for (int j = 0; j < 4; j++) sc[i][j] += a[i] * b[j];
    }
    __syncthreads();
    float l[4];
    float pv4[4][4];
    #pragma unroll
    for (int i = 0; i < 4; i++) {
        int spos = qb * 64 + ty * 4 + i;
        float tm = -INFINITY;
        #pragma unroll
        for (int j = 0; j < 4; j++) {
            int jj = tx * 4 + j;
            bool vis = (jj == 0) || ((jj <= NCB) && (jj * 64 <= spos));
            sc[i][j] = vis ? sc[i][j] * SCALE : -INFINITY;
            tm = fmaxf(tm, sc[i][j]);
        }
        #pragma unroll
        for (int o = 1; o < 16; o <<= 1) tm = fmaxf(tm, __shfl_xor(tm, o));
        float rs = 0.f;
        #pragma unroll
        for (int j = 0; j < 4; j++) {
            float p = expf(sc[i][j] - tm);
            pv4[i][j] = p;
            rs += p;
        }
        #pragma unroll
        for (int o = 1; o < 16; o <<= 1) rs += __shfl_xor(rs, o);
        l[i] = rs;
    }
    #pragma unroll
    for (int j = 0; j < 4; j++) {
        float4 w = make_float4(pv4[0][j], pv4[1][j], pv4[2][j], pv4[3][j]);
        *(float4*)&Ps[tx * 4 + j][ty * 4] = w;
    }
    __syncthreads();
    float acc[4][4] = {{0.f}};
    for (int jj = 0; jj < 64; jj++) {
        float4 av = *(const float4*)&Ps[jj][ty * 4];
        float4 bv = *(const float4*)&Vs[jj][tx * 4];
        float a[4] = {av.x, av.y, av.z, av.w};
        float b[4] = {bv.x, bv.y, bv.z, bv.w};
        #pragma unroll
        for (int i = 0; i < 4; i++)
            #pragma unroll
            for (int j = 0; j < 4; j++) acc[i][j] += a[i] * b[j];
    }
    #pragma unroll
    for (int i = 0; i < 4; i++) {
        int spos = qb * 64 + ty * 4 + i;
        float g0 = gates[((size_t)spos * HEADS + h) * 3 + 0];
        float sca = g0 / l[i];
        #pragma unroll
        for (int j = 0; j < 4; j++)
            attn[(size_t)spos * (HEADS * DH) + h * DH + tx * 4 + j] = acc[i][j] * sca;
    }
}

// ---------------- fine attention: MFMA flash, one block per (kvh, s) ----------------
// 4 waves; scores: wave w owns 16-key tile (K-frags direct from global rkb);
// PV: wave w owns 16-dim tile (V^T staged bf16 in LDS). Online softmax in LDS.
__global__ __launch_bounds__(256) void fattn_kernel(
        const float* __restrict__ rq, const short* __restrict__ rkb,
        const short* __restrict__ vb, const int* __restrict__ sel,
        const float* __restrict__ gates, float* __restrict__ attn) {
    int kvh = blockIdx.x, s = blockIdx.y;
    int tid = threadIdx.x;
    int wv = tid >> 6, lane = tid & 63;
    int lm = lane & 15, quad = lane >> 4;
    int hh = tid >> 5, lk = tid & 31;          // softmax mapping: 8 groups x 32 lanes
    __shared__ short Qb[16][68];               // [head][d] bf16 (heads 8-15 garbage)
    __shared__ short Vt[64][68];               // [d][key] bf16 (V^T)
    __shared__ short Pb[16][68];               // [head][key] bf16 probs
    __shared__ float Sc[8][68];                // [head][key] fp32 scores
    __shared__ float alph[8], fac[8];
    __shared__ int bl[9];
    for (int e = tid; e < 512; e += 256) {
        int h = e >> 6, d = e & 63;
        Qb[h][d] = f2bs(rq[(size_t)s * (HEADS * DH) + (kvh * 8 + h) * DH + d]);
    }
    if (tid < NUMSEL) bl[tid] = sel[((size_t)kvh * S + s) * NUMSEL + tid];
    if (tid == NUMSEL) bl[NUMSEL] = s >> 6;
    __syncthreads();
    // Q A-frags: A[m=lane&15][k=quad*8+j], loaded once (m>=8 rows garbage -> ignored D rows)
    bf16x8 aq0 = *(const bf16x8*)&Qb[lm][quad * 8];
    bf16x8 aq1 = *(const bf16x8*)&Qb[lm][32 + quad * 8];
    float mh = -INFINITY, lh = 0.f;
    f32x4 oacc = {0.f, 0.f, 0.f, 0.f};
    for (int i = 0; i < 9; i++) {
        int w = bl[i];
        if (i < NUMSEL && w < 0) continue;     // uniform across block
        // stage V^T (bf16): Vt[d][key]
        #pragma unroll
        for (int r = 0; r < 2; r++) {
            int idx = tid + r * 256;           // 0..511
            int c8 = idx >> 6, j = idx & 63;
            bf16x8 vv = *(const bf16x8*)(vb + ((size_t)(w * SBS + j) * KVH + kvh) * DH + c8 * 8);
            #pragma unroll
            for (int t = 0; t < 8; t++) Vt[c8 * 8 + t][j] = vv[t];
        }
        // scores: D[m=head][n=key-in-tile]; B[k=d][n=key] read direct from rkb
        {
            const short* kp = rkb + ((size_t)(w * SBS + wv * 16 + lm) * KVH + kvh) * DH;
            bf16x8 bk0 = *(const bf16x8*)(kp + quad * 8);
            bf16x8 bk1 = *(const bf16x8*)(kp + 32 + quad * 8);
            f32x4 sc4 = {0.f, 0.f, 0.f, 0.f};
            sc4 = __builtin_amdgcn_mfma_f32_16x16x32_bf16(aq0, bk0, sc4, 0, 0, 0);
            sc4 = __builtin_amdgcn_mfma_f32_16x16x32_bf16(aq1, bk1, sc4, 0, 0, 0);
            bool vis = (i < NUMSEL) || (wv * 16 + lm <= (s & 63));
            #pragma unroll
            for (int r = 0; r < 4; r++) {
                int row = quad * 4 + r;
                if (row < 8) Sc[row][wv * 16 + lm] = vis ? sc4[r] * SCALE : -INFINITY;
            }
        }
        __syncthreads();
        // online softmax: 8 head-groups x 32 lanes over 64 keys
        {
            float s0 = Sc[hh][lk], s1 = Sc[hh][lk + 32];
            float bmx = fmaxf(s0, s1);
            #pragma unroll
            for (int o = 1; o < 32; o <<= 1) bmx = fmaxf(bmx, __shfl_xor(bmx, o));
            float mn = fmaxf(mh, bmx);         // finite: >=1 visible key per block
            float scl = expf(mh - mn);         // first block: exp(-inf)=0
            float p0 = expf(s0 - mn), p1 = expf(s1 - mn);
            float rs = p0 + p1;
            #pragma unroll
            for (int o = 1; o < 32; o <<= 1) rs += __shfl_xor(rs, o);
            lh = lh * scl + rs;
            mh = mn;
            Pb[hh][lk] = f2bs(p0);
            Pb[hh][lk + 32] = f2bs(p1);
            if (lk == 0) alph[hh] = scl;
        }
        __syncthreads();
        // PV: D[m=head][n=dim-in-tile]; A=Pb, B=V (via Vt)
        {
            bf16x8 ap0 = *(const bf16x8*)&Pb[lm][quad * 8];
            bf16x8 ap1 = *(const bf16x8*)&Pb[lm][32 + quad * 8];
            bf16x8 bv0 = *(const bf16x8*)&Vt[wv * 16 + lm][quad * 8];
            bf16x8 bv1 = *(const bf16x8*)&Vt[wv * 16 + lm][32 + quad * 8];
            #pragma unroll
            for (int r = 0; r < 4; r++) oacc[r] *= alph[(quad * 4 + r) & 7];
            oacc = __builtin_amdgcn_mfma_f32_16x16x32_bf16(ap0, bv0, oacc, 0, 0, 0);
            oacc = __builtin_amdgcn_mfma_f32_16x16x32_bf16(ap1, bv1, oacc, 0, 0, 0);
        }
        __syncthreads();                       // before next Vt overwrite
    }
    if (lk == 0)
        fac[hh] = gates[((size_t)s * HEADS + kvh * 8 + hh) * 3 + 1] / lh;
    __syncthreads();
    #pragma unroll
    for (int r = 0; r < 4; r++) {
        int row = quad * 4 + r;
        if (row < 8)
            attn[(size_t)s * (HEADS * DH) + (kvh * 8 + row) * DH + wv * 16 + lm]
                += oacc[r] * fac[row];
    }
}

// ---------------- sliding window, tiled flash-style: 64 queries x 1 head per block ----------------
__global__ __launch_bounds__(256) void sattn_kernel(
        const float* __restrict__ rq, const float* __restrict__ rk,
        const float* __restrict__ qkv, const float* __restrict__ gates,
        float* __restrict__ attn) {
    int h = blockIdx.x, qb = blockIdx.y;
    int kvh = h >> 3;
    int tid = threadIdx.x;
    int tx = tid & 15, ty = tid >> 4;
    __shared__ float Qs[64][68];
    __shared__ float Ks[64][68];
    __shared__ float Vs[64][68];
    auto& Ps = Ks;
    for (int e = tid; e < 4096; e += 256) {
        int q = e >> 6, d = e & 63;
        Qs[d][q] = rq[(size_t)(qb * 64 + q) * (HEADS * DH) + h * DH + d];
    }
    float m[4], l[4], acc[4][4];
    #pragma unroll
    for (int i = 0; i < 4; i++) {
        m[i] = -INFINITY; l[i] = 0.f;
        #pragma unroll
        for (int j = 0; j < 4; j++) acc[i][j] = 0.f;
    }
    __syncthreads();
    for (int c = 0; c < 9; c++) {
        int kb = qb * 64 - WIN + c * 64;
        if (kb + 63 < 0) continue;
        for (int e = tid; e < 4096; e += 256) {
            int j = e >> 6, d = e & 63;
            int jpos = kb + j;
            float kvl = 0.f, vvl = 0.f;
            if (jpos >= 0) {
                kvl = rk[(size_t)jpos * (KVH * DH) + kvh * DH + d];
                vvl = qkv[(size_t)jpos * QKVC + VOFF + kvh * DH + d];
            }
            Ks[d][j] = kvl;
            Vs[j][d] = vvl;
        }
        __syncthreads();
        float sc[4][4] = {{0.f}};
        for (int d = 0; d < 64; d++) {
            float4 av = *(const float4*)&Qs[d][ty * 4];
            float4 bv = *(const float4*)&Ks[d][tx * 4];
            float a[4] = {av.x, av.y, av.z, av.w};
            float b[4] = {bv.x, bv.y, bv.z, bv.w};
            #pragma unroll
            for (int i = 0; i < 4; i++)
                #pragma unroll
                for (int j = 0; j < 4; j++) sc[i][j] += a[i] * b[j];
        }
        __syncthreads();
        float pv4[4][4];
        #pragma unroll
        for (int i = 0; i < 4; i++) {
            int spos = qb * 64 + ty * 4 + i;
            float tm = -INFINITY;
            #pragma unroll
            for (int j = 0; j < 4; j++) {
                int jpos = kb + tx * 4 + j;
                bool valid = (jpos >= 0) && (jpos <= spos) && (jpos >= spos - WIN);
                sc[i][j] = valid ? sc[i][j] * SCALE : -INFINITY;
                tm = fmaxf(tm, sc[i][j]);
            }
            #pragma unroll
            for (int o = 1; o < 16; o <<= 1) tm = fmaxf(tm, __shfl_xor(tm, o));
            float mn = fmaxf(m[i], tm);
            float sca = (mn == -INFINITY) ? 1.f : expf(m[i] - mn);
            float rs = 0.f;
            #pragma unroll
            for (int j = 0; j < 4; j++) {
                float p = (mn == -INFINITY) ? 0.f : expf(sc[i][j] - mn);
                pv4[i][j] = p;
                rs += p;
            }
            #pragma unroll
            for (int o = 1; o < 16; o <<= 1) rs += __shfl_xor(rs, o);
            l[i] = l[i] * sca + rs;
            m[i] = mn;
            #pragma unroll
            for (int j = 0; j < 4; j++) acc[i][j] *= sca;
        }
        #pragma unroll
        for (int j = 0; j < 4; j++) {
            float4 w = make_float4(pv4[0][j], pv4[1][j], pv4[2][j], pv4[3][j]);
            *(float4*)&Ps[tx * 4 + j][ty * 4] = w;
        }
        __syncthreads();
        for (int jj = 0; jj < 64; jj++) {
            float4 av = *(const float4*)&Ps[jj][ty * 4];
            float4 bv = *(const float4*)&Vs[jj][tx * 4];
            float a[4] = {av.x, av.y, av.z, av.w};
            float b[4] = {bv.x, bv.y, bv.z, bv.w};
            #pragma unroll
            for (int i = 0; i < 4; i++)
                #pragma unroll
                for (int j = 0; j < 4; j++) acc[i][j] += a[i] * b[j];
        }
        __syncthreads();
    }
    #pragma unroll
    for (int i = 0; i < 4; i++) {
        int spos = qb * 64 + ty * 4 + i;
        float g2 = gates[((size_t)spos * HEADS + h) * 3 + 2];
        float sca = g2 / l[i];
        #pragma unroll
        for (int j = 0; j < 4; j++)
            attn[(size_t)spos * (HEADS * DH) + h * DH + tx * 4 + j] += acc[i][j] * sca;
    }
}

// ---------------- launch ----------------
extern "C" void kernel_launch(void* const* d_in, const int* in_sizes, int n_in,
                              void* d_out, int out_size, void* d_ws, size_t ws_size,
                              hipStream_t stream) {
    const float* x      = (const float*)d_in[0];
    const float* rms_g  = (const float*)d_in[1];
    const float* W_qkv  = (const float*)d_in[2];
    const float* k_pos  = (const float*)d_in[3];
    const float* v_pos  = (const float*)d_in[4];
    const float* mem_kv = (const float*)d_in[5];
    const float* kW1    = (const float*)d_in[6];
    const float* kb1    = (const float*)d_in[7];
    const float* kW2    = (const float*)d_in[8];
    const float* kb2    = (const float*)d_in[9];
    const float* vW1    = (const float*)d_in[10];
    const float* vb1    = (const float*)d_in[11];
    const float* vW2    = (const float*)d_in[12];
    const float* vb2    = (const float*)d_in[13];
    const float* W_comb = (const float*)d_in[14];
    const float* b_comb = (const float*)d_in[15];
    const float* W_out  = (const float*)d_in[16];
    float* out = (float*)d_out;

    // workspace layout (floats) — region R (1048576 fl) is time-multiplexed:
    //   steps 1-2.5: xnb (2048*1024 bf16 = 1048576 fl exactly; gates consumes it
    //                BEFORE rotary/cmat clobber R)
    //   step 3+:     rkb (bf16, 262144 elem = 131072 fl) at R+794624..925696
    //   steps 4-8:   kcmb/vcmb (131072 fl each), khid/vhid (262144 fl each),
    //                ckb/cvb (4096 fl each) -> R+0..794624 (disjoint from rkb)
    //   steps 15-16: attnb (1048576 fl; written after fattn consumed rkb)
    float* ws    = (float*)d_ws;
    float* xn    = ws;                                     // 2097152
    float* qkv   = xn    + (size_t)S * DIM;                // 2621440
    float* rq    = qkv   + (size_t)S * QKVC;               // 2097152
    float* rk    = rq    + (size_t)S * HEADS * DH;         // 262144
    float* R     = rk    + (size_t)S * KVH * DH;           // 1048576
    float* ck    = R     + 1048576;                        // 4224
    float* cv    = ck    + (size_t)KVH * (NCB + 1) * DH;   // 4224
    float* imp   = cv    + (size_t)KVH * (NCB + 1) * DH;   // 131072
    float* gates = imp   + (size_t)KVH * S * NCB;          // 98304
    float* attn  = gates + (size_t)S * HEADS * 3;          // 2097152
    int*   sel   = (int*)(attn + (size_t)S * HEADS * DH);  // 32768 ints

    __hip_bfloat16* xnb   = (__hip_bfloat16*)R;            // dead after gates
    __hip_bfloat16* kcmb  = (__hip_bfloat16*)R;            // 262144 bf16 = 131072 fl
    __hip_bfloat16* vcmb  = (__hip_bfloat16*)(R + 131072); // 131072 fl
    float* khid  = R + 262144;                             // 262144 fl
    float* vhid  = R + 524288;                             // 262144 fl
    float* ckb   = R + 786432;                             // 4096 fl
    float* cvb   = R + 790528;                             // 4096 fl (ends 794624)
    short* rkb   = (short*)(R + 794624);                   // 131072 fl (ends 925696)
    __hip_bfloat16* attnb = (__hip_bfloat16*)R;            // reused after fattn
    short* vbb   = (short*)imp;   // 262144 bf16 = 131072 fl (imp dead after select)
    float* partW1 = attn;   // 8*64*4096 = 2097152 (attn live only from step 12)
    float* partW2 = imp;    // 32*64*64 = 131072   (imp live only steps 10-11)

    // 1. RMSNorm (fp32 + bf16)
    rmsnorm_kernel<<<S, 256, 0, stream>>>(x, rms_g, xn, xnb);
    // 2. QKV projection (bf16 MFMA): (2048,1024)@(1024,1280)
    gemm_mfma_kernel<128, 128, 2, 2, 0><<<dim3(QKVC / 128, S / 128, 1), 256, 0, stream>>>(
        xnb, W_qkv, nullptr, qkv, S, QKVC, DIM, DIM);
    // 2.5 gates = sigmoid(xn @ W_comb + b_comb) (bf16 MFMA, N=48 guarded) — uses xnb
    gemm_mfma_kernel<128, 64, 2, 2, 2><<<dim3(1, S / 128, 1), 256, 0, stream>>>(
        xnb, W_comb, b_comb, gates, S, HEADS * 3, DIM, DIM);
    // 3. rotary (also writes bf16 rkb)
    rotary_kernel<<<S, 256, 0, stream>>>(qkv, rq, rk, rkb);
    // 4. compress-MLP inputs (bf16)
    build_cmat_kernel<<<KVH * NCB, 256, 0, stream>>>(qkv, k_pos, v_pos, kcmb, vcmb);
    // 5. k-MLP W1 (bf16 MFMA, split-K 8): relu((64,4096)@(4096,4096)+b)
    gemm_mfma_kernel<64, 128, 1, 4, 0><<<dim3(CDIM / 128, 1, 8), 256, 0, stream>>>(
        kcmb, kW1, nullptr, partW1, 64, CDIM, CDIM, CDIM / 8);
    reduce_splitk_kernel<1><<<(64 * CDIM + 255) / 256, 256, 0, stream>>>(
        partW1, kb1, khid, 64 * CDIM, CDIM, 8);
    // 6. k-MLP W2 (fp32 split-K 32): (64,4096)@(4096,64)+b
    gemm_splitk_kernel<<<dim3(1, 1, 32), 256, 0, stream>>>(khid, kW2, partW2, 64, DH, CDIM, CDIM / 32);
    reduce_splitk_kernel<0><<<(64 * DH + 255) / 256, 256, 0, stream>>>(partW2, kb2, ckb, 64 * DH, DH, 32);
    // 7. v-MLP
    gemm_mfma_kernel<64, 128, 1, 4, 0><<<dim3(CDIM / 128, 1, 8), 256, 0, stream>>>(
        vcmb, vW1, nullptr, partW1, 64, CDIM, CDIM, CDIM / 8);
    reduce_splitk_kernel<1><<<(64 * CDIM + 255) / 256, 256, 0, stream>>>(
        partW1, vb1, vhid, 64 * CDIM, CDIM, 8);
    gemm_splitk_kernel<<<dim3(1, 1, 32), 256, 0, stream>>>(vhid, vW2, partW2, 64, DH, CDIM, CDIM / 32);
    reduce_splitk_kernel<0><<<(64 * DH + 255) / 256, 256, 0, stream>>>(partW2, vb2, cvb, 64 * DH, DH, 32);
    // 8. assemble ck/cv with mem tokens
    assemble_kernel<<<(KVH * (NCB + 1) * DH + 255) / 256, 256, 0, stream>>>(ckb, cvb, mem_kv, ck, cv);
    // 10. block importance
    imp_kernel<<<dim3(KVH, S), 64, 0, stream>>>(qkv, ck, imp);
    // 11. top-8 selection
    select_kernel<<<(KVH * S + 255) / 256, 256, 0, stream>>>(imp, sel);
    // 11.5 cast V cols -> bf16 vbb (reuses imp space, dead after select)
    cast_v_kernel<<<(S * KVH * DH / 4 + 255) / 256, 256, 0, stream>>>(qkv, vbb);
    // 12. compressed attention (writes attn = g0*c_out)
    cattn_kernel<<<dim3(HEADS, S / 64), 256, 0, stream>>>(qkv, ck, cv, gates, attn);
    // 13. fine attention, MFMA (attn += g1*f_out)
    fattn_kernel<<<dim3(KVH, S), 256, 0, stream>>>(rq, rkb, vbb, sel, gates, attn);
    // 14. sliding window (attn += g2*s_out)
    sattn_kernel<<<dim3(HEADS, S / 64), 256, 0, stream>>>(rq, rk, qkv, gates, attn);
    // 15. cast attn -> bf16
    cast_bf16_kernel<<<(S * HEADS * DH / 4 + 255) / 256, 256, 0, stream>>>(
        attn, attnb, S * HEADS * DH / 4);
    // 16. output projection (bf16 MFMA): (2048,1024)@(1024,1024)
    gemm_mfma_kernel<128, 128, 2, 2, 0><<<dim3(DIM / 128, S / 128, 1), 256, 0, stream>>>(
        attnb, W_out, nullptr, out, S, DIM, DIM, DIM);
}

// Round 6
// 619.585 us; speedup vs baseline: 6.4563x; 1.6082x over previous
//
#include <hip/hip_runtime.h>
#include <hip/hip_bf16.h>
#include <cstddef>
#include <cstdint>

// Problem constants (B=1)
#define S      2048
#define DIM    1024
#define HEADS  16
#define KVH    2
#define GQ     8
#define DH     64
#define CBS    64
#define SBS    64
#define NUMSEL 8
#define WIN    512
#define NCB    (S / CBS)      // 32
#define CDIM   (CBS * DH)     // 4096
#define QKVC   (HEADS * DH + 2 * KVH * DH)   // 1280
#define KOFF   (HEADS * DH)                  // 1024 (k cols start)
#define VOFF   (HEADS * DH + KVH * DH)       // 1152 (v cols start)
#define SCALE  0.125f
#define RMS_EPS 1.1920928955078125e-07f

typedef __attribute__((ext_vector_type(8))) short bf16x8;   // 8 bf16 in 4 VGPRs
typedef __attribute__((ext_vector_type(4))) float f32x4;

__device__ inline short f2bs(float f) {
    __hip_bfloat16 b = __float2bfloat16(f);
    return *(short*)&b;
}

// ---------------- wave (64-lane) reductions ----------------
__device__ inline float wave_sum(float v) {
    for (int o = 32; o > 0; o >>= 1) v += __shfl_xor(v, o);
    return v;
}

// ---------------- RMSNorm (writes fp32 + bf16 copies) ----------------
__global__ __launch_bounds__(256) void rmsnorm_kernel(
        const float* __restrict__ x, const float* __restrict__ g,
        float* __restrict__ xn, __hip_bfloat16* __restrict__ xnb) {
    int s = blockIdx.x, tid = threadIdx.x;
    const float4* row = (const float4*)(x + (size_t)s * DIM);
    float4 v = row[tid];
    float ss = v.x * v.x + v.y * v.y + v.z * v.z + v.w * v.w;
    ss = wave_sum(ss);
    __shared__ float red[4];
    if ((tid & 63) == 0) red[tid >> 6] = ss;
    __syncthreads();
    float tot = red[0] + red[1] + red[2] + red[3];
    float sc = rsqrtf(tot / (float)DIM + RMS_EPS);
    float4 gg = ((const float4*)g)[tid];
    float4 o;
    o.x = v.x * sc * gg.x; o.y = v.y * sc * gg.y;
    o.z = v.z * sc * gg.z; o.w = v.w * sc * gg.w;
    ((float4*)(xn + (size_t)s * DIM))[tid] = o;
    size_t b = (size_t)s * DIM + tid * 4;
    xnb[b + 0] = __float2bfloat16(o.x);
    xnb[b + 1] = __float2bfloat16(o.y);
    xnb[b + 2] = __float2bfloat16(o.z);
    xnb[b + 3] = __float2bfloat16(o.w);
}

// ---------------- fp32 -> bf16 cast ----------------
__global__ __launch_bounds__(256) void cast_bf16_kernel(
        const float* __restrict__ in, __hip_bfloat16* __restrict__ out, int n4) {
    int e = blockIdx.x * 256 + threadIdx.x;
    if (e >= n4) return;
    float4 v = ((const float4*)in)[e];
    out[4 * e + 0] = __float2bfloat16(v.x);
    out[4 * e + 1] = __float2bfloat16(v.y);
    out[4 * e + 2] = __float2bfloat16(v.z);
    out[4 * e + 3] = __float2bfloat16(v.w);
}

// ---------------- W (K,N) fp32 -> Wt (N,K) bf16, LDS-tiled transpose ----------------
// Requires K % 64 == 0; N guarded.
__global__ __launch_bounds__(256) void transpose_cast_kernel(
        const float* __restrict__ W, short* __restrict__ Wt, int K, int N) {
    __shared__ float tile[64][65];
    int n0 = blockIdx.x * 64, k0 = blockIdx.y * 64;
    int tid = threadIdx.x;
    #pragma unroll
    for (int e = 0; e < 16; e++) {
        int idx = tid + e * 256;
        int r = idx >> 6, c = idx & 63;
        float v = 0.f;
        if (n0 + c < N) v = W[(size_t)(k0 + r) * N + n0 + c];
        tile[r][c] = v;
    }
    __syncthreads();
    #pragma unroll
    for (int e = 0; e < 16; e++) {
        int idx = tid + e * 256;
        int r = idx >> 6, c = idx & 63;      // r = n-in-tile, c = k-in-tile
        if (n0 + r < N)
            Wt[(size_t)(n0 + r) * K + k0 + c] = f2bs(tile[c][r]);
    }
}

// ---------------- extract V columns of qkv -> vb (S, KVH, DH) bf16 ----------------
__global__ __launch_bounds__(256) void cast_v_kernel(
        const float* __restrict__ qkv, short* __restrict__ vb) {
    int e = blockIdx.x * 256 + threadIdx.x;    // e4 over S*KVH*DH/4
    if (e >= S * KVH * DH / 4) return;
    int idx = e * 4;
    int tok = idx / (KVH * DH), rem = idx % (KVH * DH);
    float4 v = *(const float4*)(qkv + (size_t)tok * QKVC + VOFF + rem);
    vb[idx + 0] = f2bs(v.x);
    vb[idx + 1] = f2bs(v.y);
    vb[idx + 2] = f2bs(v.z);
    vb[idx + 3] = f2bs(v.w);
}

// ---------------- bf16 B^T MFMA GEMM: C = act(A(bf16,MxK) @ Bt^T(N,K bf16) + bias) ---
// Both operands staged with bf16x8 vector loads. N guarded (gates). M%BM==0, K%32==0.
template <int BM, int BN, int WM, int WN, int ACT>
__global__ __launch_bounds__(256) void gemm_bt_kernel(
        const __hip_bfloat16* __restrict__ A, const short* __restrict__ Bt,
        const float* __restrict__ bias, float* __restrict__ C,
        int M, int N, int K) {
    constexpr int BK = 32;
    constexpr int TM = BM / (WM * 16);
    constexpr int TN = BN / (WN * 16);
    constexpr int LDK = BK + 8;   // stride 40 bf16 = 20 dwords (2-way free on frag reads)
    __shared__ short As[BM][LDK];
    __shared__ short Bs[BN][LDK];
    int tid = threadIdx.x;
    int wave = tid >> 6, lane = tid & 63;
    int wm = wave % WM, wn = wave / WM;
    int m0 = wm * TM * 16, n0 = wn * TN * 16;
    int bm = blockIdx.y * BM, bn = blockIdx.x * BN;
    int lm = lane & 15, quad = lane >> 4;
    const short* Ash = (const short*)A;
    f32x4 acc[TM][TN] = {};
    for (int k0 = 0; k0 < K; k0 += BK) {
        #pragma unroll
        for (int e = 0; e < BM * BK / (256 * 8); e++) {
            int idx = (tid + e * 256) * 8;
            int r = idx >> 5, kk = idx & 31;
            *(bf16x8*)(&As[r][kk]) =
                *(const bf16x8*)(Ash + (size_t)(bm + r) * K + k0 + kk);
        }
        #pragma unroll
        for (int e = 0; e < BN * BK / (256 * 8); e++) {
            int idx = (tid + e * 256) * 8;
            int r = idx >> 5, kk = idx & 31;
            bf16x8 v = {};
            if (bn + r < N)
                v = *(const bf16x8*)(Bt + (size_t)(bn + r) * K + k0 + kk);
            *(bf16x8*)(&Bs[r][kk]) = v;
        }
        __syncthreads();
        bf16x8 af[TM], bf_[TN];
        #pragma unroll
        for (int i = 0; i < TM; i++)
            af[i] = *(const bf16x8*)(&As[m0 + i * 16 + lm][quad * 8]);
        #pragma unroll
        for (int j = 0; j < TN; j++)
            bf_[j] = *(const bf16x8*)(&Bs[n0 + j * 16 + lm][quad * 8]);
        #pragma unroll
        for (int i = 0; i < TM; i++)
            #pragma unroll
            for (int j = 0; j < TN; j++)
                acc[i][j] = __builtin_amdgcn_mfma_f32_16x16x32_bf16(
                    af[i], bf_[j], acc[i][j], 0, 0, 0);
        __syncthreads();
    }
    #pragma unroll
    for (int i = 0; i < TM; i++) {
        #pragma unroll
        for (int j = 0; j < TN; j++) {
            int gn = bn + n0 + j * 16 + lm;
            if (gn >= N) continue;
            #pragma unroll
            for (int r = 0; r < 4; r++) {
                int gm = bm + m0 + i * 16 + quad * 4 + r;
                float v = acc[i][j][r];
                if (bias) v += bias[gn];
                if (ACT == 2) v = 1.f / (1.f + expf(-v));
                C[(size_t)gm * N + gn] = v;
            }
        }
    }
}

// ---------------- bf16 MFMA GEMM, fp32 B (cast in-staging, two-phase) ---------------
// Used for the W1 MLP GEMMs (split-K via blockIdx.z, fp32 partials at C + z*M*N).
template <int BM, int BN, int WM, int WN>
__global__ __launch_bounds__(256) void gemm_mfma_kernel(
        const __hip_bfloat16* __restrict__ A, const float* __restrict__ B,
        float* __restrict__ C, int M, int N, int K, int kslice) {
    constexpr int BK = 32;
    constexpr int TM = BM / (WM * 16);
    constexpr int TN = BN / (WN * 16);
    constexpr int LDK = BK + 8;
    constexpr int NB = BN * BK / 256;
    __shared__ __hip_bfloat16 As[BM][LDK];
    __shared__ __hip_bfloat16 Bs[BN][LDK];
    int tid = threadIdx.x;
    int wave = tid >> 6, lane = tid & 63;
    int wm = wave % WM, wn = wave / WM;
    int m0 = wm * TM * 16, n0 = wn * TN * 16;
    int bm = blockIdx.y * BM, bn = blockIdx.x * BN;
    int kbeg = blockIdx.z * kslice, kend = kbeg + kslice;
    int lm = lane & 15, quad = lane >> 4;
    f32x4 acc[TM][TN] = {};
    for (int k0 = kbeg; k0 < kend; k0 += BK) {
        #pragma unroll
        for (int e = 0; e < BM * BK / (256 * 8); e++) {
            int idx = (tid + e * 256) * 8;
            int r = idx >> 5, kk = idx & 31;
            *(bf16x8*)(&As[r][kk]) =
                *(const bf16x8*)(A + (size_t)(bm + r) * K + k0 + kk);
        }
        // two-phase B staging: batch ALL loads, then convert+store (one vmcnt drain)
        float tmpB[NB];
        #pragma unroll
        for (int e = 0; e < NB; e++) {
            int idx = tid + e * 256;
            int kk = idx / BN, n = idx % BN;
            tmpB[e] = B[(size_t)(k0 + kk) * N + bn + n];
        }
        #pragma unroll
        for (int e = 0; e < NB; e++) {
            int idx = tid + e * 256;
            int kk = idx / BN, n = idx % BN;
            Bs[n][kk] = __float2bfloat16(tmpB[e]);
        }
        __syncthreads();
        bf16x8 af[TM], bf_[TN];
        #pragma unroll
        for (int i = 0; i < TM; i++)
            af[i] = *(const bf16x8*)(&As[m0 + i * 16 + lm][quad * 8]);
        #pragma unroll
        for (int j = 0; j < TN; j++)
            bf_[j] = *(const bf16x8*)(&Bs[n0 + j * 16 + lm][quad * 8]);
        #pragma unroll
        for (int i = 0; i < TM; i++)
            #pragma unroll
            for (int j = 0; j < TN; j++)
                acc[i][j] = __builtin_amdgcn_mfma_f32_16x16x32_bf16(
                    af[i], bf_[j], acc[i][j], 0, 0, 0);
        __syncthreads();
    }
    size_t cbase = (size_t)blockIdx.z * M * N;
    #pragma unroll
    for (int i = 0; i < TM; i++) {
        #pragma unroll
        for (int j = 0; j < TN; j++) {
            int gn = bn + n0 + j * 16 + lm;
            #pragma unroll
            for (int r = 0; r < 4; r++) {
                int gm = bm + m0 + i * 16 + quad * 4 + r;
                C[cbase + (size_t)gm * N + gn] = acc[i][j][r];
            }
        }
    }
}

// ---------------- split-K fp32 GEMM (partials) — for the tiny W2 matmuls ----------------
__global__ __launch_bounds__(256) void gemm_splitk_kernel(
        const float* __restrict__ A, const float* __restrict__ B,
        float* __restrict__ P, int M, int N, int K, int kslice) {
    const int BM = 64, BN = 64, BK = 16;
    __shared__ float As[BK][BM + 4];
    __shared__ float Bs[BK][BN];
    int bm = blockIdx.y * BM, bn = blockIdx.x * BN;
    int z = blockIdx.z;
    int kbeg = z * kslice, kend = kbeg + kslice;
    int tid = threadIdx.x;
    int tx = tid & 15, ty = tid >> 4;
    float acc[4][4] = {{0.f}};
    for (int k0 = kbeg; k0 < kend; k0 += BK) {
        #pragma unroll
        for (int e = 0; e < 4; e++) {
            int idx = tid + e * 256;
            int m = idx >> 4, kk = idx & 15;
            int gm = bm + m;
            As[kk][m] = (gm < M) ? A[(size_t)gm * K + k0 + kk] : 0.f;
        }
        #pragma unroll
        for (int e = 0; e < 4; e++) {
            int idx = tid + e * 256;
            int kk = idx >> 6, n = idx & 63;
            int gn = bn + n;
            Bs[kk][n] = (gn < N) ? B[(size_t)(k0 + kk) * N + gn] : 0.f;
        }
        __syncthreads();
        #pragma unroll
        for (int kk = 0; kk < BK; kk++) {
            float a[4], b[4];
            #pragma unroll
            for (int i = 0; i < 4; i++) a[i] = As[kk][ty * 4 + i];
            #pragma unroll
            for (int j = 0; j < 4; j++) b[j] = Bs[kk][tx * 4 + j];
            #pragma unroll
            for (int i = 0; i < 4; i++)
                #pragma unroll
                for (int j = 0; j < 4; j++) acc[i][j] += a[i] * b[j];
        }
        __syncthreads();
    }
    #pragma unroll
    for (int i = 0; i < 4; i++) {
        int gm = bm + ty * 4 + i;
        if (gm >= M) continue;
        #pragma unroll
        for (int j = 0; j < 4; j++) {
            int gn = bn + tx * 4 + j;
            if (gn >= N) continue;
            P[((size_t)z * M + gm) * N + gn] = acc[i][j];
        }
    }
}

template <int ACT>
__global__ __launch_bounds__(256) void reduce_splitk_kernel(
        const float* __restrict__ P, const float* __restrict__ bias,
        float* __restrict__ C, int MN, int N, int splits) {
    int e = blockIdx.x * 256 + threadIdx.x;
    if (e >= MN) return;
    float s = 0.f;
    for (int z = 0; z < splits; z++) s += P[(size_t)z * MN + e];
    s += bias[e % N];
    if (ACT == 1) s = fmaxf(s, 0.f);
    C[e] = s;
}

// ---------------- rotary embedding (interleaved pairs, theta=10000) ----------------
// also emits bf16 rk copy (rkb) for the MFMA fine-attention
__global__ __launch_bounds__(256) void rotary_kernel(
        const float* __restrict__ qkv, float* __restrict__ rq, float* __restrict__ rk,
        short* __restrict__ rkb) {
    int s = blockIdx.x, tid = threadIdx.x;
    for (int p = tid; p < (HEADS + KVH) * (DH / 2); p += 256) {
        int t; const float* src; float* dst; short* dst2 = nullptr;
        if (p < HEADS * (DH / 2)) {
            int h = p >> 5; t = p & 31;
            src = qkv + (size_t)s * QKVC + h * DH + 2 * t;
            dst = rq + (size_t)s * (HEADS * DH) + h * DH + 2 * t;
        } else {
            int pp = p - HEADS * (DH / 2);
            int h = pp >> 5; t = pp & 31;
            src = qkv + (size_t)s * QKVC + KOFF + h * DH + 2 * t;
            dst = rk + (size_t)s * (KVH * DH) + h * DH + 2 * t;
            dst2 = rkb + (size_t)s * (KVH * DH) + h * DH + 2 * t;
        }
        float u0 = src[0], u1 = src[1];
        float freq = powf(10000.f, -((float)(2 * t) / (float)DH));
        float ang = (float)s * freq;
        float sn, cs;
        sincosf(ang, &sn, &cs);
        float o0 = u0 * cs - u1 * sn;
        float o1 = u1 * cs + u0 * sn;
        dst[0] = o0;
        dst[1] = o1;
        if (dst2) { dst2[0] = f2bs(o0); dst2[1] = f2bs(o1); }
    }
}

// ---------------- build compress-MLP input matrices (bf16 output) ----------------
__global__ __launch_bounds__(256) void build_cmat_kernel(
        const float* __restrict__ qkv, const float* __restrict__ k_pos,
        const float* __restrict__ v_pos, __hip_bfloat16* __restrict__ kcm,
        __hip_bfloat16* __restrict__ vcm) {
    int r = blockIdx.x;          // r = h*32 + w
    int h = r >> 5, w = r & 31;
    for (int e = threadIdx.x; e < CDIM; e += 256) {
        int i = e >> 6, d = e & 63;
        size_t qb = (size_t)(w * CBS + i) * QKVC;
        kcm[(size_t)r * CDIM + e] =
            __float2bfloat16(qkv[qb + KOFF + h * DH + d] + k_pos[(h * CBS + i) * DH + d]);
        vcm[(size_t)r * CDIM + e] =
            __float2bfloat16(qkv[qb + VOFF + h * DH + d] + v_pos[(h * CBS + i) * DH + d]);
    }
}

// ---------------- assemble ck/cv: prepend mem_kv -> (KVH, 33, DH) ----------------
__global__ __launch_bounds__(256) void assemble_kernel(
        const float* __restrict__ ckb, const float* __restrict__ cvb,
        const float* __restrict__ mem_kv, float* __restrict__ ck, float* __restrict__ cv) {
    int e = blockIdx.x * 256 + threadIdx.x;
    if (e >= KVH * (NCB + 1) * DH) return;
    int d = e & 63;
    int j = (e >> 6) % (NCB + 1);
    int h = e / ((NCB + 1) * DH);
    if (j == 0) {
        ck[e] = mem_kv[0 * KVH * DH + h * DH + d];
        cv[e] = mem_kv[1 * KVH * DH + h * DH + d];
    } else {
        ck[e] = ckb[((size_t)h * NCB + j - 1) * DH + d];
        cv[e] = cvb[((size_t)h * NCB + j - 1) * DH + d];
    }
}

// ---------------- block importance: imp[kvh][s][w] ----------------
__global__ __launch_bounds__(64) void imp_kernel(
        const float* __restrict__ qkv, const float* __restrict__ ck,
        float* __restrict__ imp) {
    int kvh = blockIdx.x, s = blockIdx.y, t = threadIdx.x;
    __shared__ float qg[GQ * DH];
    __shared__ float ckl[NCB * 65];
    for (int e = t; e < GQ * DH; e += 64) {
        int g = e >> 6, d = e & 63;
        qg[e] = qkv[(size_t)s * QKVC + (kvh * GQ + g) * DH + d];
    }
    for (int e = t; e < NCB * DH; e += 64) {
        int w = e >> 6, d = e & 63;
        ckl[w * 65 + d] = ck[((size_t)kvh * (NCB + 1) + 1 + w) * DH + d];
    }
    __syncthreads();
    if (t < NCB) {
        int w = t;
        float val;
        if (w * CBS + CBS - 1 < s) {
            float acc = 0.f;
            #pragma unroll
            for (int g = 0; g < GQ; g++) {
                const float* qp = qg + g * DH;
                const float* cp = ckl + w * 65;
                #pragma unroll 16
                for (int d = 0; d < DH; d++) acc += qp[d] * cp[d];
            }
            val = acc * SCALE * (1.f / (float)GQ);
        } else {
            val = -INFINITY;
        }
        imp[((size_t)kvh * S + s) * NCB + w] = val;
    }
}

// ---------------- top-8 selection (replicates lax.top_k stable ties) ----------------
__global__ __launch_bounds__(256) void select_kernel(
        const float* __restrict__ imp, int* __restrict__ sel) {
    int idx = blockIdx.x * 256 + threadIdx.x;
    if (idx >= KVH * S) return;
    const float* row = imp + (size_t)idx * NCB;
    float p[NCB];
    float m = -1000.f;
    for (int w = 0; w < NCB; w++) { p[w] = row[w]; m = fmaxf(m, p[w]); }
    float z = expf(-1000.f - m);
    for (int w = 0; w < NCB; w++) { p[w] = expf(p[w] - m); z += p[w]; }
    float inv = 1.f / z;
    bool used[NCB];
    for (int w = 0; w < NCB; w++) used[w] = false;
    for (int i = 0; i < NUMSEL; i++) {
        int best = 0; float bv = -1.f;
        for (int w = 0; w < NCB; w++) {
            if (!used[w]) {
                float pw = p[w] * inv;
                if (pw > bv) { bv = pw; best = w; }
            }
        }
        used[best] = true;
        sel[(size_t)idx * NUMSEL + i] = (bv > 1e-10f) ? best : -1;
    }
}

// ---------------- compressed attention, tiled: 64 queries x 1 head per block ----------------
__global__ __launch_bounds__(256) void cattn_kernel(
        const float* __restrict__ qkv, const float* __restrict__ ck,
        const float* __restrict__ cv, const float* __restrict__ gates,
        float* __restrict__ attn) {
    int h = blockIdx.x, qb = blockIdx.y;
    int kvh = h >> 3;
    int tid = threadIdx.x;
    int tx = tid & 15, ty = tid >> 4;
    __shared__ float Qs[64][68];   // [d][q]
    __shared__ float Ks[64][68];   // [d][j]; aliased by Ps[j][q] after scores
    __shared__ float Vs[64][68];   // [j][d]
    auto& Ps = Ks;
    for (int e = tid; e < 4096; e += 256) {
        int q = e >> 6, d = e & 63;
        Qs[d][q] = qkv[(size_t)(qb * 64 + q) * QKVC + h * DH + d];
    }
    for (int e = tid; e < 4096; e += 256) {
        int j = e >> 6, d = e & 63;
        float kvl = 0.f, vvl = 0.f;
        if (j < NCB + 1) {
            kvl = ck[((size_t)kvh * (NCB + 1) + j) * DH + d];
            vvl = cv[((size_t)kvh * (NCB + 1) + j) * DH + d];
        }
        Ks[d][j] = kvl;
        Vs[j][d] = vvl;
    }
    __syncthreads();
    float sc[4][4] = {{0.f}};
    for (int d = 0; d < 64; d++) {
        float4 av = *(const float4*)&Qs[d][ty * 4];
        float4 bv = *(const float4*)&Ks[d][tx * 4];
        float a[4] = {av.x, av.y, av.z, av.w};
        float b[4] = {bv.x, bv.y, bv.z, bv.w};
        #pragma unroll
        for (int i = 0; i < 4; i++)
            #pragma unroll
            for (int j = 0; j < 4; j++) sc[i][j] += a[i] * b[j];
    }
    __syncthreads();
    float l[4];
    float pv4[4][4];
    #pragma unroll
    for (int i = 0; i < 4; i++) {
        int spos = qb * 64 + ty * 4 + i;
        float tm = -INFINITY;
        #pragma unroll
        for (int j = 0; j < 4; j++) {
            int jj = tx * 4 + j;
            bool vis = (jj == 0) || ((jj <= NCB) && (jj * 64 <= spos));
            sc[i][j] = vis ? sc[i][j] * SCALE : -INFINITY;
            tm = fmaxf(tm, sc[i][j]);
        }
        #pragma unroll
        for (int o = 1; o < 16; o <<= 1) tm = fmaxf(tm, __shfl_xor(tm, o));
        float rs = 0.f;
        #pragma unroll
        for (int j = 0; j < 4; j++) {
            float p = expf(sc[i][j] - tm);
            pv4[i][j] = p;
            rs += p;
        }
        #pragma unroll
        for (int o = 1; o < 16; o <<= 1) rs += __shfl_xor(rs, o);
        l[i] = rs;
    }
    #pragma unroll
    for (int j = 0; j < 4; j++) {
        float4 w = make_float4(pv4[0][j], pv4[1][j], pv4[2][j], pv4[3][j]);
        *(float4*)&Ps[tx * 4 + j][ty * 4] = w;
    }
    __syncthreads();
    float acc[4][4] = {{0.f}};
    for (int jj = 0; jj < 64; jj++) {
        float4 av = *(const float4*)&Ps[jj][ty * 4];
        float4 bv = *(const float4*)&Vs[jj][tx * 4];
        float a[4] = {av.x, av.y, av.z, av.w};
        float b[4] = {bv.x, bv.y, bv.z, bv.w};
        #pragma unroll
        for (int i = 0; i < 4; i++)
            #pragma unroll
            for (int j = 0; j < 4; j++) acc[i][j] += a[i] * b[j];
    }
    #pragma unroll
    for (int i = 0; i < 4; i++) {
        int spos = qb * 64 + ty * 4 + i;
        float g0 = gates[((size_t)spos * HEADS + h) * 3 + 0];
        float sca = g0 / l[i];
        #pragma unroll
        for (int j = 0; j < 4; j++)
            attn[(size_t)spos * (HEADS * DH) + h * DH + tx * 4 + j] = acc[i][j] * sca;
    }
}

// ---------------- fine attention: MFMA flash, one block per (kvh, s) ----------------
__global__ __launch_bounds__(256) void fattn_kernel(
        const float* __restrict__ rq, const short* __restrict__ rkb,
        const short* __restrict__ vb, const int* __restrict__ sel,
        const float* __restrict__ gates, float* __restrict__ attn) {
    int kvh = blockIdx.x, s = blockIdx.y;
    int tid = threadIdx.x;
    int wv = tid >> 6, lane = tid & 63;
    int lm = lane & 15, quad = lane >> 4;
    int hh = tid >> 5, lk = tid & 31;          // softmax mapping: 8 groups x 32 lanes
    __shared__ short Qb[16][68];               // [head][d] bf16 (heads 8-15 garbage)
    __shared__ short Vt[64][68];               // [d][key] bf16 (V^T)
    __shared__ short Pb[16][68];               // [head][key] bf16 probs
    __shared__ float Sc[8][68];                // [head][key] fp32 scores
    __shared__ float alph[8], fac[8];
    __shared__ int bl[9];
    for (int e = tid; e < 512; e += 256) {
        int h = e >> 6, d = e & 63;
        Qb[h][d] = f2bs(rq[(size_t)s * (HEADS * DH) + (kvh * 8 + h) * DH + d]);
    }
    if (tid < NUMSEL) bl[tid] = sel[((size_t)kvh * S + s) * NUMSEL + tid];
    if (tid == NUMSEL) bl[NUMSEL] = s >> 6;
    __syncthreads();
    bf16x8 aq0 = *(const bf16x8*)&Qb[lm][quad * 8];
    bf16x8 aq1 = *(const bf16x8*)&Qb[lm][32 + quad * 8];
    float mh = -INFINITY, lh = 0.f;
    f32x4 oacc = {0.f, 0.f, 0.f, 0.f};
    for (int i = 0; i < 9; i++) {
        int w = bl[i];
        if (i < NUMSEL && w < 0) continue;     // uniform across block
        #pragma unroll
        for (int r = 0; r < 2; r++) {
            int idx = tid + r * 256;           // 0..511
            int c8 = idx >> 6, j = idx & 63;
            bf16x8 vv = *(const bf16x8*)(vb + ((size_t)(w * SBS + j) * KVH + kvh) * DH + c8 * 8);
            #pragma unroll
            for (int t = 0; t < 8; t++) Vt[c8 * 8 + t][j] = vv[t];
        }
        {
            const short* kp = rkb + ((size_t)(w * SBS + wv * 16 + lm) * KVH + kvh) * DH;
            bf16x8 bk0 = *(const bf16x8*)(kp + quad * 8);
            bf16x8 bk1 = *(const bf16x8*)(kp + 32 + quad * 8);
            f32x4 sc4 = {0.f, 0.f, 0.f, 0.f};
            sc4 = __builtin_amdgcn_mfma_f32_16x16x32_bf16(aq0, bk0, sc4, 0, 0, 0);
            sc4 = __builtin_amdgcn_mfma_f32_16x16x32_bf16(aq1, bk1, sc4, 0, 0, 0);
            bool vis = (i < NUMSEL) || (wv * 16 + lm <= (s & 63));
            #pragma unroll
            for (int r = 0; r < 4; r++) {
                int row = quad * 4 + r;
                if (row < 8) Sc[row][wv * 16 + lm] = vis ? sc4[r] * SCALE : -INFINITY;
            }
        }
        __syncthreads();
        {
            float s0 = Sc[hh][lk], s1 = Sc[hh][lk + 32];
            float bmx = fmaxf(s0, s1);
            #pragma unroll
            for (int o = 1; o < 32; o <<= 1) bmx = fmaxf(bmx, __shfl_xor(bmx, o));
            float mn = fmaxf(mh, bmx);
            float scl = expf(mh - mn);
            float p0 = expf(s0 - mn), p1 = expf(s1 - mn);
            float rs = p0 + p1;
            #pragma unroll
            for (int o = 1; o < 32; o <<= 1) rs += __shfl_xor(rs, o);
            lh = lh * scl + rs;
            mh = mn;
            Pb[hh][lk] = f2bs(p0);
            Pb[hh][lk + 32] = f2bs(p1);
            if (lk == 0) alph[hh] = scl;
        }
        __syncthreads();
        {
            bf16x8 ap0 = *(const bf16x8*)&Pb[lm][quad * 8];
            bf16x8 ap1 = *(const bf16x8*)&Pb[lm][32 + quad * 8];
            bf16x8 bv0 = *(const bf16x8*)&Vt[wv * 16 + lm][quad * 8];
            bf16x8 bv1 = *(const bf16x8*)&Vt[wv * 16 + lm][32 + quad * 8];
            #pragma unroll
            for (int r = 0; r < 4; r++) oacc[r] *= alph[(quad * 4 + r) & 7];
            oacc = __builtin_amdgcn_mfma_f32_16x16x32_bf16(ap0, bv0, oacc, 0, 0, 0);
            oacc = __builtin_amdgcn_mfma_f32_16x16x32_bf16(ap1, bv1, oacc, 0, 0, 0);
        }
        __syncthreads();
    }
    if (lk == 0)
        fac[hh] = gates[((size_t)s * HEADS + kvh * 8 + hh) * 3 + 1] / lh;
    __syncthreads();
    #pragma unroll
    for (int r = 0; r < 4; r++) {
        int row = quad * 4 + r;
        if (row < 8)
            attn[(size_t)s * (HEADS * DH) + (kvh * 8 + row) * DH + wv * 16 + lm]
                += oacc[r] * fac[row];
    }
}

// ---------------- sliding window, tiled flash-style: 64 queries x 1 head per block ----------------
__global__ __launch_bounds__(256) void sattn_kernel(
        const float* __restrict__ rq, const float* __restrict__ rk,
        const float* __restrict__ qkv, const float* __restrict__ gates,
        float* __restrict__ attn) {
    int h = blockIdx.x, qb = blockIdx.y;
    int kvh = h >> 3;
    int tid = threadIdx.x;
    int tx = tid & 15, ty = tid >> 4;
    __shared__ float Qs[64][68];
    __shared__ float Ks[64][68];
    __shared__ float Vs[64][68];
    auto& Ps = Ks;
    for (int e = tid; e < 4096; e += 256) {
        int q = e >> 6, d = e & 63;
        Qs[d][q] = rq[(size_t)(qb * 64 + q) * (HEADS * DH) + h * DH + d];
    }
    float m[4], l[4], acc[4][4];
    #pragma unroll
    for (int i = 0; i < 4; i++) {
        m[i] = -INFINITY; l[i] = 0.f;
        #pragma unroll
        for (int j = 0; j < 4; j++) acc[i][j] = 0.f;
    }
    __syncthreads();
    for (int c = 0; c < 9; c++) {
        int kb = qb * 64 - WIN + c * 64;
        if (kb + 63 < 0) continue;
        for (int e = tid; e < 4096; e += 256) {
            int j = e >> 6, d = e & 63;
            int jpos = kb + j;
            float kvl = 0.f, vvl = 0.f;
            if (jpos >= 0) {
                kvl = rk[(size_t)jpos * (KVH * DH) + kvh * DH + d];
                vvl = qkv[(size_t)jpos * QKVC + VOFF + kvh * DH + d];
            }
            Ks[d][j] = kvl;
            Vs[j][d] = vvl;
        }
        __syncthreads();
        float sc[4][4] = {{0.f}};
        for (int d = 0; d < 64; d++) {
            float4 av = *(const float4*)&Qs[d][ty * 4];
            float4 bv = *(const float4*)&Ks[d][tx * 4];
            float a[4] = {av.x, av.y, av.z, av.w};
            float b[4] = {bv.x, bv.y, bv.z, bv.w};
            #pragma unroll
            for (int i = 0; i < 4; i++)
                #pragma unroll
                for (int j = 0; j < 4; j++) sc[i][j] += a[i] * b[j];
        }
        __syncthreads();
        float pv4[4][4];
        #pragma unroll
        for (int i = 0; i < 4; i++) {
            int spos = qb * 64 + ty * 4 + i;
            float tm = -INFINITY;
            #pragma unroll
            for (int j = 0; j < 4; j++) {
                int jpos = kb + tx * 4 + j;
                bool valid = (jpos >= 0) && (jpos <= spos) && (jpos >= spos - WIN);
                sc[i][j] = valid ? sc[i][j] * SCALE : -INFINITY;
                tm = fmaxf(tm, sc[i][j]);
            }
            #pragma unroll
            for (int o = 1; o < 16; o <<= 1) tm = fmaxf(tm, __shfl_xor(tm, o));
            float mn = fmaxf(m[i], tm);
            float sca = (mn == -INFINITY) ? 1.f : expf(m[i] - mn);
            float rs = 0.f;
            #pragma unroll
            for (int j = 0; j < 4; j++) {
                float p = (mn == -INFINITY) ? 0.f : expf(sc[i][j] - mn);
                pv4[i][j] = p;
                rs += p;
            }
            #pragma unroll
            for (int o = 1; o < 16; o <<= 1) rs += __shfl_xor(rs, o);
            l[i] = l[i] * sca + rs;
            m[i] = mn;
            #pragma unroll
            for (int j = 0; j < 4; j++) acc[i][j] *= sca;
        }
        #pragma unroll
        for (int j = 0; j < 4; j++) {
            float4 w = make_float4(pv4[0][j], pv4[1][j], pv4[2][j], pv4[3][j]);
            *(float4*)&Ps[tx * 4 + j][ty * 4] = w;
        }
        __syncthreads();
        for (int jj = 0; jj < 64; jj++) {
            float4 av = *(const float4*)&Ps[jj][ty * 4];
            float4 bv = *(const float4*)&Vs[jj][tx * 4];
            float a[4] = {av.x, av.y, av.z, av.w};
            float b[4] = {bv.x, bv.y, bv.z, bv.w};
            #pragma unroll
            for (int i = 0; i < 4; i++)
                #pragma unroll
                for (int j = 0; j < 4; j++) acc[i][j] += a[i] * b[j];
        }
        __syncthreads();
    }
    #pragma unroll
    for (int i = 0; i < 4; i++) {
        int spos = qb * 64 + ty * 4 + i;
        float g2 = gates[((size_t)spos * HEADS + h) * 3 + 2];
        float sca = g2 / l[i];
        #pragma unroll
        for (int j = 0; j < 4; j++)
            attn[(size_t)spos * (HEADS * DH) + h * DH + tx * 4 + j] += acc[i][j] * sca;
    }
}

// ---------------- launch ----------------
extern "C" void kernel_launch(void* const* d_in, const int* in_sizes, int n_in,
                              void* d_out, int out_size, void* d_ws, size_t ws_size,
                              hipStream_t stream) {
    const float* x      = (const float*)d_in[0];
    const float* rms_g  = (const float*)d_in[1];
    const float* W_qkv  = (const float*)d_in[2];
    const float* k_pos  = (const float*)d_in[3];
    const float* v_pos  = (const float*)d_in[4];
    const float* mem_kv = (const float*)d_in[5];
    const float* kW1    = (const float*)d_in[6];
    const float* kb1    = (const float*)d_in[7];
    const float* kW2    = (const float*)d_in[8];
    const float* kb2    = (const float*)d_in[9];
    const float* vW1    = (const float*)d_in[10];
    const float* vb1    = (const float*)d_in[11];
    const float* vW2    = (const float*)d_in[12];
    const float* vb2    = (const float*)d_in[13];
    const float* W_comb = (const float*)d_in[14];
    const float* b_comb = (const float*)d_in[15];
    const float* W_out  = (const float*)d_in[16];
    float* out = (float*)d_out;

    // workspace layout (floats) — region R (1048576 fl) is time-multiplexed:
    //   steps 1-2.5: xnb (bf16, exactly R); steps 4-8: MLP scratch 0..794624 +
    //   rkb at 794624..925696 (step 3+); steps 15-16: attnb (R again).
    float* ws    = (float*)d_ws;
    float* xn    = ws;                                     // 2097152
    float* qkv   = xn    + (size_t)S * DIM;                // 2621440
    float* rq    = qkv   + (size_t)S * QKVC;               // 2097152
    float* rk    = rq    + (size_t)S * HEADS * DH;         // 262144
    float* R     = rk    + (size_t)S * KVH * DH;           // 1048576
    float* ck    = R     + 1048576;                        // 4224
    float* cv    = ck    + (size_t)KVH * (NCB + 1) * DH;   // 4224
    float* imp   = cv    + (size_t)KVH * (NCB + 1) * DH;   // 131072
    float* gates = imp   + (size_t)KVH * S * NCB;          // 98304
    float* attn  = gates + (size_t)S * HEADS * 3;          // 2097152
    int*   sel   = (int*)(attn + (size_t)S * HEADS * DH);  // 32768 ints
    // pre-transposed bf16 weights (new, persistent within a launch)
    float* WT    = attn + (size_t)S * HEADS * DH + 32768;
    short* wqkvT = (short*)WT;                             // 1280*1024 bf16 = 655360 fl
    short* woutT = (short*)(WT + 655360);                  // 1024*1024 bf16 = 524288 fl
    short* wcombT= (short*)(WT + 655360 + 524288);         // 48*1024 bf16 = 24576 fl

    __hip_bfloat16* xnb   = (__hip_bfloat16*)R;            // dead after gates
    __hip_bfloat16* kcmb  = (__hip_bfloat16*)R;            // 262144 bf16 = 131072 fl
    __hip_bfloat16* vcmb  = (__hip_bfloat16*)(R + 131072); // 131072 fl
    float* khid  = R + 262144;                             // 262144 fl
    float* vhid  = R + 524288;                             // 262144 fl
    float* ckb   = R + 786432;                             // 4096 fl
    float* cvb   = R + 790528;                             // 4096 fl (ends 794624)
    short* rkb   = (short*)(R + 794624);                   // 131072 fl (ends 925696)
    __hip_bfloat16* attnb = (__hip_bfloat16*)R;            // reused after fattn
    short* vbb   = (short*)imp;   // 262144 bf16 (imp dead after select)
    float* partW1 = attn;   // 8*64*4096 = 2097152 (attn live only from step 12)
    float* partW2 = imp;    // 32*64*64 = 131072   (imp live only steps 10-11)

    // 0. pre-transpose+cast weights to bf16 B^T (independent of everything)
    transpose_cast_kernel<<<dim3(QKVC / 64, DIM / 64), 256, 0, stream>>>(W_qkv, wqkvT, DIM, QKVC);
    transpose_cast_kernel<<<dim3(DIM / 64, DIM / 64), 256, 0, stream>>>(W_out, woutT, DIM, DIM);
    transpose_cast_kernel<<<dim3(1, DIM / 64), 256, 0, stream>>>(W_comb, wcombT, DIM, HEADS * 3);
    // 1. RMSNorm (fp32 + bf16)
    rmsnorm_kernel<<<S, 256, 0, stream>>>(x, rms_g, xn, xnb);
    // 2. QKV projection (bf16 B^T MFMA): (2048,1024)@(1024,1280), 640 blocks
    gemm_bt_kernel<64, 64, 2, 2, 0><<<dim3(QKVC / 64, S / 64), 256, 0, stream>>>(
        xnb, wqkvT, nullptr, qkv, S, QKVC, DIM);
    // 2.5 gates = sigmoid(xn @ W_comb + b_comb), N=48 guarded
    gemm_bt_kernel<64, 64, 2, 2, 2><<<dim3(1, S / 64), 256, 0, stream>>>(
        xnb, wcombT, b_comb, gates, S, HEADS * 3, DIM);
    // 3. rotary (also writes bf16 rkb)
    rotary_kernel<<<S, 256, 0, stream>>>(qkv, rq, rk, rkb);
    // 4. compress-MLP inputs (bf16)
    build_cmat_kernel<<<KVH * NCB, 256, 0, stream>>>(qkv, k_pos, v_pos, kcmb, vcmb);
    // 5. k-MLP W1 (bf16 MFMA, split-K 8): relu((64,4096)@(4096,4096)+b)
    gemm_mfma_kernel<64, 128, 1, 4><<<dim3(CDIM / 128, 1, 8), 256, 0, stream>>>(
        kcmb, kW1, partW1, 64, CDIM, CDIM, CDIM / 8);
    reduce_splitk_kernel<1><<<(64 * CDIM + 255) / 256, 256, 0, stream>>>(
        partW1, kb1, khid, 64 * CDIM, CDIM, 8);
    // 6. k-MLP W2 (fp32 split-K 32): (64,4096)@(4096,64)+b
    gemm_splitk_kernel<<<dim3(1, 1, 32), 256, 0, stream>>>(khid, kW2, partW2, 64, DH, CDIM, CDIM / 32);
    reduce_splitk_kernel<0><<<(64 * DH + 255) / 256, 256, 0, stream>>>(partW2, kb2, ckb, 64 * DH, DH, 32);
    // 7. v-MLP
    gemm_mfma_kernel<64, 128, 1, 4><<<dim3(CDIM / 128, 1, 8), 256, 0, stream>>>(
        vcmb, vW1, partW1, 64, CDIM, CDIM, CDIM / 8);
    reduce_splitk_kernel<1><<<(64 * CDIM + 255) / 256, 256, 0, stream>>>(
        partW1, vb1, vhid, 64 * CDIM, CDIM, 8);
    gemm_splitk_kernel<<<dim3(1, 1, 32), 256, 0, stream>>>(vhid, vW2, partW2, 64, DH, CDIM, CDIM / 32);
    reduce_splitk_kernel<0><<<(64 * DH + 255) / 256, 256, 0, stream>>>(partW2, vb2, cvb, 64 * DH, DH, 32);
    // 8. assemble ck/cv with mem tokens
    assemble_kernel<<<(KVH * (NCB + 1) * DH + 255) / 256, 256, 0, stream>>>(ckb, cvb, mem_kv, ck, cv);
    // 10. block importance
    imp_kernel<<<dim3(KVH, S), 64, 0, stream>>>(qkv, ck, imp);
    // 11. top-8 selection
    select_kernel<<<(KVH * S + 255) / 256, 256, 0, stream>>>(imp, sel);
    // 11.5 cast V cols -> bf16 vbb (reuses imp space, dead after select)
    cast_v_kernel<<<(S * KVH * DH / 4 + 255) / 256, 256, 0, stream>>>(qkv, vbb);
    // 12. compressed attention (writes attn = g0*c_out)
    cattn_kernel<<<dim3(HEADS, S / 64), 256, 0, stream>>>(qkv, ck, cv, gates, attn);
    // 13. fine attention, MFMA (attn += g1*f_out)
    fattn_kernel<<<dim3(KVH, S), 256, 0, stream>>>(rq, rkb, vbb, sel, gates, attn);
    // 14. sliding window (attn += g2*s_out)
    sattn_kernel<<<dim3(HEADS, S / 64), 256, 0, stream>>>(rq, rk, qkv, gates, attn);
    // 15. cast attn -> bf16
    cast_bf16_kernel<<<(S * HEADS * DH / 4 + 255) / 256, 256, 0, stream>>>(
        attn, attnb, S * HEADS * DH / 4);
    // 16. output projection (bf16 B^T MFMA): (2048,1024)@(1024,1024), 512 blocks
    gemm_bt_kernel<64, 64, 2, 2, 0><<<dim3(DIM / 64, S / 64), 256, 0, stream>>>(
        attnb, woutT, nullptr, out, S, DIM, DIM);
}

// Round 7
// 551.478 us; speedup vs baseline: 7.2537x; 1.1235x over previous
//
#include <hip/hip_runtime.h>
#include <hip/hip_bf16.h>
#include <cstddef>
#include <cstdint>

// Problem constants (B=1)
#define S      2048
#define DIM    1024
#define HEADS  16
#define KVH    2
#define GQ     8
#define DH     64
#define CBS    64
#define SBS    64
#define NUMSEL 8
#define WIN    512
#define NCB    (S / CBS)      // 32
#define CDIM   (CBS * DH)     // 4096
#define QKVC   (HEADS * DH + 2 * KVH * DH)   // 1280
#define KOFF   (HEADS * DH)                  // 1024 (k cols start)
#define VOFF   (HEADS * DH + KVH * DH)       // 1152 (v cols start)
#define SCALE  0.125f
#define RMS_EPS 1.1920928955078125e-07f

typedef __attribute__((ext_vector_type(8))) short bf16x8;   // 8 bf16 in 4 VGPRs
typedef __attribute__((ext_vector_type(4))) float f32x4;

__device__ inline short f2bs(float f) {
    __hip_bfloat16 b = __float2bfloat16(f);
    return *(short*)&b;
}

// ---------------- wave (64-lane) reductions ----------------
__device__ inline float wave_sum(float v) {
    for (int o = 32; o > 0; o >>= 1) v += __shfl_xor(v, o);
    return v;
}

// ---------------- RMSNorm (writes fp32 + bf16 copies) ----------------
__global__ __launch_bounds__(256) void rmsnorm_kernel(
        const float* __restrict__ x, const float* __restrict__ g,
        float* __restrict__ xn, __hip_bfloat16* __restrict__ xnb) {
    int s = blockIdx.x, tid = threadIdx.x;
    const float4* row = (const float4*)(x + (size_t)s * DIM);
    float4 v = row[tid];
    float ss = v.x * v.x + v.y * v.y + v.z * v.z + v.w * v.w;
    ss = wave_sum(ss);
    __shared__ float red[4];
    if ((tid & 63) == 0) red[tid >> 6] = ss;
    __syncthreads();
    float tot = red[0] + red[1] + red[2] + red[3];
    float sc = rsqrtf(tot / (float)DIM + RMS_EPS);
    float4 gg = ((const float4*)g)[tid];
    float4 o;
    o.x = v.x * sc * gg.x; o.y = v.y * sc * gg.y;
    o.z = v.z * sc * gg.z; o.w = v.w * sc * gg.w;
    ((float4*)(xn + (size_t)s * DIM))[tid] = o;
    size_t b = (size_t)s * DIM + tid * 4;
    xnb[b + 0] = __float2bfloat16(o.x);
    xnb[b + 1] = __float2bfloat16(o.y);
    xnb[b + 2] = __float2bfloat16(o.z);
    xnb[b + 3] = __float2bfloat16(o.w);
}

// ---------------- fp32 -> bf16 cast ----------------
__global__ __launch_bounds__(256) void cast_bf16_kernel(
        const float* __restrict__ in, __hip_bfloat16* __restrict__ out, int n4) {
    int e = blockIdx.x * 256 + threadIdx.x;
    if (e >= n4) return;
    float4 v = ((const float4*)in)[e];
    out[4 * e + 0] = __float2bfloat16(v.x);
    out[4 * e + 1] = __float2bfloat16(v.y);
    out[4 * e + 2] = __float2bfloat16(v.z);
    out[4 * e + 3] = __float2bfloat16(v.w);
}

// ---------------- W (K,N) fp32 -> Wt (N,K) bf16, LDS-tiled transpose ----------------
__global__ __launch_bounds__(256) void transpose_cast_kernel(
        const float* __restrict__ W, short* __restrict__ Wt, int K, int N) {
    __shared__ float tile[64][65];
    int n0 = blockIdx.x * 64, k0 = blockIdx.y * 64;
    int tid = threadIdx.x;
    #pragma unroll
    for (int e = 0; e < 16; e++) {
        int idx = tid + e * 256;
        int r = idx >> 6, c = idx & 63;
        float v = 0.f;
        if (n0 + c < N) v = W[(size_t)(k0 + r) * N + n0 + c];
        tile[r][c] = v;
    }
    __syncthreads();
    #pragma unroll
    for (int e = 0; e < 16; e++) {
        int idx = tid + e * 256;
        int r = idx >> 6, c = idx & 63;      // r = n-in-tile, c = k-in-tile
        if (n0 + r < N)
            Wt[(size_t)(n0 + r) * K + k0 + c] = f2bs(tile[c][r]);
    }
}

// ---------------- extract V columns of qkv -> vb (S, KVH, DH) bf16 ----------------
__global__ __launch_bounds__(256) void cast_v_kernel(
        const float* __restrict__ qkv, short* __restrict__ vb) {
    int e = blockIdx.x * 256 + threadIdx.x;    // e4 over S*KVH*DH/4
    if (e >= S * KVH * DH / 4) return;
    int idx = e * 4;
    int tok = idx / (KVH * DH), rem = idx % (KVH * DH);
    float4 v = *(const float4*)(qkv + (size_t)tok * QKVC + VOFF + rem);
    vb[idx + 0] = f2bs(v.x);
    vb[idx + 1] = f2bs(v.y);
    vb[idx + 2] = f2bs(v.z);
    vb[idx + 3] = f2bs(v.w);
}

// ---------------- bf16 B^T MFMA GEMM: C = act(A(bf16,MxK) @ Bt^T(N,K bf16) + bias) ---
template <int BM, int BN, int WM, int WN, int ACT>
__global__ __launch_bounds__(256) void gemm_bt_kernel(
        const __hip_bfloat16* __restrict__ A, const short* __restrict__ Bt,
        const float* __restrict__ bias, float* __restrict__ C,
        int M, int N, int K) {
    constexpr int BK = 32;
    constexpr int TM = BM / (WM * 16);
    constexpr int TN = BN / (WN * 16);
    constexpr int LDK = BK + 8;
    __shared__ short As[BM][LDK];
    __shared__ short Bs[BN][LDK];
    int tid = threadIdx.x;
    int wave = tid >> 6, lane = tid & 63;
    int wm = wave % WM, wn = wave / WM;
    int m0 = wm * TM * 16, n0 = wn * TN * 16;
    int bm = blockIdx.y * BM, bn = blockIdx.x * BN;
    int lm = lane & 15, quad = lane >> 4;
    const short* Ash = (const short*)A;
    f32x4 acc[TM][TN] = {};
    for (int k0 = 0; k0 < K; k0 += BK) {
        #pragma unroll
        for (int e = 0; e < BM * BK / (256 * 8); e++) {
            int idx = (tid + e * 256) * 8;
            int r = idx >> 5, kk = idx & 31;
            *(bf16x8*)(&As[r][kk]) =
                *(const bf16x8*)(Ash + (size_t)(bm + r) * K + k0 + kk);
        }
        #pragma unroll
        for (int e = 0; e < BN * BK / (256 * 8); e++) {
            int idx = (tid + e * 256) * 8;
            int r = idx >> 5, kk = idx & 31;
            bf16x8 v = {};
            if (bn + r < N)
                v = *(const bf16x8*)(Bt + (size_t)(bn + r) * K + k0 + kk);
            *(bf16x8*)(&Bs[r][kk]) = v;
        }
        __syncthreads();
        bf16x8 af[TM], bf_[TN];
        #pragma unroll
        for (int i = 0; i < TM; i++)
            af[i] = *(const bf16x8*)(&As[m0 + i * 16 + lm][quad * 8]);
        #pragma unroll
        for (int j = 0; j < TN; j++)
            bf_[j] = *(const bf16x8*)(&Bs[n0 + j * 16 + lm][quad * 8]);
        #pragma unroll
        for (int i = 0; i < TM; i++)
            #pragma unroll
            for (int j = 0; j < TN; j++)
                acc[i][j] = __builtin_amdgcn_mfma_f32_16x16x32_bf16(
                    af[i], bf_[j], acc[i][j], 0, 0, 0);
        __syncthreads();
    }
    #pragma unroll
    for (int i = 0; i < TM; i++) {
        #pragma unroll
        for (int j = 0; j < TN; j++) {
            int gn = bn + n0 + j * 16 + lm;
            if (gn >= N) continue;
            #pragma unroll
            for (int r = 0; r < 4; r++) {
                int gm = bm + m0 + i * 16 + quad * 4 + r;
                float v = acc[i][j][r];
                if (bias) v += bias[gn];
                if (ACT == 2) v = 1.f / (1.f + expf(-v));
                C[(size_t)gm * N + gn] = v;
            }
        }
    }
}

// ---------------- bf16 MFMA GEMM, fp32 B (two-phase staging), split-K ---------------
template <int BM, int BN, int WM, int WN>
__global__ __launch_bounds__(256) void gemm_mfma_kernel(
        const __hip_bfloat16* __restrict__ A, const float* __restrict__ B,
        float* __restrict__ C, int M, int N, int K, int kslice) {
    constexpr int BK = 32;
    constexpr int TM = BM / (WM * 16);
    constexpr int TN = BN / (WN * 16);
    constexpr int LDK = BK + 8;
    constexpr int NB = BN * BK / 256;
    __shared__ __hip_bfloat16 As[BM][LDK];
    __shared__ __hip_bfloat16 Bs[BN][LDK];
    int tid = threadIdx.x;
    int wave = tid >> 6, lane = tid & 63;
    int wm = wave % WM, wn = wave / WM;
    int m0 = wm * TM * 16, n0 = wn * TN * 16;
    int bm = blockIdx.y * BM, bn = blockIdx.x * BN;
    int kbeg = blockIdx.z * kslice, kend = kbeg + kslice;
    int lm = lane & 15, quad = lane >> 4;
    f32x4 acc[TM][TN] = {};
    for (int k0 = kbeg; k0 < kend; k0 += BK) {
        #pragma unroll
        for (int e = 0; e < BM * BK / (256 * 8); e++) {
            int idx = (tid + e * 256) * 8;
            int r = idx >> 5, kk = idx & 31;
            *(bf16x8*)(&As[r][kk]) =
                *(const bf16x8*)(A + (size_t)(bm + r) * K + k0 + kk);
        }
        float tmpB[NB];
        #pragma unroll
        for (int e = 0; e < NB; e++) {
            int idx = tid + e * 256;
            int kk = idx / BN, n = idx % BN;
            tmpB[e] = B[(size_t)(k0 + kk) * N + bn + n];
        }
        #pragma unroll
        for (int e = 0; e < NB; e++) {
            int idx = tid + e * 256;
            int kk = idx / BN, n = idx % BN;
            Bs[n][kk] = __float2bfloat16(tmpB[e]);
        }
        __syncthreads();
        bf16x8 af[TM], bf_[TN];
        #pragma unroll
        for (int i = 0; i < TM; i++)
            af[i] = *(const bf16x8*)(&As[m0 + i * 16 + lm][quad * 8]);
        #pragma unroll
        for (int j = 0; j < TN; j++)
            bf_[j] = *(const bf16x8*)(&Bs[n0 + j * 16 + lm][quad * 8]);
        #pragma unroll
        for (int i = 0; i < TM; i++)
            #pragma unroll
            for (int j = 0; j < TN; j++)
                acc[i][j] = __builtin_amdgcn_mfma_f32_16x16x32_bf16(
                    af[i], bf_[j], acc[i][j], 0, 0, 0);
        __syncthreads();
    }
    size_t cbase = (size_t)blockIdx.z * M * N;
    #pragma unroll
    for (int i = 0; i < TM; i++) {
        #pragma unroll
        for (int j = 0; j < TN; j++) {
            int gn = bn + n0 + j * 16 + lm;
            #pragma unroll
            for (int r = 0; r < 4; r++) {
                int gm = bm + m0 + i * 16 + quad * 4 + r;
                C[cbase + (size_t)gm * N + gn] = acc[i][j][r];
            }
        }
    }
}

// ---------------- split-K fp32 GEMM (partials) — for the tiny W2 matmuls ----------------
__global__ __launch_bounds__(256) void gemm_splitk_kernel(
        const float* __restrict__ A, const float* __restrict__ B,
        float* __restrict__ P, int M, int N, int K, int kslice) {
    const int BM = 64, BN = 64, BK = 16;
    __shared__ float As[BK][BM + 4];
    __shared__ float Bs[BK][BN];
    int bm = blockIdx.y * BM, bn = blockIdx.x * BN;
    int z = blockIdx.z;
    int kbeg = z * kslice, kend = kbeg + kslice;
    int tid = threadIdx.x;
    int tx = tid & 15, ty = tid >> 4;
    float acc[4][4] = {{0.f}};
    for (int k0 = kbeg; k0 < kend; k0 += BK) {
        #pragma unroll
        for (int e = 0; e < 4; e++) {
            int idx = tid + e * 256;
            int m = idx >> 4, kk = idx & 15;
            int gm = bm + m;
            As[kk][m] = (gm < M) ? A[(size_t)gm * K + k0 + kk] : 0.f;
        }
        #pragma unroll
        for (int e = 0; e < 4; e++) {
            int idx = tid + e * 256;
            int kk = idx >> 6, n = idx & 63;
            int gn = bn + n;
            Bs[kk][n] = (gn < N) ? B[(size_t)(k0 + kk) * N + gn] : 0.f;
        }
        __syncthreads();
        #pragma unroll
        for (int kk = 0; kk < BK; kk++) {
            float a[4], b[4];
            #pragma unroll
            for (int i = 0; i < 4; i++) a[i] = As[kk][ty * 4 + i];
            #pragma unroll
            for (int j = 0; j < 4; j++) b[j] = Bs[kk][tx * 4 + j];
            #pragma unroll
            for (int i = 0; i < 4; i++)
                #pragma unroll
                for (int j = 0; j < 4; j++) acc[i][j] += a[i] * b[j];
        }
        __syncthreads();
    }
    #pragma unroll
    for (int i = 0; i < 4; i++) {
        int gm = bm + ty * 4 + i;
        if (gm >= M) continue;
        #pragma unroll
        for (int j = 0; j < 4; j++) {
            int gn = bn + tx * 4 + j;
            if (gn >= N) continue;
            P[((size_t)z * M + gm) * N + gn] = acc[i][j];
        }
    }
}

template <int ACT>
__global__ __launch_bounds__(256) void reduce_splitk_kernel(
        const float* __restrict__ P, const float* __restrict__ bias,
        float* __restrict__ C, int MN, int N, int splits) {
    int e = blockIdx.x * 256 + threadIdx.x;
    if (e >= MN) return;
    float s = 0.f;
    for (int z = 0; z < splits; z++) s += P[(size_t)z * MN + e];
    s += bias[e % N];
    if (ACT == 1) s = fmaxf(s, 0.f);
    C[e] = s;
}

// ---------------- rotary embedding -> bf16 rqb (S,H,DH), rkb (S,KVH,DH) ----------------
__global__ __launch_bounds__(256) void rotary_kernel(
        const float* __restrict__ qkv, short* __restrict__ rqb, short* __restrict__ rkb) {
    int s = blockIdx.x, tid = threadIdx.x;
    for (int p = tid; p < (HEADS + KVH) * (DH / 2); p += 256) {
        int t; const float* src; short* dst;
        if (p < HEADS * (DH / 2)) {
            int h = p >> 5; t = p & 31;
            src = qkv + (size_t)s * QKVC + h * DH + 2 * t;
            dst = rqb + (size_t)s * (HEADS * DH) + h * DH + 2 * t;
        } else {
            int pp = p - HEADS * (DH / 2);
            int h = pp >> 5; t = pp & 31;
            src = qkv + (size_t)s * QKVC + KOFF + h * DH + 2 * t;
            dst = rkb + (size_t)s * (KVH * DH) + h * DH + 2 * t;
        }
        float u0 = src[0], u1 = src[1];
        float freq = powf(10000.f, -((float)(2 * t) / (float)DH));
        float ang = (float)s * freq;
        float sn, cs;
        sincosf(ang, &sn, &cs);
        dst[0] = f2bs(u0 * cs - u1 * sn);
        dst[1] = f2bs(u1 * cs + u0 * sn);
    }
}

// ---------------- build compress-MLP input matrices (bf16 output) ----------------
__global__ __launch_bounds__(256) void build_cmat_kernel(
        const float* __restrict__ qkv, const float* __restrict__ k_pos,
        const float* __restrict__ v_pos, __hip_bfloat16* __restrict__ kcm,
        __hip_bfloat16* __restrict__ vcm) {
    int r = blockIdx.x;          // r = h*32 + w
    int h = r >> 5, w = r & 31;
    for (int e = threadIdx.x; e < CDIM; e += 256) {
        int i = e >> 6, d = e & 63;
        size_t qb = (size_t)(w * CBS + i) * QKVC;
        kcm[(size_t)r * CDIM + e] =
            __float2bfloat16(qkv[qb + KOFF + h * DH + d] + k_pos[(h * CBS + i) * DH + d]);
        vcm[(size_t)r * CDIM + e] =
            __float2bfloat16(qkv[qb + VOFF + h * DH + d] + v_pos[(h * CBS + i) * DH + d]);
    }
}

// ---------------- assemble ck/cv (fp32 + bf16): prepend mem_kv -> (KVH, 33, DH) -------
__global__ __launch_bounds__(256) void assemble_kernel(
        const float* __restrict__ ckb, const float* __restrict__ cvb,
        const float* __restrict__ mem_kv, float* __restrict__ ck, float* __restrict__ cv,
        short* __restrict__ ck16, short* __restrict__ cv16) {
    int e = blockIdx.x * 256 + threadIdx.x;
    if (e >= KVH * (NCB + 1) * DH) return;
    int d = e & 63;
    int j = (e >> 6) % (NCB + 1);
    int h = e / ((NCB + 1) * DH);
    float kv, vv;
    if (j == 0) {
        kv = mem_kv[0 * KVH * DH + h * DH + d];
        vv = mem_kv[1 * KVH * DH + h * DH + d];
    } else {
        kv = ckb[((size_t)h * NCB + j - 1) * DH + d];
        vv = cvb[((size_t)h * NCB + j - 1) * DH + d];
    }
    ck[e] = kv; cv[e] = vv;
    ck16[e] = f2bs(kv); cv16[e] = f2bs(vv);
}

// ---------------- block importance: imp[kvh][s][w] ----------------
__global__ __launch_bounds__(64) void imp_kernel(
        const float* __restrict__ qkv, const float* __restrict__ ck,
        float* __restrict__ imp) {
    int kvh = blockIdx.x, s = blockIdx.y, t = threadIdx.x;
    __shared__ float qg[GQ * DH];
    __shared__ float ckl[NCB * 65];
    for (int e = t; e < GQ * DH; e += 64) {
        int g = e >> 6, d = e & 63;
        qg[e] = qkv[(size_t)s * QKVC + (kvh * GQ + g) * DH + d];
    }
    for (int e = t; e < NCB * DH; e += 64) {
        int w = e >> 6, d = e & 63;
        ckl[w * 65 + d] = ck[((size_t)kvh * (NCB + 1) + 1 + w) * DH + d];
    }
    __syncthreads();
    if (t < NCB) {
        int w = t;
        float val;
        if (w * CBS + CBS - 1 < s) {
            float acc = 0.f;
            #pragma unroll
            for (int g = 0; g < GQ; g++) {
                const float* qp = qg + g * DH;
                const float* cp = ckl + w * 65;
                #pragma unroll 16
                for (int d = 0; d < DH; d++) acc += qp[d] * cp[d];
            }
            val = acc * SCALE * (1.f / (float)GQ);
        } else {
            val = -INFINITY;
        }
        imp[((size_t)kvh * S + s) * NCB + w] = val;
    }
}

// ---------------- top-8 selection (replicates lax.top_k stable ties) ----------------
__global__ __launch_bounds__(256) void select_kernel(
        const float* __restrict__ imp, int* __restrict__ sel) {
    int idx = blockIdx.x * 256 + threadIdx.x;
    if (idx >= KVH * S) return;
    const float* row = imp + (size_t)idx * NCB;
    float p[NCB];
    float m = -1000.f;
    for (int w = 0; w < NCB; w++) { p[w] = row[w]; m = fmaxf(m, p[w]); }
    float z = expf(-1000.f - m);
    for (int w = 0; w < NCB; w++) { p[w] = expf(p[w] - m); z += p[w]; }
    float inv = 1.f / z;
    bool used[NCB];
    for (int w = 0; w < NCB; w++) used[w] = false;
    for (int i = 0; i < NUMSEL; i++) {
        int best = 0; float bv = -1.f;
        for (int w = 0; w < NCB; w++) {
            if (!used[w]) {
                float pw = p[w] * inv;
                if (pw > bv) { bv = pw; best = w; }
            }
        }
        used[best] = true;
        sel[(size_t)idx * NUMSEL + i] = (bv > 1e-10f) ? best : -1;
    }
}

// ---------------- compressed attention, MFMA: block=(head, 64-q tile) ----------------
// 4 waves x 16 queries; single 33-key tile (padded to 64). Visibility mask is
// block-uniform: jj==0 || jj <= min(32, qb).
__global__ __launch_bounds__(256) void cattn_kernel(
        const float* __restrict__ qkv, const short* __restrict__ ck16,
        const short* __restrict__ cv16, const float* __restrict__ gates,
        float* __restrict__ attn) {
    int h = blockIdx.x, qb = blockIdx.y;
    int kvh = h >> 3;
    int tid = threadIdx.x;
    int wv = tid >> 6, lane = tid & 63;
    int lm = lane & 15, quad = lane >> 4;
    __shared__ short Qb[64][72];   // [q][d]
    __shared__ short Ks[64][72];   // [key][d] (keys 33..63 zero)
    __shared__ short Vt[64][72];   // [d][key]
    __shared__ short Pb[64][72];   // [q][key] probs (unnormalized)
    // stage Q (fp32 -> bf16)
    for (int e = tid; e < 1024; e += 256) {
        int q = e >> 4, d4 = (e & 15) * 4;
        float4 v = *(const float4*)(qkv + (size_t)(qb * 64 + q) * QKVC + h * DH + d4);
        Qb[q][d4 + 0] = f2bs(v.x); Qb[q][d4 + 1] = f2bs(v.y);
        Qb[q][d4 + 2] = f2bs(v.z); Qb[q][d4 + 3] = f2bs(v.w);
    }
    // stage K rows + V^T
    for (int e = tid; e < 512; e += 256) {
        int c8 = e >> 6, j = e & 63;
        bf16x8 kv = {}, vv = {};
        if (j < NCB + 1) {
            kv = *(const bf16x8*)(ck16 + ((size_t)kvh * (NCB + 1) + j) * DH + c8 * 8);
            vv = *(const bf16x8*)(cv16 + ((size_t)kvh * (NCB + 1) + j) * DH + c8 * 8);
        }
        #pragma unroll
        for (int t = 0; t < 8; t++) {
            Ks[j][c8 * 8 + t] = kv[t];
            Vt[c8 * 8 + t][j] = vv[t];
        }
    }
    __syncthreads();
    bf16x8 aq0 = *(const bf16x8*)&Qb[wv * 16 + lm][quad * 8];
    bf16x8 aq1 = *(const bf16x8*)&Qb[wv * 16 + lm][32 + quad * 8];
    int vismax = (qb < NCB) ? qb : NCB;       // jj<=vismax (plus jj==0) visible
    f32x4 sc[4];
    #pragma unroll
    for (int t = 0; t < 4; t++) {
        bf16x8 bk0 = *(const bf16x8*)&Ks[t * 16 + lm][quad * 8];
        bf16x8 bk1 = *(const bf16x8*)&Ks[t * 16 + lm][32 + quad * 8];
        f32x4 s4 = {0.f, 0.f, 0.f, 0.f};
        s4 = __builtin_amdgcn_mfma_f32_16x16x32_bf16(aq0, bk0, s4, 0, 0, 0);
        s4 = __builtin_amdgcn_mfma_f32_16x16x32_bf16(aq1, bk1, s4, 0, 0, 0);
        sc[t] = s4;
    }
    // softmax per row (row = quad*4+r, cols t*16+lm; reduce over 16 lm lanes)
    float l[4];
    float pr[4][4];
    #pragma unroll
    for (int r = 0; r < 4; r++) {
        float mx = -INFINITY;
        #pragma unroll
        for (int t = 0; t < 4; t++) {
            int jj = t * 16 + lm;
            bool vis = (jj == 0) || (jj <= vismax);
            float v = vis ? sc[t][r] * SCALE : -INFINITY;
            sc[t][r] = v;
            mx = fmaxf(mx, v);
        }
        #pragma unroll
        for (int o = 1; o < 16; o <<= 1) mx = fmaxf(mx, __shfl_xor(mx, o));
        float sum = 0.f;
        #pragma unroll
        for (int t = 0; t < 4; t++) {
            float p = expf(sc[t][r] - mx);    // mx finite (jj==0 always visible)
            pr[r][t] = p;
            sum += p;
        }
        #pragma unroll
        for (int o = 1; o < 16; o <<= 1) sum += __shfl_xor(sum, o);
        l[r] = sum;
    }
    #pragma unroll
    for (int r = 0; r < 4; r++)
        #pragma unroll
        for (int t = 0; t < 4; t++)
            Pb[wv * 16 + quad * 4 + r][t * 16 + lm] = f2bs(pr[r][t]);
    __syncthreads();
    bf16x8 ap0 = *(const bf16x8*)&Pb[wv * 16 + lm][quad * 8];
    bf16x8 ap1 = *(const bf16x8*)&Pb[wv * 16 + lm][32 + quad * 8];
    f32x4 oacc[4];
    #pragma unroll
    for (int t = 0; t < 4; t++) {
        bf16x8 bv0 = *(const bf16x8*)&Vt[t * 16 + lm][quad * 8];
        bf16x8 bv1 = *(const bf16x8*)&Vt[t * 16 + lm][32 + quad * 8];
        f32x4 a = {0.f, 0.f, 0.f, 0.f};
        a = __builtin_amdgcn_mfma_f32_16x16x32_bf16(ap0, bv0, a, 0, 0, 0);
        a = __builtin_amdgcn_mfma_f32_16x16x32_bf16(ap1, bv1, a, 0, 0, 0);
        oacc[t] = a;
    }
    #pragma unroll
    for (int r = 0; r < 4; r++) {
        int spos = qb * 64 + wv * 16 + quad * 4 + r;
        float g0 = gates[((size_t)spos * HEADS + h) * 3 + 0];
        float f = g0 / l[r];
        #pragma unroll
        for (int t = 0; t < 4; t++)
            attn[(size_t)spos * (HEADS * DH) + h * DH + t * 16 + lm] = oacc[t][r] * f;
    }
}

// ---------------- fine attention: MFMA flash, one block per (kvh, s) ----------------
__global__ __launch_bounds__(256) void fattn_kernel(
        const short* __restrict__ rqb, const short* __restrict__ rkb,
        const short* __restrict__ vb, const int* __restrict__ sel,
        const float* __restrict__ gates, float* __restrict__ attn) {
    int kvh = blockIdx.x, s = blockIdx.y;
    int tid = threadIdx.x;
    int wv = tid >> 6, lane = tid & 63;
    int lm = lane & 15, quad = lane >> 4;
    int hh = tid >> 5, lk = tid & 31;          // softmax mapping: 8 groups x 32 lanes
    __shared__ short Qb[16][68];               // [head][d] bf16 (heads 8-15 garbage)
    __shared__ short Vt[64][68];               // [d][key] bf16 (V^T)
    __shared__ short Pb[16][68];               // [head][key] bf16 probs
    __shared__ float Sc[8][68];                // [head][key] fp32 scores
    __shared__ float alph[8], fac[8];
    __shared__ int bl[9];
    for (int e = tid; e < 512; e += 256) {
        int h = e >> 6, d = e & 63;
        Qb[h][d] = rqb[(size_t)s * (HEADS * DH) + (kvh * 8 + h) * DH + d];
    }
    if (tid < NUMSEL) bl[tid] = sel[((size_t)kvh * S + s) * NUMSEL + tid];
    if (tid == NUMSEL) bl[NUMSEL] = s >> 6;
    __syncthreads();
    bf16x8 aq0 = *(const bf16x8*)&Qb[lm][quad * 8];
    bf16x8 aq1 = *(const bf16x8*)&Qb[lm][32 + quad * 8];
    float mh = -INFINITY, lh = 0.f;
    f32x4 oacc = {0.f, 0.f, 0.f, 0.f};
    for (int i = 0; i < 9; i++) {
        int w = bl[i];
        if (i < NUMSEL && w < 0) continue;     // uniform across block
        #pragma unroll
        for (int r = 0; r < 2; r++) {
            int idx = tid + r * 256;           // 0..511
            int c8 = idx >> 6, j = idx & 63;
            bf16x8 vv = *(const bf16x8*)(vb + ((size_t)(w * SBS + j) * KVH + kvh) * DH + c8 * 8);
            #pragma unroll
            for (int t = 0; t < 8; t++) Vt[c8 * 8 + t][j] = vv[t];
        }
        {
            const short* kp = rkb + ((size_t)(w * SBS + wv * 16 + lm) * KVH + kvh) * DH;
            bf16x8 bk0 = *(const bf16x8*)(kp + quad * 8);
            bf16x8 bk1 = *(const bf16x8*)(kp + 32 + quad * 8);
            f32x4 sc4 = {0.f, 0.f, 0.f, 0.f};
            sc4 = __builtin_amdgcn_mfma_f32_16x16x32_bf16(aq0, bk0, sc4, 0, 0, 0);
            sc4 = __builtin_amdgcn_mfma_f32_16x16x32_bf16(aq1, bk1, sc4, 0, 0, 0);
            bool vis = (i < NUMSEL) || (wv * 16 + lm <= (s & 63));
            #pragma unroll
            for (int r = 0; r < 4; r++) {
                int row = quad * 4 + r;
                if (row < 8) Sc[row][wv * 16 + lm] = vis ? sc4[r] * SCALE : -INFINITY;
            }
        }
        __syncthreads();
        {
            float s0 = Sc[hh][lk], s1 = Sc[hh][lk + 32];
            float bmx = fmaxf(s0, s1);
            #pragma unroll
            for (int o = 1; o < 32; o <<= 1) bmx = fmaxf(bmx, __shfl_xor(bmx, o));
            float mn = fmaxf(mh, bmx);
            float scl = expf(mh - mn);
            float p0 = expf(s0 - mn), p1 = expf(s1 - mn);
            float rs = p0 + p1;
            #pragma unroll
            for (int o = 1; o < 32; o <<= 1) rs += __shfl_xor(rs, o);
            lh = lh * scl + rs;
            mh = mn;
            Pb[hh][lk] = f2bs(p0);
            Pb[hh][lk + 32] = f2bs(p1);
            if (lk == 0) alph[hh] = scl;
        }
        __syncthreads();
        {
            bf16x8 ap0 = *(const bf16x8*)&Pb[lm][quad * 8];
            bf16x8 ap1 = *(const bf16x8*)&Pb[lm][32 + quad * 8];
            bf16x8 bv0 = *(const bf16x8*)&Vt[wv * 16 + lm][quad * 8];
            bf16x8 bv1 = *(const bf16x8*)&Vt[wv * 16 + lm][32 + quad * 8];
            #pragma unroll
            for (int r = 0; r < 4; r++) oacc[r] *= alph[(quad * 4 + r) & 7];
            oacc = __builtin_amdgcn_mfma_f32_16x16x32_bf16(ap0, bv0, oacc, 0, 0, 0);
            oacc = __builtin_amdgcn_mfma_f32_16x16x32_bf16(ap1, bv1, oacc, 0, 0, 0);
        }
        __syncthreads();
    }
    if (lk == 0)
        fac[hh] = gates[((size_t)s * HEADS + kvh * 8 + hh) * 3 + 1] / lh;
    __syncthreads();
    #pragma unroll
    for (int r = 0; r < 4; r++) {
        int row = quad * 4 + r;
        if (row < 8)
            attn[(size_t)s * (HEADS * DH) + (kvh * 8 + row) * DH + wv * 16 + lm]
                += oacc[r] * fac[row];
    }
}

// ---------------- sliding window: MFMA flash, block=(head, 64-q tile) ----------------
// 4 waves x 16 queries; 9 key chunks of 64; kb always a multiple of 64 (chunks
// fully skipped or fully in-range); window mask only in chunk 0, causal in chunk 8.
__global__ __launch_bounds__(256) void sattn_kernel(
        const short* __restrict__ rqb, const short* __restrict__ rkb,
        const short* __restrict__ vb, const float* __restrict__ gates,
        float* __restrict__ attn) {
    int h = blockIdx.x, qb = blockIdx.y;
    int kvh = h >> 3;
    int tid = threadIdx.x;
    int wv = tid >> 6, lane = tid & 63;
    int lm = lane & 15, quad = lane >> 4;
    __shared__ short Vt[64][72];   // [d][key]
    __shared__ short Pb[64][72];   // [q][key] probs (unnormalized)
    const short* qp = rqb + (size_t)(qb * 64 + wv * 16 + lm) * (HEADS * DH) + h * DH;
    bf16x8 aq0 = *(const bf16x8*)(qp + quad * 8);
    bf16x8 aq1 = *(const bf16x8*)(qp + 32 + quad * 8);
    int myrow = wv * 16 + quad * 4;            // + r
    float m[4], l[4];
    f32x4 oacc[4];
    #pragma unroll
    for (int r = 0; r < 4; r++) { m[r] = -INFINITY; l[r] = 0.f; }
    #pragma unroll
    for (int t = 0; t < 4; t++) oacc[t] = (f32x4){0.f, 0.f, 0.f, 0.f};
    for (int c = 0; c < 9; c++) {
        int kb = qb * 64 - WIN + c * 64;
        if (kb < 0) continue;                  // kb is multiple of 64: all-or-nothing
        // stage V^T
        for (int e = tid; e < 512; e += 256) {
            int c8 = e >> 6, j = e & 63;
            bf16x8 vv = *(const bf16x8*)(vb + ((size_t)(kb + j) * KVH + kvh) * DH + c8 * 8);
            #pragma unroll
            for (int t = 0; t < 8; t++) Vt[c8 * 8 + t][j] = vv[t];
        }
        // scores: 4 key tiles, K B-frags direct from global rkb
        f32x4 sc[4];
        #pragma unroll
        for (int t = 0; t < 4; t++) {
            const short* kp = rkb + ((size_t)(kb + t * 16 + lm) * KVH + kvh) * DH;
            bf16x8 bk0 = *(const bf16x8*)(kp + quad * 8);
            bf16x8 bk1 = *(const bf16x8*)(kp + 32 + quad * 8);
            f32x4 s4 = {0.f, 0.f, 0.f, 0.f};
            s4 = __builtin_amdgcn_mfma_f32_16x16x32_bf16(aq0, bk0, s4, 0, 0, 0);
            s4 = __builtin_amdgcn_mfma_f32_16x16x32_bf16(aq1, bk1, s4, 0, 0, 0);
            sc[t] = s4;
        }
        // online softmax per row
        float pr[4][4];
        #pragma unroll
        for (int r = 0; r < 4; r++) {
            int row = myrow + r;
            float mx = -INFINITY;
            #pragma unroll
            for (int t = 0; t < 4; t++) {
                int jj = t * 16 + lm;
                bool vis = true;
                if (c == 0) vis = (jj >= row);          // window lower bound
                if (c == 8) vis = (jj <= row);          // causal
                float v = vis ? sc[t][r] * SCALE : -INFINITY;
                sc[t][r] = v;
                mx = fmaxf(mx, v);
            }
            #pragma unroll
            for (int o = 1; o < 16; o <<= 1) mx = fmaxf(mx, __shfl_xor(mx, o));
            float mn = fmaxf(m[r], mx);                 // finite: >=1 visible key
            float al = expf(m[r] - mn);
            float sum = 0.f;
            #pragma unroll
            for (int t = 0; t < 4; t++) {
                float p = expf(sc[t][r] - mn);
                pr[r][t] = p;
                sum += p;
            }
            #pragma unroll
            for (int o = 1; o < 16; o <<= 1) sum += __shfl_xor(sum, o);
            l[r] = l[r] * al + sum;
            m[r] = mn;
            #pragma unroll
            for (int t = 0; t < 4; t++) oacc[t][r] *= al;
        }
        __syncthreads();                                // Vt staged; prev Pb consumed
        #pragma unroll
        for (int r = 0; r < 4; r++)
            #pragma unroll
            for (int t = 0; t < 4; t++)
                Pb[myrow + r][t * 16 + lm] = f2bs(pr[r][t]);
        __syncthreads();
        // PV
        bf16x8 ap0 = *(const bf16x8*)&Pb[wv * 16 + lm][quad * 8];
        bf16x8 ap1 = *(const bf16x8*)&Pb[wv * 16 + lm][32 + quad * 8];
        #pragma unroll
        for (int t = 0; t < 4; t++) {
            bf16x8 bv0 = *(const bf16x8*)&Vt[t * 16 + lm][quad * 8];
            bf16x8 bv1 = *(const bf16x8*)&Vt[t * 16 + lm][32 + quad * 8];
            oacc[t] = __builtin_amdgcn_mfma_f32_16x16x32_bf16(ap0, bv0, oacc[t], 0, 0, 0);
            oacc[t] = __builtin_amdgcn_mfma_f32_16x16x32_bf16(ap1, bv1, oacc[t], 0, 0, 0);
        }
        __syncthreads();                                // before next Vt/Pb overwrite
    }
    #pragma unroll
    for (int r = 0; r < 4; r++) {
        int spos = qb * 64 + myrow + r;
        float g2 = gates[((size_t)spos * HEADS + h) * 3 + 2];
        float f = g2 / l[r];
        #pragma unroll
        for (int t = 0; t < 4; t++)
            attn[(size_t)spos * (HEADS * DH) + h * DH + t * 16 + lm] += oacc[t][r] * f;
    }
}

// ---------------- launch ----------------
extern "C" void kernel_launch(void* const* d_in, const int* in_sizes, int n_in,
                              void* d_out, int out_size, void* d_ws, size_t ws_size,
                              hipStream_t stream) {
    const float* x      = (const float*)d_in[0];
    const float* rms_g  = (const float*)d_in[1];
    const float* W_qkv  = (const float*)d_in[2];
    const float* k_pos  = (const float*)d_in[3];
    const float* v_pos  = (const float*)d_in[4];
    const float* mem_kv = (const float*)d_in[5];
    const float* kW1    = (const float*)d_in[6];
    const float* kb1    = (const float*)d_in[7];
    const float* kW2    = (const float*)d_in[8];
    const float* kb2    = (const float*)d_in[9];
    const float* vW1    = (const float*)d_in[10];
    const float* vb1    = (const float*)d_in[11];
    const float* vW2    = (const float*)d_in[12];
    const float* vb2    = (const float*)d_in[13];
    const float* W_comb = (const float*)d_in[14];
    const float* b_comb = (const float*)d_in[15];
    const float* W_out  = (const float*)d_in[16];
    float* out = (float*)d_out;

    // workspace layout (floats) — R (1048576 fl) time-multiplexed:
    //   steps 1-2.5: xnb; steps 4-8: MLP scratch; steps 15-16: attnb.
    float* ws    = (float*)d_ws;
    float* xn    = ws;                                     // 2097152
    float* qkv   = xn    + (size_t)S * DIM;                // 2621440
    short* rqb   = (short*)(qkv + (size_t)S * QKVC);       // 2097152 sh = 1048576 fl
    short* rkb   = (short*)((float*)rqb + 1048576);        // 262144 sh = 131072 fl
    float* R     = (float*)rkb + 131072;                   // 1048576
    float* ck    = R     + 1048576;                        // 4224
    float* cv    = ck    + (size_t)KVH * (NCB + 1) * DH;   // 4224
    short* ck16  = (short*)(cv + (size_t)KVH * (NCB + 1) * DH);  // 4224 sh = 2112 fl
    short* cv16  = (short*)((float*)ck16 + 2112);          // 2112 fl
    float* imp   = (float*)cv16 + 2112;                    // 131072
    float* gates = imp   + (size_t)KVH * S * NCB;          // 98304
    float* attn  = gates + (size_t)S * HEADS * 3;          // 2097152
    int*   sel   = (int*)(attn + (size_t)S * HEADS * DH);  // 32768 ints = 8192 fl
    float* WT    = attn + (size_t)S * HEADS * DH + 8192;
    short* wqkvT = (short*)WT;                             // 1280*1024 bf16 = 655360 fl
    short* woutT = (short*)(WT + 655360);                  // 1024*1024 bf16 = 524288 fl
    short* wcombT= (short*)(WT + 655360 + 524288);         // 48*1024 bf16 = 24576 fl

    __hip_bfloat16* xnb   = (__hip_bfloat16*)R;            // dead after gates
    __hip_bfloat16* kcmb  = (__hip_bfloat16*)R;            // 131072 fl
    __hip_bfloat16* vcmb  = (__hip_bfloat16*)(R + 131072); // 131072 fl
    float* khid  = R + 262144;                             // 262144 fl
    float* vhid  = R + 524288;                             // 262144 fl
    float* ckb   = R + 786432;                             // 4096 fl
    float* cvb   = R + 790528;                             // 4096 fl (ends 794624)
    __hip_bfloat16* attnb = (__hip_bfloat16*)R;            // reused after fattn
    short* vbb   = (short*)imp;   // 262144 bf16 = 131072 fl (imp dead after select)
    float* partW1 = attn;   // 2097152 (attn live only from step 12)
    float* partW2 = imp;    // 131072  (imp live only steps 10-11)

    // 0. pre-transpose+cast weights to bf16 B^T
    transpose_cast_kernel<<<dim3(QKVC / 64, DIM / 64), 256, 0, stream>>>(W_qkv, wqkvT, DIM, QKVC);
    transpose_cast_kernel<<<dim3(DIM / 64, DIM / 64), 256, 0, stream>>>(W_out, woutT, DIM, DIM);
    transpose_cast_kernel<<<dim3(1, DIM / 64), 256, 0, stream>>>(W_comb, wcombT, DIM, HEADS * 3);
    // 1. RMSNorm (fp32 + bf16)
    rmsnorm_kernel<<<S, 256, 0, stream>>>(x, rms_g, xn, xnb);
    // 2. QKV projection (bf16 B^T MFMA)
    gemm_bt_kernel<64, 64, 2, 2, 0><<<dim3(QKVC / 64, S / 64), 256, 0, stream>>>(
        xnb, wqkvT, nullptr, qkv, S, QKVC, DIM);
    // 2.5 gates = sigmoid(xn @ W_comb + b_comb)
    gemm_bt_kernel<64, 64, 2, 2, 2><<<dim3(1, S / 64), 256, 0, stream>>>(
        xnb, wcombT, b_comb, gates, S, HEADS * 3, DIM);
    // 3. rotary -> bf16 rqb, rkb
    rotary_kernel<<<S, 256, 0, stream>>>(qkv, rqb, rkb);
    // 4. compress-MLP inputs (bf16)
    build_cmat_kernel<<<KVH * NCB, 256, 0, stream>>>(qkv, k_pos, v_pos, kcmb, vcmb);
    // 5. k-MLP W1 (bf16 MFMA, split-K 8)
    gemm_mfma_kernel<64, 128, 1, 4><<<dim3(CDIM / 128, 1, 8), 256, 0, stream>>>(
        kcmb, kW1, partW1, 64, CDIM, CDIM, CDIM / 8);
    reduce_splitk_kernel<1><<<(64 * CDIM + 255) / 256, 256, 0, stream>>>(
        partW1, kb1, khid, 64 * CDIM, CDIM, 8);
    // 6. k-MLP W2 (fp32 split-K 32)
    gemm_splitk_kernel<<<dim3(1, 1, 32), 256, 0, stream>>>(khid, kW2, partW2, 64, DH, CDIM, CDIM / 32);
    reduce_splitk_kernel<0><<<(64 * DH + 255) / 256, 256, 0, stream>>>(partW2, kb2, ckb, 64 * DH, DH, 32);
    // 7. v-MLP
    gemm_mfma_kernel<64, 128, 1, 4><<<dim3(CDIM / 128, 1, 8), 256, 0, stream>>>(
        vcmb, vW1, partW1, 64, CDIM, CDIM, CDIM / 8);
    reduce_splitk_kernel<1><<<(64 * CDIM + 255) / 256, 256, 0, stream>>>(
        partW1, vb1, vhid, 64 * CDIM, CDIM, 8);
    gemm_splitk_kernel<<<dim3(1, 1, 32), 256, 0, stream>>>(vhid, vW2, partW2, 64, DH, CDIM, CDIM / 32);
    reduce_splitk_kernel<0><<<(64 * DH + 255) / 256, 256, 0, stream>>>(partW2, vb2, cvb, 64 * DH, DH, 32);
    // 8. assemble ck/cv (fp32 + bf16) with mem tokens
    assemble_kernel<<<(KVH * (NCB + 1) * DH + 255) / 256, 256, 0, stream>>>(
        ckb, cvb, mem_kv, ck, cv, ck16, cv16);
    // 10. block importance
    imp_kernel<<<dim3(KVH, S), 64, 0, stream>>>(qkv, ck, imp);
    // 11. top-8 selection
    select_kernel<<<(KVH * S + 255) / 256, 256, 0, stream>>>(imp, sel);
    // 11.5 cast V cols -> bf16 vbb
    cast_v_kernel<<<(S * KVH * DH / 4 + 255) / 256, 256, 0, stream>>>(qkv, vbb);
    // 12. compressed attention, MFMA (writes attn = g0*c_out)
    cattn_kernel<<<dim3(HEADS, S / 64), 256, 0, stream>>>(qkv, ck16, cv16, gates, attn);
    // 13. fine attention, MFMA (attn += g1*f_out)
    fattn_kernel<<<dim3(KVH, S), 256, 0, stream>>>(rqb, rkb, vbb, sel, gates, attn);
    // 14. sliding window, MFMA (attn += g2*s_out)
    sattn_kernel<<<dim3(HEADS, S / 64), 256, 0, stream>>>(rqb, rkb, vbb, gates, attn);
    // 15. cast attn -> bf16
    cast_bf16_kernel<<<(S * HEADS * DH / 4 + 255) / 256, 256, 0, stream>>>(
        attn, attnb, S * HEADS * DH / 4);
    // 16. output projection (bf16 B^T MFMA)
    gemm_bt_kernel<64, 64, 2, 2, 0><<<dim3(DIM / 64, S / 64), 256, 0, stream>>>(
        attnb, woutT, nullptr, out, S, DIM, DIM);
}